// Round 3
// baseline (5118.549 us; speedup 1.0000x reference)
//
#include <hip/hip_runtime.h>
#include <math.h>

#define N_NODES 30000
#define F_IN 256
#define E_RAW 300000
#define E_TOT (E_RAW + N_NODES)   /* 330000: edges + self loops */
#define HEADS 8
#define CH 128
#define HC 1024                   /* HEADS*CH */
#define OUTC 64
#define NEG_SLOPE 0.2f

/* ---------- helpers ---------- */
__device__ __forceinline__ float bf2f(unsigned short u) {
    return __uint_as_float(((unsigned)u) << 16);
}
__device__ __forceinline__ unsigned short f2bf(float f) {
    unsigned b = __float_as_uint(f);
    b += 0x7FFFu + ((b >> 16) & 1u);   /* round to nearest even */
    return (unsigned short)(b >> 16);
}
/* monotonic float<->uint for atomicMax on floats (incl. negatives) */
__device__ __forceinline__ unsigned fkey(float f) {
    unsigned b = __float_as_uint(f);
    return (b & 0x80000000u) ? ~b : (b | 0x80000000u);
}
__device__ __forceinline__ float fdec(unsigned k) {
    unsigned b = (k & 0x80000000u) ? (k & 0x7FFFFFFFu) : ~k;
    return __uint_as_float(b);
}
__device__ __forceinline__ void edge_sd(const int* __restrict__ ei, int e, int& s, int& d) {
    if (e < E_RAW) { s = ei[e]; d = ei[E_RAW + e]; }
    else           { s = e - E_RAW; d = s; }
}

__device__ __forceinline__ void storeC(unsigned short* p, float v) { *p = f2bf(v); }
__device__ __forceinline__ void storeC(float* p, float v) { *p = v; }

/* ---------- generic 64x64 tiled GEMM, fp32 accumulate ----------
   A: [M,K] row-major fp32, B: [K,N] row-major fp32, C: [M,N] fp32 or bf16 */
template <typename CT>
__global__ __launch_bounds__(256)
void gemm_64x64(const float* __restrict__ A, const float* __restrict__ B,
                CT* __restrict__ C, int M, int N, int K)
{
    __shared__ float As[16][68];
    __shared__ float Bs[16][68];
    const int tid = threadIdx.x;
    const int tr = tid >> 4;     /* 0..15 */
    const int tc = tid & 15;     /* 0..15 */
    const int row0 = blockIdx.y * 64;
    const int col0 = blockIdx.x * 64;

    float acc[4][4];
#pragma unroll
    for (int i = 0; i < 4; i++)
#pragma unroll
        for (int j = 0; j < 4; j++) acc[i][j] = 0.f;

    for (int k0 = 0; k0 < K; k0 += 16) {
#pragma unroll
        for (int u = 0; u < 4; u++) {           /* A tile: 64 rows x 16 k */
            int l = tid + 256 * u;
            int m = l >> 4, k = l & 15;
            int row = row0 + m;
            As[k][m] = (row < M) ? A[(size_t)row * K + k0 + k] : 0.f;
        }
#pragma unroll
        for (int u = 0; u < 4; u++) {           /* B tile: 16 k x 64 cols */
            int l = tid + 256 * u;
            int k = l >> 6, n = l & 63;
            Bs[k][n] = B[(size_t)(k0 + k) * N + col0 + n];
        }
        __syncthreads();
#pragma unroll
        for (int k = 0; k < 16; k++) {
            float a[4], b[4];
#pragma unroll
            for (int i = 0; i < 4; i++) a[i] = As[k][tr + 16 * i];
#pragma unroll
            for (int j = 0; j < 4; j++) b[j] = Bs[k][tc + 16 * j];
#pragma unroll
            for (int i = 0; i < 4; i++)
#pragma unroll
                for (int j = 0; j < 4; j++) acc[i][j] += a[i] * b[j];
        }
        __syncthreads();
    }
#pragma unroll
    for (int i = 0; i < 4; i++) {
        int row = row0 + tr + 16 * i;
        if (row >= M) continue;
#pragma unroll
        for (int j = 0; j < 4; j++) {
            int col = col0 + tc + 16 * j;
            storeC(C + (size_t)row * N + col, acc[i][j]);
        }
    }
}

/* ---------- layer-1 attention dots: a_src/a_dst [N,8] (h1 is bf16) ---------- */
__global__ __launch_bounds__(64)
void att1_kernel(const unsigned short* __restrict__ h1,
                 const float* __restrict__ att_src,
                 const float* __restrict__ att_dst,
                 float* __restrict__ a_src, float* __restrict__ a_dst)
{
    const int n = blockIdx.x, h = blockIdx.y, t = threadIdx.x;
    const unsigned short* hp = h1 + (size_t)n * HC + h * CH;
    const float* as = att_src + h * CH;
    const float* ad = att_dst + h * CH;
    float v0 = bf2f(hp[t]), v1 = bf2f(hp[t + 64]);
    float s = v0 * as[t] + v1 * as[t + 64];
    float d = v0 * ad[t] + v1 * ad[t + 64];
#pragma unroll
    for (int o = 32; o > 0; o >>= 1) { s += __shfl_down(s, o); d += __shfl_down(d, o); }
    if (t == 0) { a_src[n * HEADS + h] = s; a_dst[n * HEADS + h] = d; }
}

/* ---------- layer-1 edge passes ---------- */
__global__ void edge_logit1(const int* __restrict__ ei, const float* __restrict__ a_src,
                            const float* __restrict__ a_dst, float* __restrict__ e1,
                            unsigned* __restrict__ m1u)
{
    int i = blockIdx.x * 256 + threadIdx.x;
    if (i >= E_TOT * HEADS) return;
    int e = i >> 3, h = i & 7;
    int s, d; edge_sd(ei, e, s, d);
    float a = a_src[s * 8 + h] + a_dst[d * 8 + h];
    float v = a > 0.f ? a : NEG_SLOPE * a;
    e1[i] = v;
    atomicMax(&m1u[d * 8 + h], fkey(v));
}

__global__ void edge_exp1(const int* __restrict__ ei, float* __restrict__ e1,
                          const unsigned* __restrict__ m1u, float* __restrict__ denom1)
{
    int i = blockIdx.x * 256 + threadIdx.x;
    if (i >= E_TOT * HEADS) return;
    int e = i >> 3, h = i & 7;
    int s, d; edge_sd(ei, e, s, d);
    float m = fdec(m1u[d * 8 + h]);
    float ex = __expf(e1[i] - m);
    e1[i] = ex;
    atomicAdd(&denom1[d * 8 + h], ex);
}

__global__ __launch_bounds__(256)
void agg1(const int* __restrict__ ei, const unsigned short* __restrict__ h1,
          const float* __restrict__ e1, const float* __restrict__ denom1,
          float* __restrict__ out1)
{
    __shared__ float alpha[8];
    const int e = blockIdx.x;
    int s, d; edge_sd(ei, e, s, d);
    const int t = threadIdx.x;
    if (t < 8) alpha[t] = e1[e * 8 + t] / (denom1[d * 8 + t] + 1e-16f);
    __syncthreads();
    const ushort4* hp = reinterpret_cast<const ushort4*>(h1 + (size_t)s * HC);
    ushort4 u = hp[t];
    float al = alpha[t >> 5];
    float* op = out1 + (size_t)d * HC + t * 4;
    atomicAdd(op + 0, al * bf2f(u.x));
    atomicAdd(op + 1, al * bf2f(u.y));
    atomicAdd(op + 2, al * bf2f(u.z));
    atomicAdd(op + 3, al * bf2f(u.w));
}

/* ---------- ELU + bias (in place, fp32) ---------- */
__global__ void elu_bias(float* __restrict__ out1, const float* __restrict__ b1)
{
    size_t i = (size_t)blockIdx.x * 256 + threadIdx.x;
    if (i >= (size_t)N_NODES * HC) return;
    float v = out1[i] + b1[i & (HC - 1)];
    out1[i] = v > 0.f ? v : __expf(v) - 1.f;
}

/* ---------- layer-2 attention dots ---------- */
__global__ __launch_bounds__(64)
void att2_kernel(const float* __restrict__ h2, const float* __restrict__ att_src2,
                 const float* __restrict__ att_dst2,
                 float* __restrict__ a_src2, float* __restrict__ a_dst2)
{
    const int n = blockIdx.x, t = threadIdx.x;
    float v = h2[(size_t)n * OUTC + t];
    float s = v * att_src2[t];
    float d = v * att_dst2[t];
#pragma unroll
    for (int o = 32; o > 0; o >>= 1) { s += __shfl_down(s, o); d += __shfl_down(d, o); }
    if (t == 0) { a_src2[n] = s; a_dst2[n] = d; }
}

/* ---------- layer-2 edge passes ---------- */
__global__ void edge_logit2(const int* __restrict__ ei, const float* __restrict__ a_src2,
                            const float* __restrict__ a_dst2, float* __restrict__ e2,
                            unsigned* __restrict__ m2u)
{
    int e = blockIdx.x * 256 + threadIdx.x;
    if (e >= E_TOT) return;
    int s, d; edge_sd(ei, e, s, d);
    float a = a_src2[s] + a_dst2[d];
    float v = a > 0.f ? a : NEG_SLOPE * a;
    e2[e] = v;
    atomicMax(&m2u[d], fkey(v));
}

__global__ void edge_exp2(const int* __restrict__ ei, float* __restrict__ e2,
                          const unsigned* __restrict__ m2u, float* __restrict__ denom2)
{
    int e = blockIdx.x * 256 + threadIdx.x;
    if (e >= E_TOT) return;
    int s, d; edge_sd(ei, e, s, d);
    float ex = __expf(e2[e] - fdec(m2u[d]));
    e2[e] = ex;
    atomicAdd(&denom2[d], ex);
}

__global__ void agg2(const int* __restrict__ ei, const float* __restrict__ h2,
                     const float* __restrict__ e2, const float* __restrict__ denom2,
                     float* __restrict__ out2)
{
    int i = blockIdx.x * 256 + threadIdx.x;
    if (i >= E_TOT * OUTC) return;
    int e = i >> 6, c = i & 63;
    int s, d; edge_sd(ei, e, s, d);
    float alpha = e2[e] / (denom2[d] + 1e-16f);
    atomicAdd(&out2[(size_t)d * OUTC + c], alpha * h2[(size_t)s * OUTC + c]);
}

/* ---------- bias + log_softmax -> fp32 out ---------- */
__global__ __launch_bounds__(64)
void lsm_kernel(const float* __restrict__ out2, const float* __restrict__ b2,
                float* __restrict__ out)
{
    const int n = blockIdx.x, t = threadIdx.x;
    float v = out2[(size_t)n * OUTC + t] + b2[t];
    float m = v;
#pragma unroll
    for (int o = 32; o > 0; o >>= 1) m = fmaxf(m, __shfl_xor(m, o));
    float ex = __expf(v - m);
    float ssum = ex;
#pragma unroll
    for (int o = 32; o > 0; o >>= 1) ssum += __shfl_xor(ssum, o);
    out[(size_t)n * OUTC + t] = v - m - __logf(ssum);
}

extern "C" void kernel_launch(void* const* d_in, const int* in_sizes, int n_in,
                              void* d_out, int out_size, void* d_ws, size_t ws_size,
                              hipStream_t stream)
{
    const float* x   = (const float*)d_in[0];
    const int*   ei  = (const int*)d_in[1];
    const float* W1  = (const float*)d_in[2];
    const float* as1 = (const float*)d_in[3];
    const float* ad1 = (const float*)d_in[4];
    const float* b1  = (const float*)d_in[5];
    const float* W2  = (const float*)d_in[6];
    const float* as2 = (const float*)d_in[7];
    const float* ad2 = (const float*)d_in[8];
    const float* b2  = (const float*)d_in[9];

    char* p = (char*)d_ws;
    auto alloc = [&](size_t bytes) { char* r = p; p += (bytes + 255) & ~(size_t)255; return r; };

    /* region 0: h1 (bf16, 61.44 MB) — dead after agg1; layer-2 buffers alias it */
    char* region0 = (char*)alloc((size_t)N_NODES * HC * 2);
    unsigned short* h1 = (unsigned short*)region0;

    float*    out1   = (float*)alloc((size_t)N_NODES * HC * 4);
    float*    a_src1 = (float*)alloc((size_t)N_NODES * HEADS * 4);
    float*    a_dst1 = (float*)alloc((size_t)N_NODES * HEADS * 4);
    unsigned* m1u    = (unsigned*)alloc((size_t)N_NODES * HEADS * 4);
    float*    denom1 = (float*)alloc((size_t)N_NODES * HEADS * 4);
    float*    e1     = (float*)alloc((size_t)E_TOT * HEADS * 4);

    /* layer-2 buffers aliased into region0 (17.2 MB < 61.44 MB) */
    char* q = region0;
    auto alias = [&](size_t bytes) { char* r = q; q += (bytes + 255) & ~(size_t)255; return r; };
    float*    h2     = (float*)alias((size_t)N_NODES * OUTC * 4);
    float*    a_src2 = (float*)alias((size_t)N_NODES * 4);
    float*    a_dst2 = (float*)alias((size_t)N_NODES * 4);
    unsigned* m2u    = (unsigned*)alias((size_t)N_NODES * 4);
    float*    denom2 = (float*)alias((size_t)N_NODES * 4);
    float*    e2     = (float*)alias((size_t)E_TOT * 4);
    float*    out2   = (float*)alias((size_t)N_NODES * OUTC * 4);

    /* zero-init layer-1 accumulators (ws is poisoned 0xAA each call) */
    hipMemsetAsync(out1,   0, (size_t)N_NODES * HC * 4, stream);
    hipMemsetAsync(m1u,    0, (size_t)N_NODES * HEADS * 4, stream);
    hipMemsetAsync(denom1, 0, (size_t)N_NODES * HEADS * 4, stream);

    /* layer 1 */
    gemm_64x64<unsigned short>
        <<<dim3(HC / 64, (N_NODES + 63) / 64), 256, 0, stream>>>(x, W1, h1, N_NODES, HC, F_IN);
    att1_kernel<<<dim3(N_NODES, HEADS), 64, 0, stream>>>(h1, as1, ad1, a_src1, a_dst1);
    {
        int nthr = E_TOT * HEADS;
        edge_logit1<<<(nthr + 255) / 256, 256, 0, stream>>>(ei, a_src1, a_dst1, e1, m1u);
        edge_exp1<<<(nthr + 255) / 256, 256, 0, stream>>>(ei, e1, m1u, denom1);
    }
    agg1<<<E_TOT, 256, 0, stream>>>(ei, h1, e1, denom1, out1);

    /* h1 now dead — init aliased layer-2 accumulators (stream-ordered after agg1) */
    hipMemsetAsync(m2u,    0, (size_t)N_NODES * 4, stream);
    hipMemsetAsync(denom2, 0, (size_t)N_NODES * 4, stream);
    hipMemsetAsync(out2,   0, (size_t)N_NODES * OUTC * 4, stream);

    elu_bias<<<(int)(((size_t)N_NODES * HC + 255) / 256), 256, 0, stream>>>(out1, b1);

    /* layer 2 */
    gemm_64x64<float>
        <<<dim3(OUTC / 64, (N_NODES + 63) / 64), 256, 0, stream>>>(out1, W2, h2, N_NODES, OUTC, HC);
    att2_kernel<<<N_NODES, 64, 0, stream>>>(h2, as2, ad2, a_src2, a_dst2);
    edge_logit2<<<(E_TOT + 255) / 256, 256, 0, stream>>>(ei, a_src2, a_dst2, e2, m2u);
    edge_exp2<<<(E_TOT + 255) / 256, 256, 0, stream>>>(ei, e2, m2u, denom2);
    agg2<<<(int)(((size_t)E_TOT * OUTC + 255) / 256), 256, 0, stream>>>(ei, h2, e2, denom2, out2);
    lsm_kernel<<<N_NODES, 64, 0, stream>>>(out2, b2, (float*)d_out);
}

// Round 4
// 925.651 us; speedup vs baseline: 5.5297x; 5.5297x over previous
//
#include <hip/hip_runtime.h>
#include <math.h>

#define N_NODES 30000
#define F_IN 256
#define E_RAW 300000
#define E_TOT (E_RAW + N_NODES)   /* 330000: edges + self loops */
#define HEADS 8
#define CH 128
#define HC 1024                   /* HEADS*CH */
#define OUTC 64
#define NEG_SLOPE 0.2f

/* ---------- helpers ---------- */
__device__ __forceinline__ float bf2f(unsigned short u) {
    return __uint_as_float(((unsigned)u) << 16);
}
__device__ __forceinline__ unsigned short f2bf(float f) {
    unsigned b = __float_as_uint(f);
    b += 0x7FFFu + ((b >> 16) & 1u);   /* round to nearest even */
    return (unsigned short)(b >> 16);
}
/* monotonic float<->uint for atomicMax on floats (incl. negatives) */
__device__ __forceinline__ unsigned fkey(float f) {
    unsigned b = __float_as_uint(f);
    return (b & 0x80000000u) ? ~b : (b | 0x80000000u);
}
__device__ __forceinline__ float fdec(unsigned k) {
    unsigned b = (k & 0x80000000u) ? (k & 0x7FFFFFFFu) : ~k;
    return __uint_as_float(b);
}
__device__ __forceinline__ void edge_sd(const int* __restrict__ ei, int e, int& s, int& d) {
    if (e < E_RAW) { s = ei[e]; d = ei[E_RAW + e]; }
    else           { s = e - E_RAW; d = s; }
}
__device__ __forceinline__ int edge_src(const int* __restrict__ ei, int e) {
    return (e < E_RAW) ? ei[e] : e - E_RAW;
}

__device__ __forceinline__ void storeC(unsigned short* p, float v) { *p = f2bf(v); }
__device__ __forceinline__ void storeC(float* p, float v) { *p = v; }

/* ---------- generic 64x64 tiled GEMM, fp32 accumulate ---------- */
template <typename CT>
__global__ __launch_bounds__(256)
void gemm_64x64(const float* __restrict__ A, const float* __restrict__ B,
                CT* __restrict__ C, int M, int N, int K)
{
    __shared__ float As[16][68];
    __shared__ float Bs[16][68];
    const int tid = threadIdx.x;
    const int tr = tid >> 4;
    const int tc = tid & 15;
    const int row0 = blockIdx.y * 64;
    const int col0 = blockIdx.x * 64;

    float acc[4][4];
#pragma unroll
    for (int i = 0; i < 4; i++)
#pragma unroll
        for (int j = 0; j < 4; j++) acc[i][j] = 0.f;

    for (int k0 = 0; k0 < K; k0 += 16) {
#pragma unroll
        for (int u = 0; u < 4; u++) {
            int l = tid + 256 * u;
            int m = l >> 4, k = l & 15;
            int row = row0 + m;
            As[k][m] = (row < M) ? A[(size_t)row * K + k0 + k] : 0.f;
        }
#pragma unroll
        for (int u = 0; u < 4; u++) {
            int l = tid + 256 * u;
            int k = l >> 6, n = l & 63;
            Bs[k][n] = B[(size_t)(k0 + k) * N + col0 + n];
        }
        __syncthreads();
#pragma unroll
        for (int k = 0; k < 16; k++) {
            float a[4], b[4];
#pragma unroll
            for (int i = 0; i < 4; i++) a[i] = As[k][tr + 16 * i];
#pragma unroll
            for (int j = 0; j < 4; j++) b[j] = Bs[k][tc + 16 * j];
#pragma unroll
            for (int i = 0; i < 4; i++)
#pragma unroll
                for (int j = 0; j < 4; j++) acc[i][j] += a[i] * b[j];
        }
        __syncthreads();
    }
#pragma unroll
    for (int i = 0; i < 4; i++) {
        int row = row0 + tr + 16 * i;
        if (row >= M) continue;
#pragma unroll
        for (int j = 0; j < 4; j++) {
            int col = col0 + tc + 16 * j;
            storeC(C + (size_t)row * N + col, acc[i][j]);
        }
    }
}

/* ---------- CSR build ---------- */
__global__ void deg_kernel(const int* __restrict__ ei, int* __restrict__ deg)
{
    int e = blockIdx.x * 256 + threadIdx.x;
    if (e >= E_TOT) return;
    int s, d; edge_sd(ei, e, s, d);
    atomicAdd(&deg[d], 1);
}

/* single-block exclusive scan over N_NODES ints -> rowptr[N+1], cursor copy */
__global__ __launch_bounds__(1024)
void scan_kernel(const int* __restrict__ deg, int* __restrict__ rowptr,
                 int* __restrict__ cursor)
{
    __shared__ int smem[1024];
    __shared__ int carry_s;
    const int t = threadIdx.x;
    if (t == 0) carry_s = 0;
    __syncthreads();
    for (int base = 0; base < N_NODES; base += 1024) {
        int v = (base + t < N_NODES) ? deg[base + t] : 0;
        smem[t] = v;
        __syncthreads();
#pragma unroll
        for (int off = 1; off < 1024; off <<= 1) {
            int x = (t >= off) ? smem[t - off] : 0;
            __syncthreads();
            smem[t] += x;
            __syncthreads();
        }
        int excl = carry_s + smem[t] - v;
        if (base + t < N_NODES) { rowptr[base + t] = excl; cursor[base + t] = excl; }
        __syncthreads();
        if (t == 0) carry_s += smem[1023];
        __syncthreads();
    }
    if (t == 0) rowptr[N_NODES] = carry_s;
}

__global__ void scatter_kernel(const int* __restrict__ ei, int* __restrict__ cursor,
                               int* __restrict__ eid)
{
    int e = blockIdx.x * 256 + threadIdx.x;
    if (e >= E_TOT) return;
    int s, d; edge_sd(ei, e, s, d);
    int pos = atomicAdd(&cursor[d], 1);
    eid[pos] = e;
}

/* ---------- layer-1 attention dots: a_src/a_dst [N,8] (h1 is bf16) ---------- */
__global__ __launch_bounds__(64)
void att1_kernel(const unsigned short* __restrict__ h1,
                 const float* __restrict__ att_src,
                 const float* __restrict__ att_dst,
                 float* __restrict__ a_src, float* __restrict__ a_dst)
{
    const int n = blockIdx.x, h = blockIdx.y, t = threadIdx.x;
    const unsigned short* hp = h1 + (size_t)n * HC + h * CH;
    const float* as = att_src + h * CH;
    const float* ad = att_dst + h * CH;
    float v0 = bf2f(hp[t]), v1 = bf2f(hp[t + 64]);
    float s = v0 * as[t] + v1 * as[t + 64];
    float d = v0 * ad[t] + v1 * ad[t + 64];
#pragma unroll
    for (int o = 32; o > 0; o >>= 1) { s += __shfl_down(s, o); d += __shfl_down(d, o); }
    if (t == 0) { a_src[n * HEADS + h] = s; a_dst[n * HEADS + h] = d; }
}

/* ---------- layer-1 edge softmax passes (atomic max/denom, cheap) ---------- */
__global__ void edge_logit1(const int* __restrict__ ei, const float* __restrict__ a_src,
                            const float* __restrict__ a_dst, float* __restrict__ e1,
                            unsigned* __restrict__ m1u)
{
    int i = blockIdx.x * 256 + threadIdx.x;
    if (i >= E_TOT * HEADS) return;
    int e = i >> 3, h = i & 7;
    int s, d; edge_sd(ei, e, s, d);
    float a = a_src[s * 8 + h] + a_dst[d * 8 + h];
    float v = a > 0.f ? a : NEG_SLOPE * a;
    e1[i] = v;
    atomicMax(&m1u[d * 8 + h], fkey(v));
}

__global__ void edge_exp1(const int* __restrict__ ei, float* __restrict__ e1,
                          const unsigned* __restrict__ m1u, float* __restrict__ denom1)
{
    int i = blockIdx.x * 256 + threadIdx.x;
    if (i >= E_TOT * HEADS) return;
    int e = i >> 3, h = i & 7;
    int s, d; edge_sd(ei, e, s, d);
    float m = fdec(m1u[d * 8 + h]);
    float ex = __expf(e1[i] - m);
    e1[i] = ex;
    atomicAdd(&denom1[d * 8 + h], ex);
}

/* ---------- layer-1 CSR aggregation, fused bias+ELU ----------
   one 256-thread block per dst node; thread t owns channels 4t..4t+3 */
__global__ __launch_bounds__(256)
void agg1_csr(const int* __restrict__ rowptr, const int* __restrict__ eid,
              const int* __restrict__ ei, const unsigned short* __restrict__ h1,
              const float* __restrict__ e1, const float* __restrict__ denom1,
              const float* __restrict__ b1, float* __restrict__ out1)
{
    const int d = blockIdx.x;
    const int t = threadIdx.x;
    const int h = t >> 5;                      /* head = (4t)/128 */
    const float dinv = 1.f / (denom1[d * 8 + h] + 1e-16f);
    const int start = rowptr[d], end = rowptr[d + 1];
    float a0 = 0.f, a1 = 0.f, a2 = 0.f, a3 = 0.f;
    for (int i = start; i < end; i++) {
        int e = eid[i];
        int s = edge_src(ei, e);
        float alpha = e1[e * 8 + h] * dinv;
        ushort4 u = reinterpret_cast<const ushort4*>(h1 + (size_t)s * HC)[t];
        a0 += alpha * bf2f(u.x);
        a1 += alpha * bf2f(u.y);
        a2 += alpha * bf2f(u.z);
        a3 += alpha * bf2f(u.w);
    }
    float4 bb = reinterpret_cast<const float4*>(b1)[t];
    float v0 = a0 + bb.x, v1 = a1 + bb.y, v2 = a2 + bb.z, v3 = a3 + bb.w;
    v0 = v0 > 0.f ? v0 : __expf(v0) - 1.f;
    v1 = v1 > 0.f ? v1 : __expf(v1) - 1.f;
    v2 = v2 > 0.f ? v2 : __expf(v2) - 1.f;
    v3 = v3 > 0.f ? v3 : __expf(v3) - 1.f;
    reinterpret_cast<float4*>(out1 + (size_t)d * HC)[t] = make_float4(v0, v1, v2, v3);
}

/* ---------- layer-2 attention dots ---------- */
__global__ __launch_bounds__(64)
void att2_kernel(const float* __restrict__ h2, const float* __restrict__ att_src2,
                 const float* __restrict__ att_dst2,
                 float* __restrict__ a_src2, float* __restrict__ a_dst2)
{
    const int n = blockIdx.x, t = threadIdx.x;
    float v = h2[(size_t)n * OUTC + t];
    float s = v * att_src2[t];
    float d = v * att_dst2[t];
#pragma unroll
    for (int o = 32; o > 0; o >>= 1) { s += __shfl_down(s, o); d += __shfl_down(d, o); }
    if (t == 0) { a_src2[n] = s; a_dst2[n] = d; }
}

/* ---------- layer-2 edge softmax passes ---------- */
__global__ void edge_logit2(const int* __restrict__ ei, const float* __restrict__ a_src2,
                            const float* __restrict__ a_dst2, float* __restrict__ e2,
                            unsigned* __restrict__ m2u)
{
    int e = blockIdx.x * 256 + threadIdx.x;
    if (e >= E_TOT) return;
    int s, d; edge_sd(ei, e, s, d);
    float a = a_src2[s] + a_dst2[d];
    float v = a > 0.f ? a : NEG_SLOPE * a;
    e2[e] = v;
    atomicMax(&m2u[d], fkey(v));
}

__global__ void edge_exp2(const int* __restrict__ ei, float* __restrict__ e2,
                          const unsigned* __restrict__ m2u, float* __restrict__ denom2)
{
    int e = blockIdx.x * 256 + threadIdx.x;
    if (e >= E_TOT) return;
    int s, d; edge_sd(ei, e, s, d);
    float ex = __expf(e2[e] - fdec(m2u[d]));
    e2[e] = ex;
    atomicAdd(&denom2[d], ex);
}

/* ---------- layer-2 CSR aggregation fused with bias + log_softmax ----------
   one wave (64 lanes) per dst node; lane = channel; 4 nodes per block */
__global__ __launch_bounds__(256)
void agg2_lsm(const int* __restrict__ rowptr, const int* __restrict__ eid,
              const int* __restrict__ ei, const float* __restrict__ h2,
              const float* __restrict__ e2, const float* __restrict__ denom2,
              const float* __restrict__ b2, float* __restrict__ out)
{
    const int t = threadIdx.x;
    const int d = blockIdx.x * 4 + (t >> 6);
    const int lane = t & 63;
    const float dinv = 1.f / (denom2[d] + 1e-16f);
    const int start = rowptr[d], end = rowptr[d + 1];
    float acc = 0.f;
    for (int i = start; i < end; i++) {
        int e = eid[i];
        int s = edge_src(ei, e);
        acc += (e2[e] * dinv) * h2[(size_t)s * OUTC + lane];
    }
    float v = acc + b2[lane];
    float m = v;
#pragma unroll
    for (int o = 32; o > 0; o >>= 1) m = fmaxf(m, __shfl_xor(m, o));
    float ex = __expf(v - m);
    float ssum = ex;
#pragma unroll
    for (int o = 32; o > 0; o >>= 1) ssum += __shfl_xor(ssum, o);
    out[(size_t)d * OUTC + lane] = v - m - __logf(ssum);
}

extern "C" void kernel_launch(void* const* d_in, const int* in_sizes, int n_in,
                              void* d_out, int out_size, void* d_ws, size_t ws_size,
                              hipStream_t stream)
{
    const float* x   = (const float*)d_in[0];
    const int*   ei  = (const int*)d_in[1];
    const float* W1  = (const float*)d_in[2];
    const float* as1 = (const float*)d_in[3];
    const float* ad1 = (const float*)d_in[4];
    const float* b1  = (const float*)d_in[5];
    const float* W2  = (const float*)d_in[6];
    const float* as2 = (const float*)d_in[7];
    const float* ad2 = (const float*)d_in[8];
    const float* b2  = (const float*)d_in[9];

    char* p = (char*)d_ws;
    auto alloc = [&](size_t bytes) { char* r = p; p += (bytes + 255) & ~(size_t)255; return r; };

    /* region 0: h1 (bf16, 61.44 MB) — dead after agg1_csr; layer-2 buffers alias it */
    char* region0 = (char*)alloc((size_t)N_NODES * HC * 2);
    unsigned short* h1 = (unsigned short*)region0;

    float*    out1   = (float*)alloc((size_t)N_NODES * HC * 4);
    float*    a_src1 = (float*)alloc((size_t)N_NODES * HEADS * 4);
    float*    a_dst1 = (float*)alloc((size_t)N_NODES * HEADS * 4);
    unsigned* m1u    = (unsigned*)alloc((size_t)N_NODES * HEADS * 4);
    float*    denom1 = (float*)alloc((size_t)N_NODES * HEADS * 4);
    float*    e1     = (float*)alloc((size_t)E_TOT * HEADS * 4);
    int*      deg    = (int*)alloc((size_t)N_NODES * 4);
    int*      rowptr = (int*)alloc((size_t)(N_NODES + 1) * 4);
    int*      cursor = (int*)alloc((size_t)N_NODES * 4);
    int*      eid    = (int*)alloc((size_t)E_TOT * 4);

    /* layer-2 buffers aliased into region0 (~9.4 MB < 61.44 MB) */
    char* q = region0;
    auto alias = [&](size_t bytes) { char* r = q; q += (bytes + 255) & ~(size_t)255; return r; };
    float*    h2     = (float*)alias((size_t)N_NODES * OUTC * 4);
    float*    a_src2 = (float*)alias((size_t)N_NODES * 4);
    float*    a_dst2 = (float*)alias((size_t)N_NODES * 4);
    unsigned* m2u    = (unsigned*)alias((size_t)N_NODES * 4);
    float*    denom2 = (float*)alias((size_t)N_NODES * 4);
    float*    e2     = (float*)alias((size_t)E_TOT * 4);

    /* zero-init (ws is poisoned 0xAA each call) */
    hipMemsetAsync(deg,    0, (size_t)N_NODES * 4, stream);
    hipMemsetAsync(m1u,    0, (size_t)N_NODES * HEADS * 4, stream);
    hipMemsetAsync(denom1, 0, (size_t)N_NODES * HEADS * 4, stream);

    /* CSR build */
    deg_kernel<<<(E_TOT + 255) / 256, 256, 0, stream>>>(ei, deg);
    scan_kernel<<<1, 1024, 0, stream>>>(deg, rowptr, cursor);
    scatter_kernel<<<(E_TOT + 255) / 256, 256, 0, stream>>>(ei, cursor, eid);

    /* layer 1 */
    gemm_64x64<unsigned short>
        <<<dim3(HC / 64, (N_NODES + 63) / 64), 256, 0, stream>>>(x, W1, h1, N_NODES, HC, F_IN);
    att1_kernel<<<dim3(N_NODES, HEADS), 64, 0, stream>>>(h1, as1, ad1, a_src1, a_dst1);
    {
        int nthr = E_TOT * HEADS;
        edge_logit1<<<(nthr + 255) / 256, 256, 0, stream>>>(ei, a_src1, a_dst1, e1, m1u);
        edge_exp1<<<(nthr + 255) / 256, 256, 0, stream>>>(ei, e1, m1u, denom1);
    }
    agg1_csr<<<N_NODES, 256, 0, stream>>>(rowptr, eid, ei, h1, e1, denom1, b1, out1);

    /* h1 now dead — init aliased layer-2 accumulators (stream-ordered after agg1_csr) */
    hipMemsetAsync(m2u,    0, (size_t)N_NODES * 4, stream);
    hipMemsetAsync(denom2, 0, (size_t)N_NODES * 4, stream);

    /* layer 2 */
    gemm_64x64<float>
        <<<dim3(OUTC / 64, (N_NODES + 63) / 64), 256, 0, stream>>>(out1, W2, h2, N_NODES, OUTC, HC);
    att2_kernel<<<N_NODES, 64, 0, stream>>>(h2, as2, ad2, a_src2, a_dst2);
    edge_logit2<<<(E_TOT + 255) / 256, 256, 0, stream>>>(ei, a_src2, a_dst2, e2, m2u);
    edge_exp2<<<(E_TOT + 255) / 256, 256, 0, stream>>>(ei, e2, m2u, denom2);
    agg2_lsm<<<N_NODES / 4, 256, 0, stream>>>(rowptr, eid, ei, h2, e2, denom2, b2, (float*)d_out);
}

// Round 5
// 706.752 us; speedup vs baseline: 7.2424x; 1.3097x over previous
//
#include <hip/hip_runtime.h>
#include <math.h>

#define N_NODES 30000
#define F_IN 256
#define E_RAW 300000
#define E_TOT (E_RAW + N_NODES)   /* 330000: edges + self loops */
#define HEADS 8
#define CH 128
#define HC 1024                   /* HEADS*CH */
#define OUTC 64
#define NEG_SLOPE 0.2f

typedef __attribute__((ext_vector_type(8))) short bf16x8;
typedef __attribute__((ext_vector_type(4))) float f32x4;

/* ---------- helpers ---------- */
__device__ __forceinline__ float bf2f(unsigned short u) {
    return __uint_as_float(((unsigned)u) << 16);
}
__device__ __forceinline__ unsigned short f2bf(float f) {
    unsigned b = __float_as_uint(f);
    b += 0x7FFFu + ((b >> 16) & 1u);   /* round to nearest even */
    return (unsigned short)(b >> 16);
}
__device__ __forceinline__ unsigned fkey(float f) {
    unsigned b = __float_as_uint(f);
    return (b & 0x80000000u) ? ~b : (b | 0x80000000u);
}
__device__ __forceinline__ float fdec(unsigned k) {
    unsigned b = (k & 0x80000000u) ? (k & 0x7FFFFFFFu) : ~k;
    return __uint_as_float(b);
}
__device__ __forceinline__ void edge_sd(const int* __restrict__ ei, int e, int& s, int& d) {
    if (e < E_RAW) { s = ei[e]; d = ei[E_RAW + e]; }
    else           { s = e - E_RAW; d = s; }
}
__device__ __forceinline__ int edge_src(const int* __restrict__ ei, int e) {
    return (e < E_RAW) ? ei[e] : e - E_RAW;
}

/* ---------- dtype converts ---------- */
__global__ void cvt_x_kernel(const float* __restrict__ x, unsigned short* __restrict__ xb)
{
    int i = blockIdx.x * 256 + threadIdx.x;                 /* i indexes float4 groups */
    const float4 v = reinterpret_cast<const float4*>(x)[i];
    ushort4 o;
    o.x = f2bf(v.x); o.y = f2bf(v.y); o.z = f2bf(v.z); o.w = f2bf(v.w);
    reinterpret_cast<ushort4*>(xb)[i] = o;
}

/* W1 [K=256][N=1024] fp32 -> W1t [N][K] bf16 */
__global__ void cvt_w1t_kernel(const float* __restrict__ W1, unsigned short* __restrict__ W1t)
{
    int i = blockIdx.x * 256 + threadIdx.x;
    if (i >= F_IN * HC) return;
    int k = i >> 10, n = i & (HC - 1);
    W1t[n * F_IN + k] = f2bf(W1[i]);
}

/* ---------- layer-1 MFMA GEMM: C[M,1024] = xb[M,256] @ W1t[1024,256]^T ----------
   128x128 tile, BK=32, 4 waves (2x2), each wave 4x4 16x16x32 MFMA frags.   */
#define LDA 40   /* padded LDS row stride in bf16 (80 B, 16B-aligned, 2-way banks) */
__global__ __launch_bounds__(256)
void gemm1_mfma(const unsigned short* __restrict__ A,   /* [M,256] bf16 */
                const unsigned short* __restrict__ Bt,  /* [1024,256] bf16 */
                unsigned short* __restrict__ C,         /* [M,1024] bf16 */
                int M)
{
    __shared__ unsigned short Al[128 * LDA];
    __shared__ unsigned short Bl[128 * LDA];
    const int tid  = threadIdx.x;
    const int wave = tid >> 6, lane = tid & 63;
    const int quad = lane >> 4, l16 = lane & 15;
    const int wr = (wave >> 1) * 64, wc = (wave & 1) * 64;
    const int row0 = blockIdx.y * 128;
    const int col0 = blockIdx.x * 128;

    f32x4 acc[4][4];
#pragma unroll
    for (int i = 0; i < 4; i++)
#pragma unroll
        for (int j = 0; j < 4; j++) acc[i][j] = (f32x4){0.f, 0.f, 0.f, 0.f};

    for (int k0 = 0; k0 < F_IN; k0 += 32) {
#pragma unroll
        for (int p = 0; p < 2; p++) {            /* stage A: 128 rows x 32 bf16 */
            int idx = tid + 256 * p;             /* 0..511 */
            int r = idx >> 2, q = idx & 3;
            int grow = row0 + r;
            uint4 v = (grow < M)
                ? *reinterpret_cast<const uint4*>(A + (size_t)grow * F_IN + k0 + q * 8)
                : make_uint4(0u, 0u, 0u, 0u);
            *reinterpret_cast<uint4*>(Al + r * LDA + q * 8) = v;
        }
#pragma unroll
        for (int p = 0; p < 2; p++) {            /* stage B^T: 128 rows x 32 bf16 */
            int idx = tid + 256 * p;
            int r = idx >> 2, q = idx & 3;
            uint4 v = *reinterpret_cast<const uint4*>(Bt + (size_t)(col0 + r) * F_IN + k0 + q * 8);
            *reinterpret_cast<uint4*>(Bl + r * LDA + q * 8) = v;
        }
        __syncthreads();
        bf16x8 af[4], bg[4];
#pragma unroll
        for (int i = 0; i < 4; i++)
            af[i] = *reinterpret_cast<const bf16x8*>(Al + (wr + i * 16 + l16) * LDA + quad * 8);
#pragma unroll
        for (int j = 0; j < 4; j++)
            bg[j] = *reinterpret_cast<const bf16x8*>(Bl + (wc + j * 16 + l16) * LDA + quad * 8);
#pragma unroll
        for (int i = 0; i < 4; i++)
#pragma unroll
            for (int j = 0; j < 4; j++)
                acc[i][j] = __builtin_amdgcn_mfma_f32_16x16x32_bf16(af[i], bg[j], acc[i][j], 0, 0, 0);
        __syncthreads();
    }
    /* epilogue: D row = quad*4+reg, col = l16 within each 16x16 tile */
#pragma unroll
    for (int i = 0; i < 4; i++) {
#pragma unroll
        for (int r = 0; r < 4; r++) {
            int row = row0 + wr + i * 16 + quad * 4 + r;
            if (row >= M) continue;
#pragma unroll
            for (int j = 0; j < 4; j++) {
                int col = col0 + wc + j * 16 + l16;
                C[(size_t)row * HC + col] = f2bf(acc[i][j][r]);
            }
        }
    }
}

/* ---------- generic 64x64 tiled GEMM, fp32 (layer 2) ---------- */
__global__ __launch_bounds__(256)
void gemm_64x64(const float* __restrict__ A, const float* __restrict__ B,
                float* __restrict__ C, int M, int N, int K)
{
    __shared__ float As[16][68];
    __shared__ float Bs[16][68];
    const int tid = threadIdx.x;
    const int tr = tid >> 4;
    const int tc = tid & 15;
    const int row0 = blockIdx.y * 64;
    const int col0 = blockIdx.x * 64;

    float acc[4][4];
#pragma unroll
    for (int i = 0; i < 4; i++)
#pragma unroll
        for (int j = 0; j < 4; j++) acc[i][j] = 0.f;

    for (int k0 = 0; k0 < K; k0 += 16) {
#pragma unroll
        for (int u = 0; u < 4; u++) {
            int l = tid + 256 * u;
            int m = l >> 4, k = l & 15;
            int row = row0 + m;
            As[k][m] = (row < M) ? A[(size_t)row * K + k0 + k] : 0.f;
        }
#pragma unroll
        for (int u = 0; u < 4; u++) {
            int l = tid + 256 * u;
            int k = l >> 6, n = l & 63;
            Bs[k][n] = B[(size_t)(k0 + k) * N + col0 + n];
        }
        __syncthreads();
#pragma unroll
        for (int k = 0; k < 16; k++) {
            float a[4], b[4];
#pragma unroll
            for (int i = 0; i < 4; i++) a[i] = As[k][tr + 16 * i];
#pragma unroll
            for (int j = 0; j < 4; j++) b[j] = Bs[k][tc + 16 * j];
#pragma unroll
            for (int i = 0; i < 4; i++)
#pragma unroll
                for (int j = 0; j < 4; j++) acc[i][j] += a[i] * b[j];
        }
        __syncthreads();
    }
#pragma unroll
    for (int i = 0; i < 4; i++) {
        int row = row0 + tr + 16 * i;
        if (row >= M) continue;
#pragma unroll
        for (int j = 0; j < 4; j++) {
            int col = col0 + tc + 16 * j;
            C[(size_t)row * N + col] = acc[i][j];
        }
    }
}

/* ---------- CSR build ---------- */
__global__ void deg_kernel(const int* __restrict__ ei, int* __restrict__ deg)
{
    int e = blockIdx.x * 256 + threadIdx.x;
    if (e >= E_TOT) return;
    int s, d; edge_sd(ei, e, s, d);
    atomicAdd(&deg[d], 1);
}

__global__ __launch_bounds__(1024)
void scan_kernel(const int* __restrict__ deg, int* __restrict__ rowptr,
                 int* __restrict__ cursor)
{
    __shared__ int smem[1024];
    __shared__ int carry_s;
    const int t = threadIdx.x;
    if (t == 0) carry_s = 0;
    __syncthreads();
    for (int base = 0; base < N_NODES; base += 1024) {
        int v = (base + t < N_NODES) ? deg[base + t] : 0;
        smem[t] = v;
        __syncthreads();
#pragma unroll
        for (int off = 1; off < 1024; off <<= 1) {
            int x = (t >= off) ? smem[t - off] : 0;
            __syncthreads();
            smem[t] += x;
            __syncthreads();
        }
        int excl = carry_s + smem[t] - v;
        if (base + t < N_NODES) { rowptr[base + t] = excl; cursor[base + t] = excl; }
        __syncthreads();
        if (t == 0) carry_s += smem[1023];
        __syncthreads();
    }
    if (t == 0) rowptr[N_NODES] = carry_s;
}

__global__ void scatter_kernel(const int* __restrict__ ei, int* __restrict__ cursor,
                               int* __restrict__ eid)
{
    int e = blockIdx.x * 256 + threadIdx.x;
    if (e >= E_TOT) return;
    int s, d; edge_sd(ei, e, s, d);
    int pos = atomicAdd(&cursor[d], 1);
    eid[pos] = e;
}

/* ---------- layer-1 attention dots: a_src/a_dst [N,8] (h1 is bf16) ---------- */
__global__ __launch_bounds__(64)
void att1_kernel(const unsigned short* __restrict__ h1,
                 const float* __restrict__ att_src,
                 const float* __restrict__ att_dst,
                 float* __restrict__ a_src, float* __restrict__ a_dst)
{
    const int n = blockIdx.x, h = blockIdx.y, t = threadIdx.x;
    const unsigned short* hp = h1 + (size_t)n * HC + h * CH;
    const float* as = att_src + h * CH;
    const float* ad = att_dst + h * CH;
    float v0 = bf2f(hp[t]), v1 = bf2f(hp[t + 64]);
    float s = v0 * as[t] + v1 * as[t + 64];
    float d = v0 * ad[t] + v1 * ad[t + 64];
#pragma unroll
    for (int o = 32; o > 0; o >>= 1) { s += __shfl_down(s, o); d += __shfl_down(d, o); }
    if (t == 0) { a_src[n * HEADS + h] = s; a_dst[n * HEADS + h] = d; }
}

/* ---------- layer-1 edge softmax passes ---------- */
__global__ void edge_logit1(const int* __restrict__ ei, const float* __restrict__ a_src,
                            const float* __restrict__ a_dst, float* __restrict__ e1,
                            unsigned* __restrict__ m1u)
{
    int i = blockIdx.x * 256 + threadIdx.x;
    if (i >= E_TOT * HEADS) return;
    int e = i >> 3, h = i & 7;
    int s, d; edge_sd(ei, e, s, d);
    float a = a_src[s * 8 + h] + a_dst[d * 8 + h];
    float v = a > 0.f ? a : NEG_SLOPE * a;
    e1[i] = v;
    atomicMax(&m1u[d * 8 + h], fkey(v));
}

__global__ void edge_exp1(const int* __restrict__ ei, float* __restrict__ e1,
                          const unsigned* __restrict__ m1u, float* __restrict__ denom1)
{
    int i = blockIdx.x * 256 + threadIdx.x;
    if (i >= E_TOT * HEADS) return;
    int e = i >> 3, h = i & 7;
    int s, d; edge_sd(ei, e, s, d);
    float m = fdec(m1u[d * 8 + h]);
    float ex = __expf(e1[i] - m);
    e1[i] = ex;
    atomicAdd(&denom1[d * 8 + h], ex);
}

/* ---------- layer-1 CSR aggregation, fused bias+ELU ---------- */
__global__ __launch_bounds__(256)
void agg1_csr(const int* __restrict__ rowptr, const int* __restrict__ eid,
              const int* __restrict__ ei, const unsigned short* __restrict__ h1,
              const float* __restrict__ e1, const float* __restrict__ denom1,
              const float* __restrict__ b1, float* __restrict__ out1)
{
    const int d = blockIdx.x;
    const int t = threadIdx.x;
    const int h = t >> 5;
    const float dinv = 1.f / (denom1[d * 8 + h] + 1e-16f);
    const int start = rowptr[d], end = rowptr[d + 1];
    float a0 = 0.f, a1 = 0.f, a2 = 0.f, a3 = 0.f;
    for (int i = start; i < end; i++) {
        int e = eid[i];
        int s = edge_src(ei, e);
        float alpha = e1[e * 8 + h] * dinv;
        ushort4 u = reinterpret_cast<const ushort4*>(h1 + (size_t)s * HC)[t];
        a0 += alpha * bf2f(u.x);
        a1 += alpha * bf2f(u.y);
        a2 += alpha * bf2f(u.z);
        a3 += alpha * bf2f(u.w);
    }
    float4 bb = reinterpret_cast<const float4*>(b1)[t];
    float v0 = a0 + bb.x, v1 = a1 + bb.y, v2 = a2 + bb.z, v3 = a3 + bb.w;
    v0 = v0 > 0.f ? v0 : __expf(v0) - 1.f;
    v1 = v1 > 0.f ? v1 : __expf(v1) - 1.f;
    v2 = v2 > 0.f ? v2 : __expf(v2) - 1.f;
    v3 = v3 > 0.f ? v3 : __expf(v3) - 1.f;
    reinterpret_cast<float4*>(out1 + (size_t)d * HC)[t] = make_float4(v0, v1, v2, v3);
}

/* ---------- layer-2 attention dots ---------- */
__global__ __launch_bounds__(64)
void att2_kernel(const float* __restrict__ h2, const float* __restrict__ att_src2,
                 const float* __restrict__ att_dst2,
                 float* __restrict__ a_src2, float* __restrict__ a_dst2)
{
    const int n = blockIdx.x, t = threadIdx.x;
    float v = h2[(size_t)n * OUTC + t];
    float s = v * att_src2[t];
    float d = v * att_dst2[t];
#pragma unroll
    for (int o = 32; o > 0; o >>= 1) { s += __shfl_down(s, o); d += __shfl_down(d, o); }
    if (t == 0) { a_src2[n] = s; a_dst2[n] = d; }
}

/* ---------- layer-2 edge softmax passes ---------- */
__global__ void edge_logit2(const int* __restrict__ ei, const float* __restrict__ a_src2,
                            const float* __restrict__ a_dst2, float* __restrict__ e2,
                            unsigned* __restrict__ m2u)
{
    int e = blockIdx.x * 256 + threadIdx.x;
    if (e >= E_TOT) return;
    int s, d; edge_sd(ei, e, s, d);
    float a = a_src2[s] + a_dst2[d];
    float v = a > 0.f ? a : NEG_SLOPE * a;
    e2[e] = v;
    atomicMax(&m2u[d], fkey(v));
}

__global__ void edge_exp2(const int* __restrict__ ei, float* __restrict__ e2,
                          const unsigned* __restrict__ m2u, float* __restrict__ denom2)
{
    int e = blockIdx.x * 256 + threadIdx.x;
    if (e >= E_TOT) return;
    int s, d; edge_sd(ei, e, s, d);
    float ex = __expf(e2[e] - fdec(m2u[d]));
    e2[e] = ex;
    atomicAdd(&denom2[d], ex);
}

/* ---------- layer-2 CSR aggregation fused with bias + log_softmax ---------- */
__global__ __launch_bounds__(256)
void agg2_lsm(const int* __restrict__ rowptr, const int* __restrict__ eid,
              const int* __restrict__ ei, const float* __restrict__ h2,
              const float* __restrict__ e2, const float* __restrict__ denom2,
              const float* __restrict__ b2, float* __restrict__ out)
{
    const int t = threadIdx.x;
    const int d = blockIdx.x * 4 + (t >> 6);
    const int lane = t & 63;
    const float dinv = 1.f / (denom2[d] + 1e-16f);
    const int start = rowptr[d], end = rowptr[d + 1];
    float acc = 0.f;
    for (int i = start; i < end; i++) {
        int e = eid[i];
        int s = edge_src(ei, e);
        acc += (e2[e] * dinv) * h2[(size_t)s * OUTC + lane];
    }
    float v = acc + b2[lane];
    float m = v;
#pragma unroll
    for (int o = 32; o > 0; o >>= 1) m = fmaxf(m, __shfl_xor(m, o));
    float ex = __expf(v - m);
    float ssum = ex;
#pragma unroll
    for (int o = 32; o > 0; o >>= 1) ssum += __shfl_xor(ssum, o);
    out[(size_t)d * OUTC + lane] = v - m - __logf(ssum);
}

extern "C" void kernel_launch(void* const* d_in, const int* in_sizes, int n_in,
                              void* d_out, int out_size, void* d_ws, size_t ws_size,
                              hipStream_t stream)
{
    const float* x   = (const float*)d_in[0];
    const int*   ei  = (const int*)d_in[1];
    const float* W1  = (const float*)d_in[2];
    const float* as1 = (const float*)d_in[3];
    const float* ad1 = (const float*)d_in[4];
    const float* b1  = (const float*)d_in[5];
    const float* W2  = (const float*)d_in[6];
    const float* as2 = (const float*)d_in[7];
    const float* ad2 = (const float*)d_in[8];
    const float* b2  = (const float*)d_in[9];

    char* p = (char*)d_ws;
    auto alloc = [&](size_t bytes) { char* r = p; p += (bytes + 255) & ~(size_t)255; return r; };

    /* region 0: h1 (bf16, 61.44 MB) — dead after agg1_csr; layer-2 buffers alias it */
    char* region0 = (char*)alloc((size_t)N_NODES * HC * 2);
    unsigned short* h1 = (unsigned short*)region0;

    /* region 1: out1 (fp32, 122.88 MB) — written first by agg1_csr;
       xb/W1t (16 MB, dead after gemm1_mfma which precedes agg1_csr) alias it */
    char* region1 = (char*)alloc((size_t)N_NODES * HC * 4);
    float* out1 = (float*)region1;
    unsigned short* xb  = (unsigned short*)region1;                         /* 15.36 MB */
    unsigned short* W1t = (unsigned short*)(region1 + (size_t)N_NODES * F_IN * 2 + 256);

    float*    a_src1 = (float*)alloc((size_t)N_NODES * HEADS * 4);
    float*    a_dst1 = (float*)alloc((size_t)N_NODES * HEADS * 4);
    unsigned* m1u    = (unsigned*)alloc((size_t)N_NODES * HEADS * 4);
    float*    denom1 = (float*)alloc((size_t)N_NODES * HEADS * 4);
    float*    e1     = (float*)alloc((size_t)E_TOT * HEADS * 4);
    int*      deg    = (int*)alloc((size_t)N_NODES * 4);
    int*      rowptr = (int*)alloc((size_t)(N_NODES + 1) * 4);
    int*      cursor = (int*)alloc((size_t)N_NODES * 4);
    int*      eid    = (int*)alloc((size_t)E_TOT * 4);

    /* layer-2 buffers aliased into region0 (~9.4 MB < 61.44 MB) */
    char* q = region0;
    auto alias = [&](size_t bytes) { char* r = q; q += (bytes + 255) & ~(size_t)255; return r; };
    float*    h2     = (float*)alias((size_t)N_NODES * OUTC * 4);
    float*    a_src2 = (float*)alias((size_t)N_NODES * 4);
    float*    a_dst2 = (float*)alias((size_t)N_NODES * 4);
    unsigned* m2u    = (unsigned*)alias((size_t)N_NODES * 4);
    float*    denom2 = (float*)alias((size_t)N_NODES * 4);
    float*    e2     = (float*)alias((size_t)E_TOT * 4);

    /* zero-init (ws is poisoned 0xAA each call) */
    hipMemsetAsync(deg,    0, (size_t)N_NODES * 4, stream);
    hipMemsetAsync(m1u,    0, (size_t)N_NODES * HEADS * 4, stream);
    hipMemsetAsync(denom1, 0, (size_t)N_NODES * HEADS * 4, stream);

    /* CSR build */
    deg_kernel<<<(E_TOT + 255) / 256, 256, 0, stream>>>(ei, deg);
    scan_kernel<<<1, 1024, 0, stream>>>(deg, rowptr, cursor);
    scatter_kernel<<<(E_TOT + 255) / 256, 256, 0, stream>>>(ei, cursor, eid);

    /* bf16 conversions */
    cvt_x_kernel<<<(N_NODES * F_IN / 4 + 255) / 256, 256, 0, stream>>>(x, xb);
    cvt_w1t_kernel<<<(F_IN * HC + 255) / 256, 256, 0, stream>>>(W1, W1t);

    /* layer 1 */
    gemm1_mfma<<<dim3(HC / 128, (N_NODES + 127) / 128), 256, 0, stream>>>(xb, W1t, h1, N_NODES);
    att1_kernel<<<dim3(N_NODES, HEADS), 64, 0, stream>>>(h1, as1, ad1, a_src1, a_dst1);
    {
        int nthr = E_TOT * HEADS;
        edge_logit1<<<(nthr + 255) / 256, 256, 0, stream>>>(ei, a_src1, a_dst1, e1, m1u);
        edge_exp1<<<(nthr + 255) / 256, 256, 0, stream>>>(ei, e1, m1u, denom1);
    }
    agg1_csr<<<N_NODES, 256, 0, stream>>>(rowptr, eid, ei, h1, e1, denom1, b1, out1);

    /* h1 now dead — init aliased layer-2 accumulators (stream-ordered after agg1_csr) */
    hipMemsetAsync(m2u,    0, (size_t)N_NODES * 4, stream);
    hipMemsetAsync(denom2, 0, (size_t)N_NODES * 4, stream);

    /* layer 2 */
    gemm_64x64<<<dim3(OUTC / 64, (N_NODES + 63) / 64), 256, 0, stream>>>(out1, W2, h2, N_NODES, OUTC, HC);
    att2_kernel<<<N_NODES, 64, 0, stream>>>(h2, as2, ad2, a_src2, a_dst2);
    edge_logit2<<<(E_TOT + 255) / 256, 256, 0, stream>>>(ei, a_src2, a_dst2, e2, m2u);
    edge_exp2<<<(E_TOT + 255) / 256, 256, 0, stream>>>(ei, e2, m2u, denom2);
    agg2_lsm<<<N_NODES / 4, 256, 0, stream>>>(rowptr, eid, ei, h2, e2, denom2, b2, (float*)d_out);
}

// Round 6
// 543.524 us; speedup vs baseline: 9.4173x; 1.3003x over previous
//
#include <hip/hip_runtime.h>
#include <math.h>

#define N_NODES 30000
#define F_IN 256
#define E_RAW 300000
#define E_TOT (E_RAW + N_NODES)   /* 330000: edges + self loops */
#define HEADS 8
#define CH 128
#define HC 1024                   /* HEADS*CH */
#define OUTC 64
#define NEG_SLOPE 0.2f

typedef __attribute__((ext_vector_type(8))) short bf16x8;
typedef __attribute__((ext_vector_type(4))) float f32x4;

/* ---------- helpers ---------- */
__device__ __forceinline__ float bf2f(unsigned short u) {
    return __uint_as_float(((unsigned)u) << 16);
}
__device__ __forceinline__ unsigned short f2bf(float f) {
    unsigned b = __float_as_uint(f);
    b += 0x7FFFu + ((b >> 16) & 1u);   /* round to nearest even */
    return (unsigned short)(b >> 16);
}
__device__ __forceinline__ void edge_sd(const int* __restrict__ ei, int e, int& s, int& d) {
    if (e < E_RAW) { s = ei[e]; d = ei[E_RAW + e]; }
    else           { s = e - E_RAW; d = s; }
}
__device__ __forceinline__ int edge_src(const int* __restrict__ ei, int e) {
    return (e < E_RAW) ? ei[e] : e - E_RAW;
}

/* ---------- dtype converts ---------- */
__global__ void cvt_x_kernel(const float* __restrict__ x, unsigned short* __restrict__ xb)
{
    int i = blockIdx.x * 256 + threadIdx.x;                 /* i indexes float4 groups */
    const float4 v = reinterpret_cast<const float4*>(x)[i];
    ushort4 o;
    o.x = f2bf(v.x); o.y = f2bf(v.y); o.z = f2bf(v.z); o.w = f2bf(v.w);
    reinterpret_cast<ushort4*>(xb)[i] = o;
}

/* W1 [K=256][N=1024] fp32 -> W1t [N][K] bf16 */
__global__ void cvt_w1t_kernel(const float* __restrict__ W1, unsigned short* __restrict__ W1t)
{
    int i = blockIdx.x * 256 + threadIdx.x;
    if (i >= F_IN * HC) return;
    int k = i >> 10, n = i & (HC - 1);
    W1t[n * F_IN + k] = f2bf(W1[i]);
}

/* W2 [K=1024][N=64] fp32 -> W2t [N][K] bf16 */
__global__ void cvt_w2t_kernel(const float* __restrict__ W2, unsigned short* __restrict__ W2t)
{
    int i = blockIdx.x * 256 + threadIdx.x;
    if (i >= HC * OUTC) return;
    int k = i >> 6, n = i & (OUTC - 1);
    W2t[n * HC + k] = f2bf(W2[i]);
}

/* ---------- layer-1 MFMA GEMM: C[M,1024] = xb[M,256] @ W1t[1024,256]^T ----------
   128x128 tile, BK=32, 4 waves (2x2), each wave 4x4 16x16x32 MFMA frags.   */
#define LDA 40   /* padded LDS row stride in bf16 (80 B, 16B-aligned, 2-way banks) */
__global__ __launch_bounds__(256)
void gemm1_mfma(const unsigned short* __restrict__ A,   /* [M,256] bf16 */
                const unsigned short* __restrict__ Bt,  /* [1024,256] bf16 */
                unsigned short* __restrict__ C,         /* [M,1024] bf16 */
                int M)
{
    __shared__ unsigned short Al[128 * LDA];
    __shared__ unsigned short Bl[128 * LDA];
    const int tid  = threadIdx.x;
    const int wave = tid >> 6, lane = tid & 63;
    const int quad = lane >> 4, l16 = lane & 15;
    const int wr = (wave >> 1) * 64, wc = (wave & 1) * 64;
    const int row0 = blockIdx.y * 128;
    const int col0 = blockIdx.x * 128;

    f32x4 acc[4][4];
#pragma unroll
    for (int i = 0; i < 4; i++)
#pragma unroll
        for (int j = 0; j < 4; j++) acc[i][j] = (f32x4){0.f, 0.f, 0.f, 0.f};

    for (int k0 = 0; k0 < F_IN; k0 += 32) {
#pragma unroll
        for (int p = 0; p < 2; p++) {            /* stage A: 128 rows x 32 bf16 */
            int idx = tid + 256 * p;             /* 0..511 */
            int r = idx >> 2, q = idx & 3;
            int grow = row0 + r;
            uint4 v = (grow < M)
                ? *reinterpret_cast<const uint4*>(A + (size_t)grow * F_IN + k0 + q * 8)
                : make_uint4(0u, 0u, 0u, 0u);
            *reinterpret_cast<uint4*>(Al + r * LDA + q * 8) = v;
        }
#pragma unroll
        for (int p = 0; p < 2; p++) {            /* stage B^T: 128 rows x 32 bf16 */
            int idx = tid + 256 * p;
            int r = idx >> 2, q = idx & 3;
            uint4 v = *reinterpret_cast<const uint4*>(Bt + (size_t)(col0 + r) * F_IN + k0 + q * 8);
            *reinterpret_cast<uint4*>(Bl + r * LDA + q * 8) = v;
        }
        __syncthreads();
        bf16x8 af[4], bg[4];
#pragma unroll
        for (int i = 0; i < 4; i++)
            af[i] = *reinterpret_cast<const bf16x8*>(Al + (wr + i * 16 + l16) * LDA + quad * 8);
#pragma unroll
        for (int j = 0; j < 4; j++)
            bg[j] = *reinterpret_cast<const bf16x8*>(Bl + (wc + j * 16 + l16) * LDA + quad * 8);
#pragma unroll
        for (int i = 0; i < 4; i++)
#pragma unroll
            for (int j = 0; j < 4; j++)
                acc[i][j] = __builtin_amdgcn_mfma_f32_16x16x32_bf16(af[i], bg[j], acc[i][j], 0, 0, 0);
        __syncthreads();
    }
#pragma unroll
    for (int i = 0; i < 4; i++) {
#pragma unroll
        for (int r = 0; r < 4; r++) {
            int row = row0 + wr + i * 16 + quad * 4 + r;
            if (row >= M) continue;
#pragma unroll
            for (int j = 0; j < 4; j++) {
                int col = col0 + wc + j * 16 + l16;
                C[(size_t)row * HC + col] = f2bf(acc[i][j][r]);
            }
        }
    }
}

/* ---------- layer-2 MFMA GEMM: h2[M,64] = out1[M,1024] @ W2t[64,1024]^T ----------
   128x64 tile, BK=32, 4 waves stacked (each 32 rows x 64 cols, 2x4 frags). */
__global__ __launch_bounds__(256)
void gemm2_mfma(const unsigned short* __restrict__ A,   /* [M,1024] bf16 */
                const unsigned short* __restrict__ Bt,  /* [64,1024] bf16 */
                float* __restrict__ C,                  /* [M,64] fp32 */
                int M)
{
    __shared__ unsigned short Al[128 * LDA];
    __shared__ unsigned short Bl[64 * LDA];
    const int tid  = threadIdx.x;
    const int wave = tid >> 6, lane = tid & 63;
    const int quad = lane >> 4, l16 = lane & 15;
    const int wr = wave * 32;
    const int row0 = blockIdx.x * 128;

    f32x4 acc[2][4];
#pragma unroll
    for (int i = 0; i < 2; i++)
#pragma unroll
        for (int j = 0; j < 4; j++) acc[i][j] = (f32x4){0.f, 0.f, 0.f, 0.f};

    for (int k0 = 0; k0 < HC; k0 += 32) {
#pragma unroll
        for (int p = 0; p < 2; p++) {            /* stage A: 128 rows x 32 bf16 */
            int idx = tid + 256 * p;
            int r = idx >> 2, q = idx & 3;
            int grow = row0 + r;
            uint4 v = (grow < M)
                ? *reinterpret_cast<const uint4*>(A + (size_t)grow * HC + k0 + q * 8)
                : make_uint4(0u, 0u, 0u, 0u);
            *reinterpret_cast<uint4*>(Al + r * LDA + q * 8) = v;
        }
        {                                        /* stage B^T: 64 rows x 32 bf16 */
            int r = tid >> 2, q = tid & 3;
            uint4 v = *reinterpret_cast<const uint4*>(Bt + (size_t)r * HC + k0 + q * 8);
            *reinterpret_cast<uint4*>(Bl + r * LDA + q * 8) = v;
        }
        __syncthreads();
        bf16x8 af[2], bg[4];
#pragma unroll
        for (int i = 0; i < 2; i++)
            af[i] = *reinterpret_cast<const bf16x8*>(Al + (wr + i * 16 + l16) * LDA + quad * 8);
#pragma unroll
        for (int j = 0; j < 4; j++)
            bg[j] = *reinterpret_cast<const bf16x8*>(Bl + (j * 16 + l16) * LDA + quad * 8);
#pragma unroll
        for (int i = 0; i < 2; i++)
#pragma unroll
            for (int j = 0; j < 4; j++)
                acc[i][j] = __builtin_amdgcn_mfma_f32_16x16x32_bf16(af[i], bg[j], acc[i][j], 0, 0, 0);
        __syncthreads();
    }
#pragma unroll
    for (int i = 0; i < 2; i++) {
#pragma unroll
        for (int r = 0; r < 4; r++) {
            int row = row0 + wr + i * 16 + quad * 4 + r;
            if (row >= M) continue;
#pragma unroll
            for (int j = 0; j < 4; j++) {
                int col = j * 16 + l16;
                C[(size_t)row * OUTC + col] = acc[i][j][r];
            }
        }
    }
}

/* ---------- CSR build ---------- */
__global__ void deg_kernel(const int* __restrict__ ei, int* __restrict__ deg)
{
    int e = blockIdx.x * 256 + threadIdx.x;
    if (e >= E_TOT) return;
    int s, d; edge_sd(ei, e, s, d);
    atomicAdd(&deg[d], 1);
}

__global__ __launch_bounds__(1024)
void scan_kernel(const int* __restrict__ deg, int* __restrict__ rowptr,
                 int* __restrict__ cursor)
{
    __shared__ int smem[1024];
    __shared__ int carry_s;
    const int t = threadIdx.x;
    if (t == 0) carry_s = 0;
    __syncthreads();
    for (int base = 0; base < N_NODES; base += 1024) {
        int v = (base + t < N_NODES) ? deg[base + t] : 0;
        smem[t] = v;
        __syncthreads();
#pragma unroll
        for (int off = 1; off < 1024; off <<= 1) {
            int x = (t >= off) ? smem[t - off] : 0;
            __syncthreads();
            smem[t] += x;
            __syncthreads();
        }
        int excl = carry_s + smem[t] - v;
        if (base + t < N_NODES) { rowptr[base + t] = excl; cursor[base + t] = excl; }
        __syncthreads();
        if (t == 0) carry_s += smem[1023];
        __syncthreads();
    }
    if (t == 0) rowptr[N_NODES] = carry_s;
}

__global__ void scatter_kernel(const int* __restrict__ ei, int* __restrict__ cursor,
                               int* __restrict__ eid)
{
    int e = blockIdx.x * 256 + threadIdx.x;
    if (e >= E_TOT) return;
    int s, d; edge_sd(ei, e, s, d);
    int pos = atomicAdd(&cursor[d], 1);
    eid[pos] = e;
}

/* ---------- layer-1 attention dots: a_src/a_dst [N,8] (h1 is bf16) ---------- */
__global__ __launch_bounds__(64)
void att1_kernel(const unsigned short* __restrict__ h1,
                 const float* __restrict__ att_src,
                 const float* __restrict__ att_dst,
                 float* __restrict__ a_src, float* __restrict__ a_dst)
{
    const int n = blockIdx.x, h = blockIdx.y, t = threadIdx.x;
    const unsigned short* hp = h1 + (size_t)n * HC + h * CH;
    const float* as = att_src + h * CH;
    const float* ad = att_dst + h * CH;
    float v0 = bf2f(hp[t]), v1 = bf2f(hp[t + 64]);
    float s = v0 * as[t] + v1 * as[t + 64];
    float d = v0 * ad[t] + v1 * ad[t + 64];
#pragma unroll
    for (int o = 32; o > 0; o >>= 1) { s += __shfl_down(s, o); d += __shfl_down(d, o); }
    if (t == 0) { a_src[n * HEADS + h] = s; a_dst[n * HEADS + h] = d; }
}

/* ---------- layer-1 fused exp+denom edge pass (softmax is shift-invariant;
   logits are O(3) so exp cannot overflow — max pass dropped) ---------- */
__global__ void edge_sumexp1(const int* __restrict__ ei, const float* __restrict__ a_src,
                             const float* __restrict__ a_dst, float* __restrict__ e1,
                             float* __restrict__ denom1)
{
    int i = blockIdx.x * 256 + threadIdx.x;
    if (i >= E_TOT * HEADS) return;
    int e = i >> 3, h = i & 7;
    int s, d; edge_sd(ei, e, s, d);
    float a = a_src[s * 8 + h] + a_dst[d * 8 + h];
    float v = a > 0.f ? a : NEG_SLOPE * a;
    float ex = __expf(v);
    e1[i] = ex;
    atomicAdd(&denom1[d * 8 + h], ex);
}

/* ---------- layer-1 CSR aggregation, fused bias+ELU, bf16 out ---------- */
__global__ __launch_bounds__(256)
void agg1_csr(const int* __restrict__ rowptr, const int* __restrict__ eid,
              const int* __restrict__ ei, const unsigned short* __restrict__ h1,
              const float* __restrict__ e1, const float* __restrict__ denom1,
              const float* __restrict__ b1, unsigned short* __restrict__ out1)
{
    const int d = blockIdx.x;
    const int t = threadIdx.x;
    const int h = t >> 5;
    const float dinv = 1.f / (denom1[d * 8 + h] + 1e-16f);
    const int start = rowptr[d], end = rowptr[d + 1];
    float a0 = 0.f, a1 = 0.f, a2 = 0.f, a3 = 0.f;
    for (int i = start; i < end; i++) {
        int e = eid[i];
        int s = edge_src(ei, e);
        float alpha = e1[e * 8 + h] * dinv;
        ushort4 u = reinterpret_cast<const ushort4*>(h1 + (size_t)s * HC)[t];
        a0 += alpha * bf2f(u.x);
        a1 += alpha * bf2f(u.y);
        a2 += alpha * bf2f(u.z);
        a3 += alpha * bf2f(u.w);
    }
    float4 bb = reinterpret_cast<const float4*>(b1)[t];
    float v0 = a0 + bb.x, v1 = a1 + bb.y, v2 = a2 + bb.z, v3 = a3 + bb.w;
    v0 = v0 > 0.f ? v0 : __expf(v0) - 1.f;
    v1 = v1 > 0.f ? v1 : __expf(v1) - 1.f;
    v2 = v2 > 0.f ? v2 : __expf(v2) - 1.f;
    v3 = v3 > 0.f ? v3 : __expf(v3) - 1.f;
    ushort4 o;
    o.x = f2bf(v0); o.y = f2bf(v1); o.z = f2bf(v2); o.w = f2bf(v3);
    reinterpret_cast<ushort4*>(out1 + (size_t)d * HC)[t] = o;
}

/* ---------- layer-2 attention dots ---------- */
__global__ __launch_bounds__(64)
void att2_kernel(const float* __restrict__ h2, const float* __restrict__ att_src2,
                 const float* __restrict__ att_dst2,
                 float* __restrict__ a_src2, float* __restrict__ a_dst2)
{
    const int n = blockIdx.x, t = threadIdx.x;
    float v = h2[(size_t)n * OUTC + t];
    float s = v * att_src2[t];
    float d = v * att_dst2[t];
#pragma unroll
    for (int o = 32; o > 0; o >>= 1) { s += __shfl_down(s, o); d += __shfl_down(d, o); }
    if (t == 0) { a_src2[n] = s; a_dst2[n] = d; }
}

/* ---------- layer-2 fused exp+denom edge pass ---------- */
__global__ void edge_sumexp2(const int* __restrict__ ei, const float* __restrict__ a_src2,
                             const float* __restrict__ a_dst2, float* __restrict__ e2,
                             float* __restrict__ denom2)
{
    int e = blockIdx.x * 256 + threadIdx.x;
    if (e >= E_TOT) return;
    int s, d; edge_sd(ei, e, s, d);
    float a = a_src2[s] + a_dst2[d];
    float v = a > 0.f ? a : NEG_SLOPE * a;
    float ex = __expf(v);
    e2[e] = ex;
    atomicAdd(&denom2[d], ex);
}

/* ---------- layer-2 CSR aggregation fused with bias + log_softmax ---------- */
__global__ __launch_bounds__(256)
void agg2_lsm(const int* __restrict__ rowptr, const int* __restrict__ eid,
              const int* __restrict__ ei, const float* __restrict__ h2,
              const float* __restrict__ e2, const float* __restrict__ denom2,
              const float* __restrict__ b2, float* __restrict__ out)
{
    const int t = threadIdx.x;
    const int d = blockIdx.x * 4 + (t >> 6);
    const int lane = t & 63;
    const float dinv = 1.f / (denom2[d] + 1e-16f);
    const int start = rowptr[d], end = rowptr[d + 1];
    float acc = 0.f;
    for (int i = start; i < end; i++) {
        int e = eid[i];
        int s = edge_src(ei, e);
        acc += (e2[e] * dinv) * h2[(size_t)s * OUTC + lane];
    }
    float v = acc + b2[lane];
    float m = v;
#pragma unroll
    for (int o = 32; o > 0; o >>= 1) m = fmaxf(m, __shfl_xor(m, o));
    float ex = __expf(v - m);
    float ssum = ex;
#pragma unroll
    for (int o = 32; o > 0; o >>= 1) ssum += __shfl_xor(ssum, o);
    out[(size_t)d * OUTC + lane] = v - m - __logf(ssum);
}

extern "C" void kernel_launch(void* const* d_in, const int* in_sizes, int n_in,
                              void* d_out, int out_size, void* d_ws, size_t ws_size,
                              hipStream_t stream)
{
    const float* x   = (const float*)d_in[0];
    const int*   ei  = (const int*)d_in[1];
    const float* W1  = (const float*)d_in[2];
    const float* as1 = (const float*)d_in[3];
    const float* ad1 = (const float*)d_in[4];
    const float* b1  = (const float*)d_in[5];
    const float* W2  = (const float*)d_in[6];
    const float* as2 = (const float*)d_in[7];
    const float* ad2 = (const float*)d_in[8];
    const float* b2  = (const float*)d_in[9];

    char* p = (char*)d_ws;
    auto alloc = [&](size_t bytes) { char* r = p; p += (bytes + 255) & ~(size_t)255; return r; };

    /* region 0: h1 (bf16, 61.44 MB) — dead after agg1_csr; layer-2 buffers alias it */
    char* region0 = (char*)alloc((size_t)N_NODES * HC * 2);
    unsigned short* h1 = (unsigned short*)region0;

    /* region 1: out1 (bf16, 61.44 MB) — written by agg1_csr;
       xb/W1t (15.9 MB, dead after gemm1_mfma which precedes agg1_csr) alias it */
    char* region1 = (char*)alloc((size_t)N_NODES * HC * 2);
    unsigned short* out1 = (unsigned short*)region1;
    unsigned short* xb   = (unsigned short*)region1;                         /* 15.36 MB */
    unsigned short* W1t  = (unsigned short*)(region1 + (size_t)N_NODES * F_IN * 2 + 256);

    /* W2t lives OUTSIDE region1: gemm2 reads it after agg1_csr overwrites out1 */
    unsigned short* W2t = (unsigned short*)alloc((size_t)OUTC * HC * 2);

    float*    a_src1 = (float*)alloc((size_t)N_NODES * HEADS * 4);
    float*    a_dst1 = (float*)alloc((size_t)N_NODES * HEADS * 4);
    float*    denom1 = (float*)alloc((size_t)N_NODES * HEADS * 4);
    float*    e1     = (float*)alloc((size_t)E_TOT * HEADS * 4);
    int*      deg    = (int*)alloc((size_t)N_NODES * 4);
    int*      rowptr = (int*)alloc((size_t)(N_NODES + 1) * 4);
    int*      cursor = (int*)alloc((size_t)N_NODES * 4);
    int*      eid    = (int*)alloc((size_t)E_TOT * 4);

    /* layer-2 buffers aliased into region0 (~9.4 MB < 61.44 MB) */
    char* q = region0;
    auto alias = [&](size_t bytes) { char* r = q; q += (bytes + 255) & ~(size_t)255; return r; };
    float*    h2     = (float*)alias((size_t)N_NODES * OUTC * 4);
    float*    a_src2 = (float*)alias((size_t)N_NODES * 4);
    float*    a_dst2 = (float*)alias((size_t)N_NODES * 4);
    float*    denom2 = (float*)alias((size_t)N_NODES * 4);
    float*    e2     = (float*)alias((size_t)E_TOT * 4);

    /* zero-init (ws is poisoned 0xAA each call) */
    hipMemsetAsync(deg,    0, (size_t)N_NODES * 4, stream);
    hipMemsetAsync(denom1, 0, (size_t)N_NODES * HEADS * 4, stream);

    /* CSR build */
    deg_kernel<<<(E_TOT + 255) / 256, 256, 0, stream>>>(ei, deg);
    scan_kernel<<<1, 1024, 0, stream>>>(deg, rowptr, cursor);
    scatter_kernel<<<(E_TOT + 255) / 256, 256, 0, stream>>>(ei, cursor, eid);

    /* bf16 conversions */
    cvt_x_kernel<<<(N_NODES * F_IN / 4 + 255) / 256, 256, 0, stream>>>(x, xb);
    cvt_w1t_kernel<<<(F_IN * HC + 255) / 256, 256, 0, stream>>>(W1, W1t);
    cvt_w2t_kernel<<<(HC * OUTC + 255) / 256, 256, 0, stream>>>(W2, W2t);

    /* layer 1 */
    gemm1_mfma<<<dim3(HC / 128, (N_NODES + 127) / 128), 256, 0, stream>>>(xb, W1t, h1, N_NODES);
    att1_kernel<<<dim3(N_NODES, HEADS), 64, 0, stream>>>(h1, as1, ad1, a_src1, a_dst1);
    edge_sumexp1<<<(E_TOT * HEADS + 255) / 256, 256, 0, stream>>>(ei, a_src1, a_dst1, e1, denom1);
    agg1_csr<<<N_NODES, 256, 0, stream>>>(rowptr, eid, ei, h1, e1, denom1, b1, out1);

    /* h1 now dead — init aliased layer-2 accumulators (stream-ordered after agg1_csr) */
    hipMemsetAsync(denom2, 0, (size_t)N_NODES * 4, stream);

    /* layer 2 */
    gemm2_mfma<<<(N_NODES + 127) / 128, 256, 0, stream>>>(out1, W2t, h2, N_NODES);
    att2_kernel<<<N_NODES, 64, 0, stream>>>(h2, as2, ad2, a_src2, a_dst2);
    edge_sumexp2<<<(E_TOT + 255) / 256, 256, 0, stream>>>(ei, a_src2, a_dst2, e2, denom2);
    agg2_lsm<<<N_NODES / 4, 256, 0, stream>>>(rowptr, eid, ei, h2, e2, denom2, b2, (float*)d_out);
}

// Round 7
// 420.524 us; speedup vs baseline: 12.1718x; 1.2925x over previous
//
#include <hip/hip_runtime.h>
#include <math.h>

#define N_NODES 30000
#define F_IN 256
#define E_RAW 300000
#define E_TOT (E_RAW + N_NODES)   /* 330000: edges + self loops */
#define HEADS 8
#define CH 128
#define HC 1024                   /* HEADS*CH */
#define OUTC 64
#define NEG_SLOPE 0.2f

typedef __attribute__((ext_vector_type(8))) short bf16x8;
typedef __attribute__((ext_vector_type(4))) float f32x4;

/* ---------- helpers ---------- */
__device__ __forceinline__ float bf2f(unsigned short u) {
    return __uint_as_float(((unsigned)u) << 16);
}
__device__ __forceinline__ unsigned short f2bf(float f) {
    unsigned b = __float_as_uint(f);
    b += 0x7FFFu + ((b >> 16) & 1u);   /* round to nearest even */
    return (unsigned short)(b >> 16);
}
__device__ __forceinline__ void edge_sd(const int* __restrict__ ei, int e, int& s, int& d) {
    if (e < E_RAW) { s = ei[e]; d = ei[E_RAW + e]; }
    else           { s = e - E_RAW; d = s; }
}

/* ---------- dtype converts ---------- */
__global__ void cvt_x_kernel(const float* __restrict__ x, unsigned short* __restrict__ xb)
{
    int i = blockIdx.x * 256 + threadIdx.x;
    const float4 v = reinterpret_cast<const float4*>(x)[i];
    ushort4 o;
    o.x = f2bf(v.x); o.y = f2bf(v.y); o.z = f2bf(v.z); o.w = f2bf(v.w);
    reinterpret_cast<ushort4*>(xb)[i] = o;
}

__global__ void cvt_w1t_kernel(const float* __restrict__ W1, unsigned short* __restrict__ W1t)
{
    int i = blockIdx.x * 256 + threadIdx.x;
    if (i >= F_IN * HC) return;
    int k = i >> 10, n = i & (HC - 1);
    W1t[n * F_IN + k] = f2bf(W1[i]);
}

__global__ void cvt_w2t_kernel(const float* __restrict__ W2, unsigned short* __restrict__ W2t)
{
    int i = blockIdx.x * 256 + threadIdx.x;
    if (i >= HC * OUTC) return;
    int k = i >> 6, n = i & (OUTC - 1);
    W2t[n * HC + k] = f2bf(W2[i]);
}

/* ---------- layer-1 MFMA GEMM: C[M,1024] = xb[M,256] @ W1t[1024,256]^T ---------- */
#define LDA 40
__global__ __launch_bounds__(256)
void gemm1_mfma(const unsigned short* __restrict__ A,
                const unsigned short* __restrict__ Bt,
                unsigned short* __restrict__ C, int M)
{
    __shared__ unsigned short Al[128 * LDA];
    __shared__ unsigned short Bl[128 * LDA];
    const int tid  = threadIdx.x;
    const int wave = tid >> 6, lane = tid & 63;
    const int quad = lane >> 4, l16 = lane & 15;
    const int wr = (wave >> 1) * 64, wc = (wave & 1) * 64;
    const int row0 = blockIdx.y * 128;
    const int col0 = blockIdx.x * 128;

    f32x4 acc[4][4];
#pragma unroll
    for (int i = 0; i < 4; i++)
#pragma unroll
        for (int j = 0; j < 4; j++) acc[i][j] = (f32x4){0.f, 0.f, 0.f, 0.f};

    for (int k0 = 0; k0 < F_IN; k0 += 32) {
#pragma unroll
        for (int p = 0; p < 2; p++) {
            int idx = tid + 256 * p;
            int r = idx >> 2, q = idx & 3;
            int grow = row0 + r;
            uint4 v = (grow < M)
                ? *reinterpret_cast<const uint4*>(A + (size_t)grow * F_IN + k0 + q * 8)
                : make_uint4(0u, 0u, 0u, 0u);
            *reinterpret_cast<uint4*>(Al + r * LDA + q * 8) = v;
        }
#pragma unroll
        for (int p = 0; p < 2; p++) {
            int idx = tid + 256 * p;
            int r = idx >> 2, q = idx & 3;
            uint4 v = *reinterpret_cast<const uint4*>(Bt + (size_t)(col0 + r) * F_IN + k0 + q * 8);
            *reinterpret_cast<uint4*>(Bl + r * LDA + q * 8) = v;
        }
        __syncthreads();
        bf16x8 af[4], bg[4];
#pragma unroll
        for (int i = 0; i < 4; i++)
            af[i] = *reinterpret_cast<const bf16x8*>(Al + (wr + i * 16 + l16) * LDA + quad * 8);
#pragma unroll
        for (int j = 0; j < 4; j++)
            bg[j] = *reinterpret_cast<const bf16x8*>(Bl + (wc + j * 16 + l16) * LDA + quad * 8);
#pragma unroll
        for (int i = 0; i < 4; i++)
#pragma unroll
            for (int j = 0; j < 4; j++)
                acc[i][j] = __builtin_amdgcn_mfma_f32_16x16x32_bf16(af[i], bg[j], acc[i][j], 0, 0, 0);
        __syncthreads();
    }
#pragma unroll
    for (int i = 0; i < 4; i++) {
#pragma unroll
        for (int r = 0; r < 4; r++) {
            int row = row0 + wr + i * 16 + quad * 4 + r;
            if (row >= M) continue;
#pragma unroll
            for (int j = 0; j < 4; j++) {
                int col = col0 + wc + j * 16 + l16;
                C[(size_t)row * HC + col] = f2bf(acc[i][j][r]);
            }
        }
    }
}

/* ---------- layer-2 MFMA GEMM: h2[M,64] = out1[M,1024] @ W2t[64,1024]^T ---------- */
__global__ __launch_bounds__(256)
void gemm2_mfma(const unsigned short* __restrict__ A,
                const unsigned short* __restrict__ Bt,
                float* __restrict__ C, int M)
{
    __shared__ unsigned short Al[128 * LDA];
    __shared__ unsigned short Bl[64 * LDA];
    const int tid  = threadIdx.x;
    const int wave = tid >> 6, lane = tid & 63;
    const int quad = lane >> 4, l16 = lane & 15;
    const int wr = wave * 32;
    const int row0 = blockIdx.x * 128;

    f32x4 acc[2][4];
#pragma unroll
    for (int i = 0; i < 2; i++)
#pragma unroll
        for (int j = 0; j < 4; j++) acc[i][j] = (f32x4){0.f, 0.f, 0.f, 0.f};

    for (int k0 = 0; k0 < HC; k0 += 32) {
#pragma unroll
        for (int p = 0; p < 2; p++) {
            int idx = tid + 256 * p;
            int r = idx >> 2, q = idx & 3;
            int grow = row0 + r;
            uint4 v = (grow < M)
                ? *reinterpret_cast<const uint4*>(A + (size_t)grow * HC + k0 + q * 8)
                : make_uint4(0u, 0u, 0u, 0u);
            *reinterpret_cast<uint4*>(Al + r * LDA + q * 8) = v;
        }
        {
            int r = tid >> 2, q = tid & 3;
            uint4 v = *reinterpret_cast<const uint4*>(Bt + (size_t)r * HC + k0 + q * 8);
            *reinterpret_cast<uint4*>(Bl + r * LDA + q * 8) = v;
        }
        __syncthreads();
        bf16x8 af[2], bg[4];
#pragma unroll
        for (int i = 0; i < 2; i++)
            af[i] = *reinterpret_cast<const bf16x8*>(Al + (wr + i * 16 + l16) * LDA + quad * 8);
#pragma unroll
        for (int j = 0; j < 4; j++)
            bg[j] = *reinterpret_cast<const bf16x8*>(Bl + (j * 16 + l16) * LDA + quad * 8);
#pragma unroll
        for (int i = 0; i < 2; i++)
#pragma unroll
            for (int j = 0; j < 4; j++)
                acc[i][j] = __builtin_amdgcn_mfma_f32_16x16x32_bf16(af[i], bg[j], acc[i][j], 0, 0, 0);
        __syncthreads();
    }
#pragma unroll
    for (int i = 0; i < 2; i++) {
#pragma unroll
        for (int r = 0; r < 4; r++) {
            int row = row0 + wr + i * 16 + quad * 4 + r;
            if (row >= M) continue;
#pragma unroll
            for (int j = 0; j < 4; j++) {
                int col = j * 16 + l16;
                C[(size_t)row * OUTC + col] = acc[i][j][r];
            }
        }
    }
}

/* ---------- CSR build ---------- */
__global__ void deg_kernel(const int* __restrict__ ei, int* __restrict__ deg)
{
    int e = blockIdx.x * 256 + threadIdx.x;
    if (e >= E_TOT) return;
    int s, d; edge_sd(ei, e, s, d);
    atomicAdd(&deg[d], 1);
}

__global__ __launch_bounds__(1024)
void scan_kernel(const int* __restrict__ deg, int* __restrict__ rowptr,
                 int* __restrict__ cursor)
{
    __shared__ int smem[1024];
    __shared__ int carry_s;
    const int t = threadIdx.x;
    if (t == 0) carry_s = 0;
    __syncthreads();
    for (int base = 0; base < N_NODES; base += 1024) {
        int v = (base + t < N_NODES) ? deg[base + t] : 0;
        smem[t] = v;
        __syncthreads();
#pragma unroll
        for (int off = 1; off < 1024; off <<= 1) {
            int x = (t >= off) ? smem[t - off] : 0;
            __syncthreads();
            smem[t] += x;
            __syncthreads();
        }
        int excl = carry_s + smem[t] - v;
        if (base + t < N_NODES) { rowptr[base + t] = excl; cursor[base + t] = excl; }
        __syncthreads();
        if (t == 0) carry_s += smem[1023];
        __syncthreads();
    }
    if (t == 0) rowptr[N_NODES] = carry_s;
}

/* writes per-slot src and the edge->slot inverse permutation */
__global__ void scatter_kernel(const int* __restrict__ ei, int* __restrict__ cursor,
                               int* __restrict__ csr_src, int* __restrict__ csr_pos)
{
    int e = blockIdx.x * 256 + threadIdx.x;
    if (e >= E_TOT) return;
    int s, d; edge_sd(ei, e, s, d);
    int pos = atomicAdd(&cursor[d], 1);
    csr_src[pos] = s;
    csr_pos[e] = pos;
}

/* ---------- layer-1 attention dots: one block per node, all heads ---------- */
__global__ __launch_bounds__(256)
void att1_kernel(const unsigned short* __restrict__ h1,
                 const float* __restrict__ att_src,
                 const float* __restrict__ att_dst,
                 float* __restrict__ a_src, float* __restrict__ a_dst)
{
    const int n = blockIdx.x, t = threadIdx.x, h = t >> 5;
    ushort4 u = reinterpret_cast<const ushort4*>(h1 + (size_t)n * HC)[t];
    float4 as = reinterpret_cast<const float4*>(att_src)[t];
    float4 ad = reinterpret_cast<const float4*>(att_dst)[t];
    float s = bf2f(u.x) * as.x + bf2f(u.y) * as.y + bf2f(u.z) * as.z + bf2f(u.w) * as.w;
    float d = bf2f(u.x) * ad.x + bf2f(u.y) * ad.y + bf2f(u.z) * ad.z + bf2f(u.w) * ad.w;
#pragma unroll
    for (int o = 16; o > 0; o >>= 1) { s += __shfl_xor(s, o); d += __shfl_xor(d, o); }
    if ((t & 31) == 0) { a_src[n * HEADS + h] = s; a_dst[n * HEADS + h] = d; }
}

/* ---------- layer-1 edge pass: exp(leaky) written in CSR slot order ---------- */
__global__ void edge_sumexp1(const int* __restrict__ ei, const int* __restrict__ csr_pos,
                             const float* __restrict__ a_src, const float* __restrict__ a_dst,
                             float* __restrict__ e1s)
{
    int i = blockIdx.x * 256 + threadIdx.x;
    if (i >= E_TOT * HEADS) return;
    int e = i >> 3, h = i & 7;
    int s, d; edge_sd(ei, e, s, d);
    float a = a_src[s * 8 + h] + a_dst[d * 8 + h];
    float v = a > 0.f ? a : NEG_SLOPE * a;
    e1s[(size_t)csr_pos[e] * 8 + h] = __expf(v);
}

/* ---------- layer-1 CSR aggregation: inline denom, pipelined gather,
   fused bias+ELU, bf16 out ---------- */
__global__ __launch_bounds__(256)
void agg1_csr(const int* __restrict__ rowptr, const int* __restrict__ csr_src,
              const unsigned short* __restrict__ h1, const float* __restrict__ e1s,
              const float* __restrict__ b1, unsigned short* __restrict__ out1)
{
    const int d = blockIdx.x;
    const int t = threadIdx.x;
    const int h = t >> 5;
    const int start = rowptr[d], end = rowptr[d + 1];

    /* phase 1: denominator per head (self-loop guarantees deg >= 1) */
    float part = 0.f;
    for (int i = start + (t & 31); i < end; i += 32)
        part += e1s[i * 8 + h];
#pragma unroll
    for (int o = 16; o > 0; o >>= 1) part += __shfl_xor(part, o);
    __shared__ float dinv_s[8];
    if ((t & 31) == 0) dinv_s[h] = 1.f / (part + 1e-16f);
    __syncthreads();
    const float dinv = dinv_s[h];

    /* phase 2: pipelined gather */
    const ushort4* __restrict__ h1v = reinterpret_cast<const ushort4*>(h1);
    float a0 = 0.f, a1 = 0.f, a2 = 0.f, a3 = 0.f;
    int s_cur = csr_src[start];
    float w_cur = e1s[start * 8 + h];
    for (int i = start; i < end - 1; i++) {
        int s_nxt = csr_src[i + 1];
        float w_nxt = e1s[(i + 1) * 8 + h];
        ushort4 u = h1v[(size_t)s_cur * (HC / 4) + t];
        float alpha = w_cur * dinv;
        a0 += alpha * bf2f(u.x);
        a1 += alpha * bf2f(u.y);
        a2 += alpha * bf2f(u.z);
        a3 += alpha * bf2f(u.w);
        s_cur = s_nxt; w_cur = w_nxt;
    }
    {
        ushort4 u = h1v[(size_t)s_cur * (HC / 4) + t];
        float alpha = w_cur * dinv;
        a0 += alpha * bf2f(u.x);
        a1 += alpha * bf2f(u.y);
        a2 += alpha * bf2f(u.z);
        a3 += alpha * bf2f(u.w);
    }
    float4 bb = reinterpret_cast<const float4*>(b1)[t];
    float v0 = a0 + bb.x, v1 = a1 + bb.y, v2 = a2 + bb.z, v3 = a3 + bb.w;
    v0 = v0 > 0.f ? v0 : __expf(v0) - 1.f;
    v1 = v1 > 0.f ? v1 : __expf(v1) - 1.f;
    v2 = v2 > 0.f ? v2 : __expf(v2) - 1.f;
    v3 = v3 > 0.f ? v3 : __expf(v3) - 1.f;
    ushort4 o;
    o.x = f2bf(v0); o.y = f2bf(v1); o.z = f2bf(v2); o.w = f2bf(v3);
    reinterpret_cast<ushort4*>(out1 + (size_t)d * HC)[t] = o;
}

/* ---------- layer-2 attention dots ---------- */
__global__ __launch_bounds__(64)
void att2_kernel(const float* __restrict__ h2, const float* __restrict__ att_src2,
                 const float* __restrict__ att_dst2,
                 float* __restrict__ a_src2, float* __restrict__ a_dst2)
{
    const int n = blockIdx.x, t = threadIdx.x;
    float v = h2[(size_t)n * OUTC + t];
    float s = v * att_src2[t];
    float d = v * att_dst2[t];
#pragma unroll
    for (int o = 32; o > 0; o >>= 1) { s += __shfl_down(s, o); d += __shfl_down(d, o); }
    if (t == 0) { a_src2[n] = s; a_dst2[n] = d; }
}

/* ---------- layer-2 edge pass: exp in CSR slot order ---------- */
__global__ void edge_sumexp2(const int* __restrict__ ei, const int* __restrict__ csr_pos,
                             const float* __restrict__ a_src2, const float* __restrict__ a_dst2,
                             float* __restrict__ e2s)
{
    int e = blockIdx.x * 256 + threadIdx.x;
    if (e >= E_TOT) return;
    int s, d; edge_sd(ei, e, s, d);
    float a = a_src2[s] + a_dst2[d];
    float v = a > 0.f ? a : NEG_SLOPE * a;
    e2s[csr_pos[e]] = __expf(v);
}

/* ---------- layer-2 CSR aggregation: inline denom, fused bias+log_softmax ---------- */
__global__ __launch_bounds__(256)
void agg2_lsm(const int* __restrict__ rowptr, const int* __restrict__ csr_src,
              const float* __restrict__ h2, const float* __restrict__ e2s,
              const float* __restrict__ b2, float* __restrict__ out)
{
    const int t = threadIdx.x;
    const int d = blockIdx.x * 4 + (t >> 6);
    const int lane = t & 63;
    const int start = rowptr[d], end = rowptr[d + 1];

    /* denom: butterfly over the full wave */
    float part = 0.f;
    for (int i = start + lane; i < end; i += 64) part += e2s[i];
#pragma unroll
    for (int o = 32; o > 0; o >>= 1) part += __shfl_xor(part, o);
    const float dinv = 1.f / (part + 1e-16f);

    /* pipelined gather */
    float acc = 0.f;
    int s_cur = csr_src[start];
    float w_cur = e2s[start];
    for (int i = start; i < end - 1; i++) {
        int s_nxt = csr_src[i + 1];
        float w_nxt = e2s[i + 1];
        acc += (w_cur * dinv) * h2[(size_t)s_cur * OUTC + lane];
        s_cur = s_nxt; w_cur = w_nxt;
    }
    acc += (w_cur * dinv) * h2[(size_t)s_cur * OUTC + lane];

    float v = acc + b2[lane];
    float m = v;
#pragma unroll
    for (int o = 32; o > 0; o >>= 1) m = fmaxf(m, __shfl_xor(m, o));
    float ex = __expf(v - m);
    float ssum = ex;
#pragma unroll
    for (int o = 32; o > 0; o >>= 1) ssum += __shfl_xor(ssum, o);
    out[(size_t)d * OUTC + lane] = v - m - __logf(ssum);
}

extern "C" void kernel_launch(void* const* d_in, const int* in_sizes, int n_in,
                              void* d_out, int out_size, void* d_ws, size_t ws_size,
                              hipStream_t stream)
{
    const float* x   = (const float*)d_in[0];
    const int*   ei  = (const int*)d_in[1];
    const float* W1  = (const float*)d_in[2];
    const float* as1 = (const float*)d_in[3];
    const float* ad1 = (const float*)d_in[4];
    const float* b1  = (const float*)d_in[5];
    const float* W2  = (const float*)d_in[6];
    const float* as2 = (const float*)d_in[7];
    const float* ad2 = (const float*)d_in[8];
    const float* b2  = (const float*)d_in[9];

    char* p = (char*)d_ws;
    auto alloc = [&](size_t bytes) { char* r = p; p += (bytes + 255) & ~(size_t)255; return r; };

    /* region 0: h1 (bf16, 61.44 MB) — dead after agg1_csr; layer-2 buffers alias it */
    char* region0 = (char*)alloc((size_t)N_NODES * HC * 2);
    unsigned short* h1 = (unsigned short*)region0;

    /* region 1: out1 (bf16, 61.44 MB); xb/W1t (dead after gemm1_mfma) alias it */
    char* region1 = (char*)alloc((size_t)N_NODES * HC * 2);
    unsigned short* out1 = (unsigned short*)region1;
    unsigned short* xb   = (unsigned short*)region1;
    unsigned short* W1t  = (unsigned short*)(region1 + (size_t)N_NODES * F_IN * 2 + 256);

    unsigned short* W2t = (unsigned short*)alloc((size_t)OUTC * HC * 2);

    float* a_src1  = (float*)alloc((size_t)N_NODES * HEADS * 4);
    float* a_dst1  = (float*)alloc((size_t)N_NODES * HEADS * 4);
    float* e1s     = (float*)alloc((size_t)E_TOT * HEADS * 4);
    int*   deg     = (int*)alloc((size_t)N_NODES * 4);
    int*   rowptr  = (int*)alloc((size_t)(N_NODES + 1) * 4);
    int*   cursor  = (int*)alloc((size_t)N_NODES * 4);
    int*   csr_src = (int*)alloc((size_t)E_TOT * 4);
    int*   csr_pos = (int*)alloc((size_t)E_TOT * 4);

    /* layer-2 buffers aliased into region0 (~9.3 MB < 61.44 MB) */
    char* q = region0;
    auto alias = [&](size_t bytes) { char* r = q; q += (bytes + 255) & ~(size_t)255; return r; };
    float* h2      = (float*)alias((size_t)N_NODES * OUTC * 4);
    float* a_src2  = (float*)alias((size_t)N_NODES * 4);
    float* a_dst2  = (float*)alias((size_t)N_NODES * 4);
    float* e2s     = (float*)alias((size_t)E_TOT * 4);

    hipMemsetAsync(deg, 0, (size_t)N_NODES * 4, stream);

    /* CSR build */
    deg_kernel<<<(E_TOT + 255) / 256, 256, 0, stream>>>(ei, deg);
    scan_kernel<<<1, 1024, 0, stream>>>(deg, rowptr, cursor);
    scatter_kernel<<<(E_TOT + 255) / 256, 256, 0, stream>>>(ei, cursor, csr_src, csr_pos);

    /* bf16 conversions */
    cvt_x_kernel<<<(N_NODES * F_IN / 4 + 255) / 256, 256, 0, stream>>>(x, xb);
    cvt_w1t_kernel<<<(F_IN * HC + 255) / 256, 256, 0, stream>>>(W1, W1t);
    cvt_w2t_kernel<<<(HC * OUTC + 255) / 256, 256, 0, stream>>>(W2, W2t);

    /* layer 1 */
    gemm1_mfma<<<dim3(HC / 128, (N_NODES + 127) / 128), 256, 0, stream>>>(xb, W1t, h1, N_NODES);
    att1_kernel<<<N_NODES, 256, 0, stream>>>(h1, as1, ad1, a_src1, a_dst1);
    edge_sumexp1<<<(E_TOT * HEADS + 255) / 256, 256, 0, stream>>>(ei, csr_pos, a_src1, a_dst1, e1s);
    agg1_csr<<<N_NODES, 256, 0, stream>>>(rowptr, csr_src, h1, e1s, b1, out1);

    /* layer 2 (h1 dead; aliased buffers now safe, stream-ordered) */
    gemm2_mfma<<<(N_NODES + 127) / 128, 256, 0, stream>>>(out1, W2t, h2, N_NODES);
    att2_kernel<<<N_NODES, 64, 0, stream>>>(h2, as2, ad2, a_src2, a_dst2);
    edge_sumexp2<<<(E_TOT + 255) / 256, 256, 0, stream>>>(ei, csr_pos, a_src2, a_dst2, e2s);
    agg2_lsm<<<N_NODES / 4, 256, 0, stream>>>(rowptr, csr_src, h2, e2s, b2, (float*)d_out);
}

// Round 8
// 397.057 us; speedup vs baseline: 12.8912x; 1.0591x over previous
//
#include <hip/hip_runtime.h>
#include <math.h>

#define N_NODES 30000
#define F_IN 256
#define E_RAW 300000
#define E_TOT (E_RAW + N_NODES)   /* 330000: edges + self loops */
#define HEADS 8
#define CH 128
#define HC 1024                   /* HEADS*CH */
#define OUTC 64
#define NEG_SLOPE 0.2f
#define CAP 64                    /* edges per LDS chunk in fused agg kernels */

typedef __attribute__((ext_vector_type(8))) short bf16x8;
typedef __attribute__((ext_vector_type(4))) float f32x4;

/* ---------- helpers ---------- */
__device__ __forceinline__ float bf2f(unsigned short u) {
    return __uint_as_float(((unsigned)u) << 16);
}
__device__ __forceinline__ unsigned short f2bf(float f) {
    unsigned b = __float_as_uint(f);
    b += 0x7FFFu + ((b >> 16) & 1u);   /* round to nearest even */
    return (unsigned short)(b >> 16);
}
__device__ __forceinline__ void edge_sd(const int* __restrict__ ei, int e, int& s, int& d) {
    if (e < E_RAW) { s = ei[e]; d = ei[E_RAW + e]; }
    else           { s = e - E_RAW; d = s; }
}

/* ---------- dtype converts ---------- */
__global__ void cvt_x_kernel(const float* __restrict__ x, unsigned short* __restrict__ xb)
{
    int i = blockIdx.x * 256 + threadIdx.x;
    const float4 v = reinterpret_cast<const float4*>(x)[i];
    ushort4 o;
    o.x = f2bf(v.x); o.y = f2bf(v.y); o.z = f2bf(v.z); o.w = f2bf(v.w);
    reinterpret_cast<ushort4*>(xb)[i] = o;
}

__global__ void cvt_w1t_kernel(const float* __restrict__ W1, unsigned short* __restrict__ W1t)
{
    int i = blockIdx.x * 256 + threadIdx.x;
    if (i >= F_IN * HC) return;
    int k = i >> 10, n = i & (HC - 1);
    W1t[n * F_IN + k] = f2bf(W1[i]);
}

__global__ void cvt_w2t_kernel(const float* __restrict__ W2, unsigned short* __restrict__ W2t)
{
    int i = blockIdx.x * 256 + threadIdx.x;
    if (i >= HC * OUTC) return;
    int k = i >> 6, n = i & (OUTC - 1);
    W2t[n * HC + k] = f2bf(W2[i]);
}

/* ---------- layer-1 MFMA GEMM: C[M,1024] = xb[M,256] @ W1t[1024,256]^T ---------- */
#define LDA 40
__global__ __launch_bounds__(256)
void gemm1_mfma(const unsigned short* __restrict__ A,
                const unsigned short* __restrict__ Bt,
                unsigned short* __restrict__ C, int M)
{
    __shared__ unsigned short Al[128 * LDA];
    __shared__ unsigned short Bl[128 * LDA];
    const int tid  = threadIdx.x;
    const int wave = tid >> 6, lane = tid & 63;
    const int quad = lane >> 4, l16 = lane & 15;
    const int wr = (wave >> 1) * 64, wc = (wave & 1) * 64;
    const int row0 = blockIdx.y * 128;
    const int col0 = blockIdx.x * 128;

    f32x4 acc[4][4];
#pragma unroll
    for (int i = 0; i < 4; i++)
#pragma unroll
        for (int j = 0; j < 4; j++) acc[i][j] = (f32x4){0.f, 0.f, 0.f, 0.f};

    for (int k0 = 0; k0 < F_IN; k0 += 32) {
#pragma unroll
        for (int p = 0; p < 2; p++) {
            int idx = tid + 256 * p;
            int r = idx >> 2, q = idx & 3;
            int grow = row0 + r;
            uint4 v = (grow < M)
                ? *reinterpret_cast<const uint4*>(A + (size_t)grow * F_IN + k0 + q * 8)
                : make_uint4(0u, 0u, 0u, 0u);
            *reinterpret_cast<uint4*>(Al + r * LDA + q * 8) = v;
        }
#pragma unroll
        for (int p = 0; p < 2; p++) {
            int idx = tid + 256 * p;
            int r = idx >> 2, q = idx & 3;
            uint4 v = *reinterpret_cast<const uint4*>(Bt + (size_t)(col0 + r) * F_IN + k0 + q * 8);
            *reinterpret_cast<uint4*>(Bl + r * LDA + q * 8) = v;
        }
        __syncthreads();
        bf16x8 af[4], bg[4];
#pragma unroll
        for (int i = 0; i < 4; i++)
            af[i] = *reinterpret_cast<const bf16x8*>(Al + (wr + i * 16 + l16) * LDA + quad * 8);
#pragma unroll
        for (int j = 0; j < 4; j++)
            bg[j] = *reinterpret_cast<const bf16x8*>(Bl + (wc + j * 16 + l16) * LDA + quad * 8);
#pragma unroll
        for (int i = 0; i < 4; i++)
#pragma unroll
            for (int j = 0; j < 4; j++)
                acc[i][j] = __builtin_amdgcn_mfma_f32_16x16x32_bf16(af[i], bg[j], acc[i][j], 0, 0, 0);
        __syncthreads();
    }
#pragma unroll
    for (int i = 0; i < 4; i++) {
#pragma unroll
        for (int r = 0; r < 4; r++) {
            int row = row0 + wr + i * 16 + quad * 4 + r;
            if (row >= M) continue;
#pragma unroll
            for (int j = 0; j < 4; j++) {
                int col = col0 + wc + j * 16 + l16;
                C[(size_t)row * HC + col] = f2bf(acc[i][j][r]);
            }
        }
    }
}

/* ---------- layer-2 MFMA GEMM: h2[M,64] = out1[M,1024] @ W2t[64,1024]^T ---------- */
__global__ __launch_bounds__(256)
void gemm2_mfma(const unsigned short* __restrict__ A,
                const unsigned short* __restrict__ Bt,
                float* __restrict__ C, int M)
{
    __shared__ unsigned short Al[128 * LDA];
    __shared__ unsigned short Bl[64 * LDA];
    const int tid  = threadIdx.x;
    const int wave = tid >> 6, lane = tid & 63;
    const int quad = lane >> 4, l16 = lane & 15;
    const int wr = wave * 32;
    const int row0 = blockIdx.x * 128;

    f32x4 acc[2][4];
#pragma unroll
    for (int i = 0; i < 2; i++)
#pragma unroll
        for (int j = 0; j < 4; j++) acc[i][j] = (f32x4){0.f, 0.f, 0.f, 0.f};

    for (int k0 = 0; k0 < HC; k0 += 32) {
#pragma unroll
        for (int p = 0; p < 2; p++) {
            int idx = tid + 256 * p;
            int r = idx >> 2, q = idx & 3;
            int grow = row0 + r;
            uint4 v = (grow < M)
                ? *reinterpret_cast<const uint4*>(A + (size_t)grow * HC + k0 + q * 8)
                : make_uint4(0u, 0u, 0u, 0u);
            *reinterpret_cast<uint4*>(Al + r * LDA + q * 8) = v;
        }
        {
            int r = tid >> 2, q = tid & 3;
            uint4 v = *reinterpret_cast<const uint4*>(Bt + (size_t)r * HC + k0 + q * 8);
            *reinterpret_cast<uint4*>(Bl + r * LDA + q * 8) = v;
        }
        __syncthreads();
        bf16x8 af[2], bg[4];
#pragma unroll
        for (int i = 0; i < 2; i++)
            af[i] = *reinterpret_cast<const bf16x8*>(Al + (wr + i * 16 + l16) * LDA + quad * 8);
#pragma unroll
        for (int j = 0; j < 4; j++)
            bg[j] = *reinterpret_cast<const bf16x8*>(Bl + (j * 16 + l16) * LDA + quad * 8);
#pragma unroll
        for (int i = 0; i < 2; i++)
#pragma unroll
            for (int j = 0; j < 4; j++)
                acc[i][j] = __builtin_amdgcn_mfma_f32_16x16x32_bf16(af[i], bg[j], acc[i][j], 0, 0, 0);
        __syncthreads();
    }
#pragma unroll
    for (int i = 0; i < 2; i++) {
#pragma unroll
        for (int r = 0; r < 4; r++) {
            int row = row0 + wr + i * 16 + quad * 4 + r;
            if (row >= M) continue;
#pragma unroll
            for (int j = 0; j < 4; j++) {
                int col = j * 16 + l16;
                C[(size_t)row * OUTC + col] = acc[i][j][r];
            }
        }
    }
}

/* ---------- CSR build ---------- */
__global__ void deg_kernel(const int* __restrict__ ei, int* __restrict__ deg)
{
    int e = blockIdx.x * 256 + threadIdx.x;
    if (e >= E_TOT) return;
    int s, d; edge_sd(ei, e, s, d);
    atomicAdd(&deg[d], 1);
}

__global__ __launch_bounds__(1024)
void scan_kernel(const int* __restrict__ deg, int* __restrict__ rowptr,
                 int* __restrict__ cursor)
{
    __shared__ int smem[1024];
    __shared__ int carry_s;
    const int t = threadIdx.x;
    if (t == 0) carry_s = 0;
    __syncthreads();
    for (int base = 0; base < N_NODES; base += 1024) {
        int v = (base + t < N_NODES) ? deg[base + t] : 0;
        smem[t] = v;
        __syncthreads();
#pragma unroll
        for (int off = 1; off < 1024; off <<= 1) {
            int x = (t >= off) ? smem[t - off] : 0;
            __syncthreads();
            smem[t] += x;
            __syncthreads();
        }
        int excl = carry_s + smem[t] - v;
        if (base + t < N_NODES) { rowptr[base + t] = excl; cursor[base + t] = excl; }
        __syncthreads();
        if (t == 0) carry_s += smem[1023];
        __syncthreads();
    }
    if (t == 0) rowptr[N_NODES] = carry_s;
}

__global__ void scatter_kernel(const int* __restrict__ ei, int* __restrict__ cursor,
                               int* __restrict__ csr_src)
{
    int e = blockIdx.x * 256 + threadIdx.x;
    if (e >= E_TOT) return;
    int s, d; edge_sd(ei, e, s, d);
    int pos = atomicAdd(&cursor[d], 1);
    csr_src[pos] = s;
}

/* ---------- layer-1 attention dots: one block per node, all heads ---------- */
__global__ __launch_bounds__(256)
void att1_kernel(const unsigned short* __restrict__ h1,
                 const float* __restrict__ att_src,
                 const float* __restrict__ att_dst,
                 float* __restrict__ a_src, float* __restrict__ a_dst)
{
    const int n = blockIdx.x, t = threadIdx.x, h = t >> 5;
    ushort4 u = reinterpret_cast<const ushort4*>(h1 + (size_t)n * HC)[t];
    float4 as = reinterpret_cast<const float4*>(att_src)[t];
    float4 ad = reinterpret_cast<const float4*>(att_dst)[t];
    float s = bf2f(u.x) * as.x + bf2f(u.y) * as.y + bf2f(u.z) * as.z + bf2f(u.w) * as.w;
    float d = bf2f(u.x) * ad.x + bf2f(u.y) * ad.y + bf2f(u.z) * ad.z + bf2f(u.w) * ad.w;
#pragma unroll
    for (int o = 16; o > 0; o >>= 1) { s += __shfl_xor(s, o); d += __shfl_xor(d, o); }
    if ((t & 31) == 0) { a_src[n * HEADS + h] = s; a_dst[n * HEADS + h] = d; }
}

/* ---------- layer-1 fused softmax+aggregation, bias+ELU, bf16 out ----------
   2 nodes per 256-block; 128 threads/node; thread owns 8 channels (16B loads).
   Per chunk of <=CAP edges: phase1 computes exp(leaky(logit)) into LDS
   (16 lanes per head, strided), phase2 gathers h1 rows weighted by exp.
   1/denom folded in once at the end (softmax scale is linear). */
__global__ __launch_bounds__(256)
void agg1_fused(const int* __restrict__ rowptr, const int* __restrict__ csr_src,
                const unsigned short* __restrict__ h1,
                const float* __restrict__ a_src1, const float* __restrict__ a_dst1,
                const float* __restrict__ b1, unsigned short* __restrict__ out1)
{
    const int t   = threadIdx.x;
    const int sub = t >> 7;            /* node within block: 0/1 */
    const int tl  = t & 127;           /* thread within node */
    const int h   = tl >> 4;           /* head 0..7 */
    const int l   = tl & 15;           /* lane within head group */
    const int d   = blockIdx.x * 2 + sub;

    __shared__ float exps[2][CAP * 8];
    __shared__ int   srcs[2][CAP];
    __shared__ int   maxdeg_s;

    const int start = rowptr[d], end = rowptr[d + 1];
    const int deg = end - start;

    if (t == 0) maxdeg_s = 0;
    __syncthreads();
    if (tl == 0) atomicMax(&maxdeg_s, deg);
    __syncthreads();
    const int maxdeg = maxdeg_s;

    const float adst = a_dst1[d * 8 + h];
    const uint4* __restrict__ h1v = reinterpret_cast<const uint4*>(h1);

    float denom_part = 0.f;
    float acc[8];
#pragma unroll
    for (int k = 0; k < 8; k++) acc[k] = 0.f;

    for (int c0 = 0; c0 < maxdeg; c0 += CAP) {
        const int cend = min(deg - c0, CAP);   /* may be <=0 if this node is done */
        /* phase 1: exps for my head, edges strided by 16 lanes */
        for (int c = l; c < cend; c += 16) {
            int s = csr_src[start + c0 + c];
            if (h == 0) srcs[sub][c] = s;
            float a = a_src1[s * 8 + h] + adst;
            float v = a > 0.f ? a : NEG_SLOPE * a;
            float ex = __expf(v);
            exps[sub][c * 8 + h] = ex;
            denom_part += ex;
        }
        __syncthreads();
        /* phase 2: weighted gather, 1-ahead prefetch */
        if (cend > 0) {
            int   s_cur = srcs[sub][0];
            float w_cur = exps[sub][h];
            uint4 u_cur = h1v[(size_t)s_cur * (HC / 8) + tl];
            for (int c = 0; c < cend; c++) {
                int   s_nxt = 0; float w_nxt = 0.f; uint4 u_nxt;
                if (c + 1 < cend) {
                    s_nxt = srcs[sub][c + 1];
                    w_nxt = exps[sub][(c + 1) * 8 + h];
                    u_nxt = h1v[(size_t)s_nxt * (HC / 8) + tl];
                }
                acc[0] += w_cur * __uint_as_float(u_cur.x << 16);
                acc[1] += w_cur * __uint_as_float(u_cur.x & 0xFFFF0000u);
                acc[2] += w_cur * __uint_as_float(u_cur.y << 16);
                acc[3] += w_cur * __uint_as_float(u_cur.y & 0xFFFF0000u);
                acc[4] += w_cur * __uint_as_float(u_cur.z << 16);
                acc[5] += w_cur * __uint_as_float(u_cur.z & 0xFFFF0000u);
                acc[6] += w_cur * __uint_as_float(u_cur.w << 16);
                acc[7] += w_cur * __uint_as_float(u_cur.w & 0xFFFF0000u);
                s_cur = s_nxt; w_cur = w_nxt; u_cur = u_nxt;
            }
        }
        __syncthreads();
    }
    /* denominator: butterfly over the 16 lanes of this head group */
#pragma unroll
    for (int o = 8; o > 0; o >>= 1) denom_part += __shfl_xor(denom_part, o);
    const float dinv = 1.f / (denom_part + 1e-16f);

    float4 b0 = reinterpret_cast<const float4*>(b1)[tl * 2];
    float4 b4 = reinterpret_cast<const float4*>(b1)[tl * 2 + 1];
    float v[8];
    v[0] = acc[0] * dinv + b0.x; v[1] = acc[1] * dinv + b0.y;
    v[2] = acc[2] * dinv + b0.z; v[3] = acc[3] * dinv + b0.w;
    v[4] = acc[4] * dinv + b4.x; v[5] = acc[5] * dinv + b4.y;
    v[6] = acc[6] * dinv + b4.z; v[7] = acc[7] * dinv + b4.w;
#pragma unroll
    for (int k = 0; k < 8; k++) v[k] = v[k] > 0.f ? v[k] : __expf(v[k]) - 1.f;
    uint4 o;
    o.x = (unsigned)f2bf(v[0]) | ((unsigned)f2bf(v[1]) << 16);
    o.y = (unsigned)f2bf(v[2]) | ((unsigned)f2bf(v[3]) << 16);
    o.z = (unsigned)f2bf(v[4]) | ((unsigned)f2bf(v[5]) << 16);
    o.w = (unsigned)f2bf(v[6]) | ((unsigned)f2bf(v[7]) << 16);
    reinterpret_cast<uint4*>(out1 + (size_t)d * HC)[tl] = o;
}

/* ---------- layer-2 attention dots ---------- */
__global__ __launch_bounds__(64)
void att2_kernel(const float* __restrict__ h2, const float* __restrict__ att_src2,
                 const float* __restrict__ att_dst2,
                 float* __restrict__ a_src2, float* __restrict__ a_dst2)
{
    const int n = blockIdx.x, t = threadIdx.x;
    float v = h2[(size_t)n * OUTC + t];
    float s = v * att_src2[t];
    float d = v * att_dst2[t];
#pragma unroll
    for (int o = 32; o > 0; o >>= 1) { s += __shfl_down(s, o); d += __shfl_down(d, o); }
    if (t == 0) { a_src2[n] = s; a_dst2[n] = d; }
}

/* ---------- layer-2 fused softmax+agg + bias + log_softmax ----------
   4 nodes per 256-block (wave per node); lane = channel. */
__global__ __launch_bounds__(256)
void agg2_lsm(const int* __restrict__ rowptr, const int* __restrict__ csr_src,
              const float* __restrict__ h2,
              const float* __restrict__ a_src2, const float* __restrict__ a_dst2,
              const float* __restrict__ b2, float* __restrict__ out)
{
    const int t = threadIdx.x;
    const int sub = t >> 6;
    const int lane = t & 63;
    const int d = blockIdx.x * 4 + sub;

    __shared__ float exs[4][CAP];
    __shared__ int   ss[4][CAP];
    __shared__ int   maxdeg_s;

    const int start = rowptr[d], end = rowptr[d + 1];
    const int deg = end - start;

    if (t == 0) maxdeg_s = 0;
    __syncthreads();
    if (lane == 0) atomicMax(&maxdeg_s, deg);
    __syncthreads();
    const int maxdeg = maxdeg_s;

    const float adst = a_dst2[d];
    float denom_part = 0.f;
    float acc = 0.f;

    for (int c0 = 0; c0 < maxdeg; c0 += CAP) {
        const int cend = min(deg - c0, CAP);
        for (int c = lane; c < cend; c += 64) {
            int s = csr_src[start + c0 + c];
            ss[sub][c] = s;
            float a = a_src2[s] + adst;
            float v = a > 0.f ? a : NEG_SLOPE * a;
            float ex = __expf(v);
            exs[sub][c] = ex;
            denom_part += ex;
        }
        __syncthreads();
        if (cend > 0) {
            int   s_cur = ss[sub][0];
            float w_cur = exs[sub][0];
            for (int c = 0; c < cend - 1; c++) {
                int   s_nxt = ss[sub][c + 1];
                float w_nxt = exs[sub][c + 1];
                acc += w_cur * h2[(size_t)s_cur * OUTC + lane];
                s_cur = s_nxt; w_cur = w_nxt;
            }
            acc += w_cur * h2[(size_t)s_cur * OUTC + lane];
        }
        __syncthreads();
    }
#pragma unroll
    for (int o = 32; o > 0; o >>= 1) denom_part += __shfl_xor(denom_part, o);
    const float dinv = 1.f / (denom_part + 1e-16f);

    float v = acc * dinv + b2[lane];
    float m = v;
#pragma unroll
    for (int o = 32; o > 0; o >>= 1) m = fmaxf(m, __shfl_xor(m, o));
    float ex = __expf(v - m);
    float ssum = ex;
#pragma unroll
    for (int o = 32; o > 0; o >>= 1) ssum += __shfl_xor(ssum, o);
    out[(size_t)d * OUTC + lane] = v - m - __logf(ssum);
}

extern "C" void kernel_launch(void* const* d_in, const int* in_sizes, int n_in,
                              void* d_out, int out_size, void* d_ws, size_t ws_size,
                              hipStream_t stream)
{
    const float* x   = (const float*)d_in[0];
    const int*   ei  = (const int*)d_in[1];
    const float* W1  = (const float*)d_in[2];
    const float* as1 = (const float*)d_in[3];
    const float* ad1 = (const float*)d_in[4];
    const float* b1  = (const float*)d_in[5];
    const float* W2  = (const float*)d_in[6];
    const float* as2 = (const float*)d_in[7];
    const float* ad2 = (const float*)d_in[8];
    const float* b2  = (const float*)d_in[9];

    char* p = (char*)d_ws;
    auto alloc = [&](size_t bytes) { char* r = p; p += (bytes + 255) & ~(size_t)255; return r; };

    /* region 0: h1 (bf16, 61.44 MB) — dead after agg1_fused; layer-2 buffers alias it */
    char* region0 = (char*)alloc((size_t)N_NODES * HC * 2);
    unsigned short* h1 = (unsigned short*)region0;

    /* region 1: out1 (bf16, 61.44 MB); xb/W1t (dead after gemm1_mfma) alias it */
    char* region1 = (char*)alloc((size_t)N_NODES * HC * 2);
    unsigned short* out1 = (unsigned short*)region1;
    unsigned short* xb   = (unsigned short*)region1;
    unsigned short* W1t  = (unsigned short*)(region1 + (size_t)N_NODES * F_IN * 2 + 256);

    unsigned short* W2t = (unsigned short*)alloc((size_t)OUTC * HC * 2);

    float* a_src1  = (float*)alloc((size_t)N_NODES * HEADS * 4);
    float* a_dst1  = (float*)alloc((size_t)N_NODES * HEADS * 4);
    int*   deg     = (int*)alloc((size_t)N_NODES * 4);
    int*   rowptr  = (int*)alloc((size_t)(N_NODES + 1) * 4);
    int*   cursor  = (int*)alloc((size_t)N_NODES * 4);
    int*   csr_src = (int*)alloc((size_t)E_TOT * 4);

    /* layer-2 buffers aliased into region0 (~8 MB < 61.44 MB) */
    char* q = region0;
    auto alias = [&](size_t bytes) { char* r = q; q += (bytes + 255) & ~(size_t)255; return r; };
    float* h2      = (float*)alias((size_t)N_NODES * OUTC * 4);
    float* a_src2  = (float*)alias((size_t)N_NODES * 4);
    float* a_dst2  = (float*)alias((size_t)N_NODES * 4);

    hipMemsetAsync(deg, 0, (size_t)N_NODES * 4, stream);

    /* CSR build */
    deg_kernel<<<(E_TOT + 255) / 256, 256, 0, stream>>>(ei, deg);
    scan_kernel<<<1, 1024, 0, stream>>>(deg, rowptr, cursor);
    scatter_kernel<<<(E_TOT + 255) / 256, 256, 0, stream>>>(ei, cursor, csr_src);

    /* bf16 conversions */
    cvt_x_kernel<<<(N_NODES * F_IN / 4 + 255) / 256, 256, 0, stream>>>(x, xb);
    cvt_w1t_kernel<<<(F_IN * HC + 255) / 256, 256, 0, stream>>>(W1, W1t);
    cvt_w2t_kernel<<<(HC * OUTC + 255) / 256, 256, 0, stream>>>(W2, W2t);

    /* layer 1 */
    gemm1_mfma<<<dim3(HC / 128, (N_NODES + 127) / 128), 256, 0, stream>>>(xb, W1t, h1, N_NODES);
    att1_kernel<<<N_NODES, 256, 0, stream>>>(h1, as1, ad1, a_src1, a_dst1);
    agg1_fused<<<N_NODES / 2, 256, 0, stream>>>(rowptr, csr_src, h1, a_src1, a_dst1, b1, out1);

    /* layer 2 (h1 dead; aliased buffers now safe, stream-ordered) */
    gemm2_mfma<<<(N_NODES + 127) / 128, 256, 0, stream>>>(out1, W2t, h2, N_NODES);
    att2_kernel<<<N_NODES, 64, 0, stream>>>(h2, as2, ad2, a_src2, a_dst2);
    agg2_lsm<<<N_NODES / 4, 256, 0, stream>>>(rowptr, csr_src, h2, a_src2, a_dst2, b2, (float*)d_out);
}

// Round 9
// 353.717 us; speedup vs baseline: 14.4707x; 1.1225x over previous
//
#include <hip/hip_runtime.h>
#include <math.h>

#define N_NODES 30000
#define F_IN 256
#define E_RAW 300000
#define E_TOT (E_RAW + N_NODES)   /* 330000: edges + self loops */
#define HEADS 8
#define CH 128
#define HC 1024                   /* HEADS*CH */
#define OUTC 64
#define NEG_SLOPE 0.2f
#define CAP 64                    /* edges per LDS chunk in fused agg kernels */

typedef __attribute__((ext_vector_type(8))) short bf16x8;
typedef __attribute__((ext_vector_type(4))) float f32x4;

/* ---------- helpers ---------- */
__device__ __forceinline__ float bf2f(unsigned short u) {
    return __uint_as_float(((unsigned)u) << 16);
}
__device__ __forceinline__ unsigned short f2bf(float f) {
    unsigned b = __float_as_uint(f);
    b += 0x7FFFu + ((b >> 16) & 1u);   /* round to nearest even */
    return (unsigned short)(b >> 16);
}
__device__ __forceinline__ void edge_sd(const int* __restrict__ ei, int e, int& s, int& d) {
    if (e < E_RAW) { s = ei[e]; d = ei[E_RAW + e]; }
    else           { s = e - E_RAW; d = s; }
}

/* ---------- dtype converts ---------- */
__global__ void cvt_x_kernel(const float* __restrict__ x, unsigned short* __restrict__ xb)
{
    int i = blockIdx.x * 256 + threadIdx.x;
    const float4 v = reinterpret_cast<const float4*>(x)[i];
    ushort4 o;
    o.x = f2bf(v.x); o.y = f2bf(v.y); o.z = f2bf(v.z); o.w = f2bf(v.w);
    reinterpret_cast<ushort4*>(xb)[i] = o;
}

__global__ void cvt_w1t_kernel(const float* __restrict__ W1, unsigned short* __restrict__ W1t)
{
    int i = blockIdx.x * 256 + threadIdx.x;
    if (i >= F_IN * HC) return;
    int k = i >> 10, n = i & (HC - 1);
    W1t[n * F_IN + k] = f2bf(W1[i]);
}

__global__ void cvt_w2t_kernel(const float* __restrict__ W2, unsigned short* __restrict__ W2t)
{
    int i = blockIdx.x * 256 + threadIdx.x;
    if (i >= HC * OUTC) return;
    int k = i >> 6, n = i & (OUTC - 1);
    W2t[n * HC + k] = f2bf(W2[i]);
}

/* ---------- layer-1 MFMA GEMM + fused attention dots ----------
   C[M,1024] = xb[M,256] @ W1t[1024,256]^T.  blockIdx.x = head (128 cols).
   Epilogue also computes a_src/a_dst[row, head] from the register tile. */
#define LDA 40
__global__ __launch_bounds__(256)
void gemm1_mfma(const unsigned short* __restrict__ A,
                const unsigned short* __restrict__ Bt,
                unsigned short* __restrict__ C,
                const float* __restrict__ att_src, const float* __restrict__ att_dst,
                float* __restrict__ a_src, float* __restrict__ a_dst, int M)
{
    __shared__ unsigned short Al[128 * LDA];
    __shared__ unsigned short Bl[128 * LDA];
    __shared__ float s_src[128][2];
    __shared__ float s_dst[128][2];
    const int tid  = threadIdx.x;
    const int wave = tid >> 6, lane = tid & 63;
    const int quad = lane >> 4, l16 = lane & 15;
    const int wr = (wave >> 1) * 64, wc = (wave & 1) * 64;
    const int row0 = blockIdx.y * 128;
    const int col0 = blockIdx.x * 128;

    f32x4 acc[4][4];
#pragma unroll
    for (int i = 0; i < 4; i++)
#pragma unroll
        for (int j = 0; j < 4; j++) acc[i][j] = (f32x4){0.f, 0.f, 0.f, 0.f};

    for (int k0 = 0; k0 < F_IN; k0 += 32) {
#pragma unroll
        for (int p = 0; p < 2; p++) {
            int idx = tid + 256 * p;
            int r = idx >> 2, q = idx & 3;
            int grow = row0 + r;
            uint4 v = (grow < M)
                ? *reinterpret_cast<const uint4*>(A + (size_t)grow * F_IN + k0 + q * 8)
                : make_uint4(0u, 0u, 0u, 0u);
            *reinterpret_cast<uint4*>(Al + r * LDA + q * 8) = v;
        }
#pragma unroll
        for (int p = 0; p < 2; p++) {
            int idx = tid + 256 * p;
            int r = idx >> 2, q = idx & 3;
            uint4 v = *reinterpret_cast<const uint4*>(Bt + (size_t)(col0 + r) * F_IN + k0 + q * 8);
            *reinterpret_cast<uint4*>(Bl + r * LDA + q * 8) = v;
        }
        __syncthreads();
        bf16x8 af[4], bg[4];
#pragma unroll
        for (int i = 0; i < 4; i++)
            af[i] = *reinterpret_cast<const bf16x8*>(Al + (wr + i * 16 + l16) * LDA + quad * 8);
#pragma unroll
        for (int j = 0; j < 4; j++)
            bg[j] = *reinterpret_cast<const bf16x8*>(Bl + (wc + j * 16 + l16) * LDA + quad * 8);
#pragma unroll
        for (int i = 0; i < 4; i++)
#pragma unroll
            for (int j = 0; j < 4; j++)
                acc[i][j] = __builtin_amdgcn_mfma_f32_16x16x32_bf16(af[i], bg[j], acc[i][j], 0, 0, 0);
        __syncthreads();
    }
    /* C write */
#pragma unroll
    for (int i = 0; i < 4; i++) {
#pragma unroll
        for (int r = 0; r < 4; r++) {
            int row = row0 + wr + i * 16 + quad * 4 + r;
            if (row >= M) continue;
#pragma unroll
            for (int j = 0; j < 4; j++) {
                int col = col0 + wc + j * 16 + l16;
                C[(size_t)row * HC + col] = f2bf(acc[i][j][r]);
            }
        }
    }
    /* fused attention dots for head = blockIdx.x */
    const float* asv = att_src + blockIdx.x * CH;
    const float* adv = att_dst + blockIdx.x * CH;
    float av[4], dv[4];
#pragma unroll
    for (int j = 0; j < 4; j++) {
        av[j] = asv[wc + j * 16 + l16];
        dv[j] = adv[wc + j * 16 + l16];
    }
#pragma unroll
    for (int i = 0; i < 4; i++) {
#pragma unroll
        for (int r = 0; r < 4; r++) {
            float ps = 0.f, pd = 0.f;
#pragma unroll
            for (int j = 0; j < 4; j++) {
                float cc = acc[i][j][r];
                ps += cc * av[j];
                pd += cc * dv[j];
            }
#pragma unroll
            for (int o = 1; o < 16; o <<= 1) {
                ps += __shfl_xor(ps, o);
                pd += __shfl_xor(pd, o);
            }
            if (l16 == 0) {
                int lr = wr + i * 16 + quad * 4 + r;
                s_src[lr][wc >> 6] = ps;
                s_dst[lr][wc >> 6] = pd;
            }
        }
    }
    __syncthreads();
    if (tid < 128) {
        int row = row0 + tid;
        if (row < M) {
            a_src[row * 8 + blockIdx.x] = s_src[tid][0] + s_src[tid][1];
            a_dst[row * 8 + blockIdx.x] = s_dst[tid][0] + s_dst[tid][1];
        }
    }
}

/* ---------- layer-2 MFMA GEMM: h2[M,64] = out1[M,1024] @ W2t[64,1024]^T ---------- */
__global__ __launch_bounds__(256)
void gemm2_mfma(const unsigned short* __restrict__ A,
                const unsigned short* __restrict__ Bt,
                float* __restrict__ C, int M)
{
    __shared__ unsigned short Al[128 * LDA];
    __shared__ unsigned short Bl[64 * LDA];
    const int tid  = threadIdx.x;
    const int wave = tid >> 6, lane = tid & 63;
    const int quad = lane >> 4, l16 = lane & 15;
    const int wr = wave * 32;
    const int row0 = blockIdx.x * 128;

    f32x4 acc[2][4];
#pragma unroll
    for (int i = 0; i < 2; i++)
#pragma unroll
        for (int j = 0; j < 4; j++) acc[i][j] = (f32x4){0.f, 0.f, 0.f, 0.f};

    for (int k0 = 0; k0 < HC; k0 += 32) {
#pragma unroll
        for (int p = 0; p < 2; p++) {
            int idx = tid + 256 * p;
            int r = idx >> 2, q = idx & 3;
            int grow = row0 + r;
            uint4 v = (grow < M)
                ? *reinterpret_cast<const uint4*>(A + (size_t)grow * HC + k0 + q * 8)
                : make_uint4(0u, 0u, 0u, 0u);
            *reinterpret_cast<uint4*>(Al + r * LDA + q * 8) = v;
        }
        {
            int r = tid >> 2, q = tid & 3;
            uint4 v = *reinterpret_cast<const uint4*>(Bt + (size_t)r * HC + k0 + q * 8);
            *reinterpret_cast<uint4*>(Bl + r * LDA + q * 8) = v;
        }
        __syncthreads();
        bf16x8 af[2], bg[4];
#pragma unroll
        for (int i = 0; i < 2; i++)
            af[i] = *reinterpret_cast<const bf16x8*>(Al + (wr + i * 16 + l16) * LDA + quad * 8);
#pragma unroll
        for (int j = 0; j < 4; j++)
            bg[j] = *reinterpret_cast<const bf16x8*>(Bl + (j * 16 + l16) * LDA + quad * 8);
#pragma unroll
        for (int i = 0; i < 2; i++)
#pragma unroll
            for (int j = 0; j < 4; j++)
                acc[i][j] = __builtin_amdgcn_mfma_f32_16x16x32_bf16(af[i], bg[j], acc[i][j], 0, 0, 0);
        __syncthreads();
    }
#pragma unroll
    for (int i = 0; i < 2; i++) {
#pragma unroll
        for (int r = 0; r < 4; r++) {
            int row = row0 + wr + i * 16 + quad * 4 + r;
            if (row >= M) continue;
#pragma unroll
            for (int j = 0; j < 4; j++) {
                int col = j * 16 + l16;
                C[(size_t)row * OUTC + col] = acc[i][j][r];
            }
        }
    }
}

/* ---------- CSR build ---------- */
__global__ void deg_kernel(const int* __restrict__ ei, int* __restrict__ deg)
{
    int e = blockIdx.x * 256 + threadIdx.x;
    if (e >= E_TOT) return;
    int s, d; edge_sd(ei, e, s, d);
    atomicAdd(&deg[d], 1);
}

/* parallel range allocation: wave prefix + one atomic per wave.
   Node ranges are disjoint but unordered — agg uses rowstart[d], deg[d]. */
__global__ __launch_bounds__(256)
void alloc_kernel(const int* __restrict__ deg, int* __restrict__ rowstart,
                  int* __restrict__ cursor, int* __restrict__ counter)
{
    int d = blockIdx.x * 256 + threadIdx.x;
    int lane = threadIdx.x & 63;
    int v = (d < N_NODES) ? deg[d] : 0;
    int x = v;
#pragma unroll
    for (int o = 1; o < 64; o <<= 1) {
        int y = __shfl_up(x, o);
        if (lane >= o) x += y;
    }
    int excl = x - v;
    int total = __shfl(x, 63);
    int base = 0;
    if (lane == 63) base = atomicAdd(counter, total);
    base = __shfl(base, 63);
    if (d < N_NODES) {
        rowstart[d] = base + excl;
        cursor[d]   = base + excl;
    }
}

__global__ void scatter_kernel(const int* __restrict__ ei, int* __restrict__ cursor,
                               int* __restrict__ csr_src)
{
    int e = blockIdx.x * 256 + threadIdx.x;
    if (e >= E_TOT) return;
    int s, d; edge_sd(ei, e, s, d);
    int pos = atomicAdd(&cursor[d], 1);
    csr_src[pos] = s;
}

/* ---------- layer-1 fused softmax+aggregation, bias+ELU, bf16 out ----------
   2 nodes per 256-block; 128 threads/node; thread owns 8 channels (16B loads). */
__global__ __launch_bounds__(256)
void agg1_fused(const int* __restrict__ rowstart, const int* __restrict__ degv,
                const int* __restrict__ csr_src,
                const unsigned short* __restrict__ h1,
                const float* __restrict__ a_src1, const float* __restrict__ a_dst1,
                const float* __restrict__ b1, unsigned short* __restrict__ out1)
{
    const int t   = threadIdx.x;
    const int sub = t >> 7;            /* node within block: 0/1 */
    const int tl  = t & 127;           /* thread within node */
    const int h   = tl >> 4;           /* head 0..7 */
    const int l   = tl & 15;           /* lane within head group */
    const int d   = blockIdx.x * 2 + sub;

    __shared__ float exps[2][CAP * 8];
    __shared__ int   srcs[2][CAP];
    __shared__ int   maxdeg_s;

    const int start = rowstart[d];
    const int deg   = degv[d];

    if (t == 0) maxdeg_s = 0;
    __syncthreads();
    if (tl == 0) atomicMax(&maxdeg_s, deg);
    __syncthreads();
    const int maxdeg = maxdeg_s;

    const float adst = a_dst1[d * 8 + h];
    const uint4* __restrict__ h1v = reinterpret_cast<const uint4*>(h1);

    float denom_part = 0.f;
    float acc[8];
#pragma unroll
    for (int k = 0; k < 8; k++) acc[k] = 0.f;

    for (int c0 = 0; c0 < maxdeg; c0 += CAP) {
        const int cend = min(deg - c0, CAP);
        for (int c = l; c < cend; c += 16) {
            int s = csr_src[start + c0 + c];
            if (h == 0) srcs[sub][c] = s;
            float a = a_src1[s * 8 + h] + adst;
            float v = a > 0.f ? a : NEG_SLOPE * a;
            float ex = __expf(v);
            exps[sub][c * 8 + h] = ex;
            denom_part += ex;
        }
        __syncthreads();
        if (cend > 0) {
            int   s_cur = srcs[sub][0];
            float w_cur = exps[sub][h];
            uint4 u_cur = h1v[(size_t)s_cur * (HC / 8) + tl];
            for (int c = 0; c < cend; c++) {
                int   s_nxt = 0; float w_nxt = 0.f; uint4 u_nxt;
                if (c + 1 < cend) {
                    s_nxt = srcs[sub][c + 1];
                    w_nxt = exps[sub][(c + 1) * 8 + h];
                    u_nxt = h1v[(size_t)s_nxt * (HC / 8) + tl];
                }
                acc[0] += w_cur * __uint_as_float(u_cur.x << 16);
                acc[1] += w_cur * __uint_as_float(u_cur.x & 0xFFFF0000u);
                acc[2] += w_cur * __uint_as_float(u_cur.y << 16);
                acc[3] += w_cur * __uint_as_float(u_cur.y & 0xFFFF0000u);
                acc[4] += w_cur * __uint_as_float(u_cur.z << 16);
                acc[5] += w_cur * __uint_as_float(u_cur.z & 0xFFFF0000u);
                acc[6] += w_cur * __uint_as_float(u_cur.w << 16);
                acc[7] += w_cur * __uint_as_float(u_cur.w & 0xFFFF0000u);
                s_cur = s_nxt; w_cur = w_nxt; u_cur = u_nxt;
            }
        }
        __syncthreads();
    }
#pragma unroll
    for (int o = 8; o > 0; o >>= 1) denom_part += __shfl_xor(denom_part, o);
    const float dinv = 1.f / (denom_part + 1e-16f);

    float4 b0 = reinterpret_cast<const float4*>(b1)[tl * 2];
    float4 b4 = reinterpret_cast<const float4*>(b1)[tl * 2 + 1];
    float v[8];
    v[0] = acc[0] * dinv + b0.x; v[1] = acc[1] * dinv + b0.y;
    v[2] = acc[2] * dinv + b0.z; v[3] = acc[3] * dinv + b0.w;
    v[4] = acc[4] * dinv + b4.x; v[5] = acc[5] * dinv + b4.y;
    v[6] = acc[6] * dinv + b4.z; v[7] = acc[7] * dinv + b4.w;
#pragma unroll
    for (int k = 0; k < 8; k++) v[k] = v[k] > 0.f ? v[k] : __expf(v[k]) - 1.f;
    uint4 o;
    o.x = (unsigned)f2bf(v[0]) | ((unsigned)f2bf(v[1]) << 16);
    o.y = (unsigned)f2bf(v[2]) | ((unsigned)f2bf(v[3]) << 16);
    o.z = (unsigned)f2bf(v[4]) | ((unsigned)f2bf(v[5]) << 16);
    o.w = (unsigned)f2bf(v[6]) | ((unsigned)f2bf(v[7]) << 16);
    reinterpret_cast<uint4*>(out1 + (size_t)d * HC)[tl] = o;
}

/* ---------- layer-2 attention dots ---------- */
__global__ __launch_bounds__(64)
void att2_kernel(const float* __restrict__ h2, const float* __restrict__ att_src2,
                 const float* __restrict__ att_dst2,
                 float* __restrict__ a_src2, float* __restrict__ a_dst2)
{
    const int n = blockIdx.x, t = threadIdx.x;
    float v = h2[(size_t)n * OUTC + t];
    float s = v * att_src2[t];
    float d = v * att_dst2[t];
#pragma unroll
    for (int o = 32; o > 0; o >>= 1) { s += __shfl_down(s, o); d += __shfl_down(d, o); }
    if (t == 0) { a_src2[n] = s; a_dst2[n] = d; }
}

/* ---------- layer-2 fused softmax+agg + bias + log_softmax ---------- */
__global__ __launch_bounds__(256)
void agg2_lsm(const int* __restrict__ rowstart, const int* __restrict__ degv,
              const int* __restrict__ csr_src,
              const float* __restrict__ h2,
              const float* __restrict__ a_src2, const float* __restrict__ a_dst2,
              const float* __restrict__ b2, float* __restrict__ out)
{
    const int t = threadIdx.x;
    const int sub = t >> 6;
    const int lane = t & 63;
    const int d = blockIdx.x * 4 + sub;

    __shared__ float exs[4][CAP];
    __shared__ int   ss[4][CAP];
    __shared__ int   maxdeg_s;

    const int start = rowstart[d];
    const int deg   = degv[d];

    if (t == 0) maxdeg_s = 0;
    __syncthreads();
    if (lane == 0) atomicMax(&maxdeg_s, deg);
    __syncthreads();
    const int maxdeg = maxdeg_s;

    const float adst = a_dst2[d];
    float denom_part = 0.f;
    float acc = 0.f;

    for (int c0 = 0; c0 < maxdeg; c0 += CAP) {
        const int cend = min(deg - c0, CAP);
        for (int c = lane; c < cend; c += 64) {
            int s = csr_src[start + c0 + c];
            ss[sub][c] = s;
            float a = a_src2[s] + adst;
            float v = a > 0.f ? a : NEG_SLOPE * a;
            float ex = __expf(v);
            exs[sub][c] = ex;
            denom_part += ex;
        }
        __syncthreads();
        if (cend > 0) {
            int   s_cur = ss[sub][0];
            float w_cur = exs[sub][0];
            for (int c = 0; c < cend - 1; c++) {
                int   s_nxt = ss[sub][c + 1];
                float w_nxt = exs[sub][c + 1];
                acc += w_cur * h2[(size_t)s_cur * OUTC + lane];
                s_cur = s_nxt; w_cur = w_nxt;
            }
            acc += w_cur * h2[(size_t)s_cur * OUTC + lane];
        }
        __syncthreads();
    }
#pragma unroll
    for (int o = 32; o > 0; o >>= 1) denom_part += __shfl_xor(denom_part, o);
    const float dinv = 1.f / (denom_part + 1e-16f);

    float v = acc * dinv + b2[lane];
    float m = v;
#pragma unroll
    for (int o = 32; o > 0; o >>= 1) m = fmaxf(m, __shfl_xor(m, o));
    float ex = __expf(v - m);
    float ssum = ex;
#pragma unroll
    for (int o = 32; o > 0; o >>= 1) ssum += __shfl_xor(ssum, o);
    out[(size_t)d * OUTC + lane] = v - m - __logf(ssum);
}

extern "C" void kernel_launch(void* const* d_in, const int* in_sizes, int n_in,
                              void* d_out, int out_size, void* d_ws, size_t ws_size,
                              hipStream_t stream)
{
    const float* x   = (const float*)d_in[0];
    const int*   ei  = (const int*)d_in[1];
    const float* W1  = (const float*)d_in[2];
    const float* as1 = (const float*)d_in[3];
    const float* ad1 = (const float*)d_in[4];
    const float* b1  = (const float*)d_in[5];
    const float* W2  = (const float*)d_in[6];
    const float* as2 = (const float*)d_in[7];
    const float* ad2 = (const float*)d_in[8];
    const float* b2  = (const float*)d_in[9];

    char* p = (char*)d_ws;
    auto alloc = [&](size_t bytes) { char* r = p; p += (bytes + 255) & ~(size_t)255; return r; };

    /* region 0: h1 (bf16, 61.44 MB) — dead after agg1_fused; layer-2 buffers alias it */
    char* region0 = (char*)alloc((size_t)N_NODES * HC * 2);
    unsigned short* h1 = (unsigned short*)region0;

    /* region 1: out1 (bf16, 61.44 MB); xb/W1t (dead after gemm1_mfma) alias it */
    char* region1 = (char*)alloc((size_t)N_NODES * HC * 2);
    unsigned short* out1 = (unsigned short*)region1;
    unsigned short* xb   = (unsigned short*)region1;
    unsigned short* W1t  = (unsigned short*)(region1 + (size_t)N_NODES * F_IN * 2 + 256);

    unsigned short* W2t = (unsigned short*)alloc((size_t)OUTC * HC * 2);

    float* a_src1   = (float*)alloc((size_t)N_NODES * HEADS * 4);
    float* a_dst1   = (float*)alloc((size_t)N_NODES * HEADS * 4);
    int*   deg      = (int*)alloc((size_t)(N_NODES + 1) * 4);  /* +1: alloc counter */
    int*   counter  = deg + N_NODES;
    int*   rowstart = (int*)alloc((size_t)N_NODES * 4);
    int*   cursor   = (int*)alloc((size_t)N_NODES * 4);
    int*   csr_src  = (int*)alloc((size_t)E_TOT * 4);

    /* layer-2 buffers aliased into region0 (~8 MB < 61.44 MB) */
    char* q = region0;
    auto alias = [&](size_t bytes) { char* r = q; q += (bytes + 255) & ~(size_t)255; return r; };
    float* h2      = (float*)alias((size_t)N_NODES * OUTC * 4);
    float* a_src2  = (float*)alias((size_t)N_NODES * 4);
    float* a_dst2  = (float*)alias((size_t)N_NODES * 4);

    hipMemsetAsync(deg, 0, (size_t)(N_NODES + 1) * 4, stream);

    /* CSR build (parallel, unordered ranges) */
    deg_kernel<<<(E_TOT + 255) / 256, 256, 0, stream>>>(ei, deg);
    alloc_kernel<<<(N_NODES + 255) / 256, 256, 0, stream>>>(deg, rowstart, cursor, counter);
    scatter_kernel<<<(E_TOT + 255) / 256, 256, 0, stream>>>(ei, cursor, csr_src);

    /* bf16 conversions */
    cvt_x_kernel<<<(N_NODES * F_IN / 4 + 255) / 256, 256, 0, stream>>>(x, xb);
    cvt_w1t_kernel<<<(F_IN * HC + 255) / 256, 256, 0, stream>>>(W1, W1t);
    cvt_w2t_kernel<<<(HC * OUTC + 255) / 256, 256, 0, stream>>>(W2, W2t);

    /* layer 1 (att dots fused into gemm1 epilogue) */
    gemm1_mfma<<<dim3(HC / 128, (N_NODES + 127) / 128), 256, 0, stream>>>(
        xb, W1t, h1, as1, ad1, a_src1, a_dst1, N_NODES);
    agg1_fused<<<N_NODES / 2, 256, 0, stream>>>(rowstart, deg, csr_src, h1, a_src1, a_dst1, b1, out1);

    /* layer 2 (h1 dead; aliased buffers now safe, stream-ordered) */
    gemm2_mfma<<<(N_NODES + 127) / 128, 256, 0, stream>>>(out1, W2t, h2, N_NODES);
    att2_kernel<<<N_NODES, 64, 0, stream>>>(h2, as2, ad2, a_src2, a_dst2);
    agg2_lsm<<<N_NODES / 4, 256, 0, stream>>>(rowstart, deg, csr_src, h2, a_src2, a_dst2, b2, (float*)d_out);
}

// Round 10
// 340.960 us; speedup vs baseline: 15.0122x; 1.0374x over previous
//
#include <hip/hip_runtime.h>
#include <math.h>

#define N_NODES 30000
#define F_IN 256
#define E_RAW 300000
#define E_TOT (E_RAW + N_NODES)   /* 330000: edges + self loops */
#define HEADS 8
#define CH 128
#define HC 1024                   /* HEADS*CH */
#define OUTC 64
#define NEG_SLOPE 0.2f
#define CAP 64                    /* edges per LDS chunk in fused agg kernels */

typedef __attribute__((ext_vector_type(8))) short bf16x8;
typedef __attribute__((ext_vector_type(4))) float f32x4;

/* ---------- helpers ---------- */
__device__ __forceinline__ float bf2f(unsigned short u) {
    return __uint_as_float(((unsigned)u) << 16);
}
__device__ __forceinline__ unsigned short f2bf(float f) {
    unsigned b = __float_as_uint(f);
    b += 0x7FFFu + ((b >> 16) & 1u);   /* round to nearest even */
    return (unsigned short)(b >> 16);
}
__device__ __forceinline__ void edge_sd(const int* __restrict__ ei, int e, int& s, int& d) {
    if (e < E_RAW) { s = ei[e]; d = ei[E_RAW + e]; }
    else           { s = e - E_RAW; d = s; }
}

/* ---------- fused prep: cvt_x | deg | cvt_w1t | cvt_w2t (independent jobs) ---------- */
#define NB_CVTX (N_NODES * F_IN / 4 / 256)      /* 7500 */
#define NB_DEG  ((E_TOT + 255) / 256)           /* 1290 */
#define NB_W1T  ((F_IN * HC + 255) / 256)       /* 1024 */
#define NB_W2T  ((HC * OUTC + 255) / 256)       /* 256 */
#define NB_PREP (NB_CVTX + NB_DEG + NB_W1T + NB_W2T)

__global__ __launch_bounds__(256)
void prep_kernel(const float* __restrict__ x, unsigned short* __restrict__ xb,
                 const float* __restrict__ W1, unsigned short* __restrict__ W1t,
                 const float* __restrict__ W2, unsigned short* __restrict__ W2t,
                 const int* __restrict__ ei, int* __restrict__ deg)
{
    const int b = blockIdx.x, t = threadIdx.x;
    if (b < NB_CVTX) {
        int i = b * 256 + t;
        const float4 v = reinterpret_cast<const float4*>(x)[i];
        ushort4 o;
        o.x = f2bf(v.x); o.y = f2bf(v.y); o.z = f2bf(v.z); o.w = f2bf(v.w);
        reinterpret_cast<ushort4*>(xb)[i] = o;
    } else if (b < NB_CVTX + NB_DEG) {
        int e = (b - NB_CVTX) * 256 + t;
        if (e < E_TOT) {
            int s, d; edge_sd(ei, e, s, d);
            atomicAdd(&deg[d], 1);
        }
    } else if (b < NB_CVTX + NB_DEG + NB_W1T) {
        int i = (b - NB_CVTX - NB_DEG) * 256 + t;
        if (i < F_IN * HC) {
            int k = i >> 10, n = i & (HC - 1);
            W1t[n * F_IN + k] = f2bf(W1[i]);
        }
    } else {
        int i = (b - NB_CVTX - NB_DEG - NB_W1T) * 256 + t;
        if (i < HC * OUTC) {
            int k = i >> 6, n = i & (OUTC - 1);
            W2t[n * HC + k] = f2bf(W2[i]);
        }
    }
}

/* ---------- layer-1 MFMA GEMM + fused attention dots ---------- */
#define LDA 40
__global__ __launch_bounds__(256)
void gemm1_mfma(const unsigned short* __restrict__ A,
                const unsigned short* __restrict__ Bt,
                unsigned short* __restrict__ C,
                const float* __restrict__ att_src, const float* __restrict__ att_dst,
                float* __restrict__ a_src, float* __restrict__ a_dst, int M)
{
    __shared__ unsigned short Al[128 * LDA];
    __shared__ unsigned short Bl[128 * LDA];
    __shared__ float s_src[128][2];
    __shared__ float s_dst[128][2];
    const int tid  = threadIdx.x;
    const int wave = tid >> 6, lane = tid & 63;
    const int quad = lane >> 4, l16 = lane & 15;
    const int wr = (wave >> 1) * 64, wc = (wave & 1) * 64;
    const int row0 = blockIdx.y * 128;
    const int col0 = blockIdx.x * 128;

    f32x4 acc[4][4];
#pragma unroll
    for (int i = 0; i < 4; i++)
#pragma unroll
        for (int j = 0; j < 4; j++) acc[i][j] = (f32x4){0.f, 0.f, 0.f, 0.f};

    for (int k0 = 0; k0 < F_IN; k0 += 32) {
#pragma unroll
        for (int p = 0; p < 2; p++) {
            int idx = tid + 256 * p;
            int r = idx >> 2, q = idx & 3;
            int grow = row0 + r;
            uint4 v = (grow < M)
                ? *reinterpret_cast<const uint4*>(A + (size_t)grow * F_IN + k0 + q * 8)
                : make_uint4(0u, 0u, 0u, 0u);
            *reinterpret_cast<uint4*>(Al + r * LDA + q * 8) = v;
        }
#pragma unroll
        for (int p = 0; p < 2; p++) {
            int idx = tid + 256 * p;
            int r = idx >> 2, q = idx & 3;
            uint4 v = *reinterpret_cast<const uint4*>(Bt + (size_t)(col0 + r) * F_IN + k0 + q * 8);
            *reinterpret_cast<uint4*>(Bl + r * LDA + q * 8) = v;
        }
        __syncthreads();
        bf16x8 af[4], bg[4];
#pragma unroll
        for (int i = 0; i < 4; i++)
            af[i] = *reinterpret_cast<const bf16x8*>(Al + (wr + i * 16 + l16) * LDA + quad * 8);
#pragma unroll
        for (int j = 0; j < 4; j++)
            bg[j] = *reinterpret_cast<const bf16x8*>(Bl + (wc + j * 16 + l16) * LDA + quad * 8);
#pragma unroll
        for (int i = 0; i < 4; i++)
#pragma unroll
            for (int j = 0; j < 4; j++)
                acc[i][j] = __builtin_amdgcn_mfma_f32_16x16x32_bf16(af[i], bg[j], acc[i][j], 0, 0, 0);
        __syncthreads();
    }
#pragma unroll
    for (int i = 0; i < 4; i++) {
#pragma unroll
        for (int r = 0; r < 4; r++) {
            int row = row0 + wr + i * 16 + quad * 4 + r;
            if (row >= M) continue;
#pragma unroll
            for (int j = 0; j < 4; j++) {
                int col = col0 + wc + j * 16 + l16;
                C[(size_t)row * HC + col] = f2bf(acc[i][j][r]);
            }
        }
    }
    /* fused attention dots for head = blockIdx.x */
    const float* asv = att_src + blockIdx.x * CH;
    const float* adv = att_dst + blockIdx.x * CH;
    float av[4], dv[4];
#pragma unroll
    for (int j = 0; j < 4; j++) {
        av[j] = asv[wc + j * 16 + l16];
        dv[j] = adv[wc + j * 16 + l16];
    }
#pragma unroll
    for (int i = 0; i < 4; i++) {
#pragma unroll
        for (int r = 0; r < 4; r++) {
            float ps = 0.f, pd = 0.f;
#pragma unroll
            for (int j = 0; j < 4; j++) {
                float cc = acc[i][j][r];
                ps += cc * av[j];
                pd += cc * dv[j];
            }
#pragma unroll
            for (int o = 1; o < 16; o <<= 1) {
                ps += __shfl_xor(ps, o);
                pd += __shfl_xor(pd, o);
            }
            if (l16 == 0) {
                int lr = wr + i * 16 + quad * 4 + r;
                s_src[lr][wc >> 6] = ps;
                s_dst[lr][wc >> 6] = pd;
            }
        }
    }
    __syncthreads();
    if (tid < 128) {
        int row = row0 + tid;
        if (row < M) {
            a_src[row * 8 + blockIdx.x] = s_src[tid][0] + s_src[tid][1];
            a_dst[row * 8 + blockIdx.x] = s_dst[tid][0] + s_dst[tid][1];
        }
    }
}

/* ---------- layer-2 MFMA GEMM + fused att2 dots ----------
   h2[M,64] = out1[M,1024] @ W2t[64,1024]^T; per-row att2 dots from registers. */
__global__ __launch_bounds__(256)
void gemm2_mfma(const unsigned short* __restrict__ A,
                const unsigned short* __restrict__ Bt,
                float* __restrict__ C,
                const float* __restrict__ att_src2, const float* __restrict__ att_dst2,
                float* __restrict__ a_src2, float* __restrict__ a_dst2, int M)
{
    __shared__ unsigned short Al[128 * LDA];
    __shared__ unsigned short Bl[64 * LDA];
    const int tid  = threadIdx.x;
    const int wave = tid >> 6, lane = tid & 63;
    const int quad = lane >> 4, l16 = lane & 15;
    const int wr = wave * 32;
    const int row0 = blockIdx.x * 128;

    f32x4 acc[2][4];
#pragma unroll
    for (int i = 0; i < 2; i++)
#pragma unroll
        for (int j = 0; j < 4; j++) acc[i][j] = (f32x4){0.f, 0.f, 0.f, 0.f};

    for (int k0 = 0; k0 < HC; k0 += 32) {
#pragma unroll
        for (int p = 0; p < 2; p++) {
            int idx = tid + 256 * p;
            int r = idx >> 2, q = idx & 3;
            int grow = row0 + r;
            uint4 v = (grow < M)
                ? *reinterpret_cast<const uint4*>(A + (size_t)grow * HC + k0 + q * 8)
                : make_uint4(0u, 0u, 0u, 0u);
            *reinterpret_cast<uint4*>(Al + r * LDA + q * 8) = v;
        }
        {
            int r = tid >> 2, q = tid & 3;
            uint4 v = *reinterpret_cast<const uint4*>(Bt + (size_t)r * HC + k0 + q * 8);
            *reinterpret_cast<uint4*>(Bl + r * LDA + q * 8) = v;
        }
        __syncthreads();
        bf16x8 af[2], bg[4];
#pragma unroll
        for (int i = 0; i < 2; i++)
            af[i] = *reinterpret_cast<const bf16x8*>(Al + (wr + i * 16 + l16) * LDA + quad * 8);
#pragma unroll
        for (int j = 0; j < 4; j++)
            bg[j] = *reinterpret_cast<const bf16x8*>(Bl + (j * 16 + l16) * LDA + quad * 8);
#pragma unroll
        for (int i = 0; i < 2; i++)
#pragma unroll
            for (int j = 0; j < 4; j++)
                acc[i][j] = __builtin_amdgcn_mfma_f32_16x16x32_bf16(af[i], bg[j], acc[i][j], 0, 0, 0);
        __syncthreads();
    }
    float av[4], dv[4];
#pragma unroll
    for (int j = 0; j < 4; j++) {
        av[j] = att_src2[j * 16 + l16];
        dv[j] = att_dst2[j * 16 + l16];
    }
#pragma unroll
    for (int i = 0; i < 2; i++) {
#pragma unroll
        for (int r = 0; r < 4; r++) {
            int row = row0 + wr + i * 16 + quad * 4 + r;
            float ps = 0.f, pd = 0.f;
#pragma unroll
            for (int j = 0; j < 4; j++) {
                float cc = acc[i][j][r];
                int col = j * 16 + l16;
                if (row < M) C[(size_t)row * OUTC + col] = cc;
                ps += cc * av[j];
                pd += cc * dv[j];
            }
#pragma unroll
            for (int o = 1; o < 16; o <<= 1) {
                ps += __shfl_xor(ps, o);
                pd += __shfl_xor(pd, o);
            }
            if (l16 == 0 && row < M) {
                a_src2[row] = ps;
                a_dst2[row] = pd;
            }
        }
    }
}

/* ---------- CSR build ---------- */
/* parallel range allocation: wave prefix + one atomic per wave.
   Node ranges are disjoint but unordered — agg uses rowstart[d], deg[d]. */
__global__ __launch_bounds__(256)
void alloc_kernel(const int* __restrict__ deg, int* __restrict__ rowstart,
                  int* __restrict__ cursor, int* __restrict__ counter)
{
    int d = blockIdx.x * 256 + threadIdx.x;
    int lane = threadIdx.x & 63;
    int v = (d < N_NODES) ? deg[d] : 0;
    int x = v;
#pragma unroll
    for (int o = 1; o < 64; o <<= 1) {
        int y = __shfl_up(x, o);
        if (lane >= o) x += y;
    }
    int excl = x - v;
    int total = __shfl(x, 63);
    int base = 0;
    if (lane == 63) base = atomicAdd(counter, total);
    base = __shfl(base, 63);
    if (d < N_NODES) {
        rowstart[d] = base + excl;
        cursor[d]   = base + excl;
    }
}

__global__ void scatter_kernel(const int* __restrict__ ei, int* __restrict__ cursor,
                               int* __restrict__ csr_src)
{
    int e = blockIdx.x * 256 + threadIdx.x;
    if (e >= E_TOT) return;
    int s, d; edge_sd(ei, e, s, d);
    int pos = atomicAdd(&cursor[d], 1);
    csr_src[pos] = s;
}

/* ---------- layer-1 fused softmax+aggregation, bias+ELU, bf16 out ----------
   2 nodes per 256-block; 128 threads/node; 2-ahead pipelined gather. */
__global__ __launch_bounds__(256)
void agg1_fused(const int* __restrict__ rowstart, const int* __restrict__ degv,
                const int* __restrict__ csr_src,
                const unsigned short* __restrict__ h1,
                const float* __restrict__ a_src1, const float* __restrict__ a_dst1,
                const float* __restrict__ b1, unsigned short* __restrict__ out1)
{
    const int t   = threadIdx.x;
    const int sub = t >> 7;
    const int tl  = t & 127;
    const int h   = tl >> 4;
    const int l   = tl & 15;
    const int d   = blockIdx.x * 2 + sub;

    __shared__ float exps[2][CAP * 8];
    __shared__ int   srcs[2][CAP];
    __shared__ int   maxdeg_s;

    const int start = rowstart[d];
    const int deg   = degv[d];

    if (t == 0) maxdeg_s = 0;
    __syncthreads();
    if (tl == 0) atomicMax(&maxdeg_s, deg);
    __syncthreads();
    const int maxdeg = maxdeg_s;

    const float adst = a_dst1[d * 8 + h];
    const uint4* __restrict__ h1v = reinterpret_cast<const uint4*>(h1);

    float denom_part = 0.f;
    float acc[8];
#pragma unroll
    for (int k = 0; k < 8; k++) acc[k] = 0.f;

    for (int c0 = 0; c0 < maxdeg; c0 += CAP) {
        const int cend = min(deg - c0, CAP);
        for (int c = l; c < cend; c += 16) {
            int s = csr_src[start + c0 + c];
            if (h == 0) srcs[sub][c] = s;
            float a = a_src1[s * 8 + h] + adst;
            float v = a > 0.f ? a : NEG_SLOPE * a;
            float ex = __expf(v);
            exps[sub][c * 8 + h] = ex;
            denom_part += ex;
        }
        __syncthreads();
        if (cend > 0) {
            /* 2-deep pipeline, unroll x2 */
            uint4 u0, u1; float w0, w1;
            u0 = h1v[(size_t)srcs[sub][0] * (HC / 8) + tl];
            w0 = exps[sub][h];
            if (cend > 1) {
                u1 = h1v[(size_t)srcs[sub][1] * (HC / 8) + tl];
                w1 = exps[sub][8 + h];
            } else { u1 = u0; w1 = 0.f; }
            int c = 0;
            for (; c + 2 < cend; c += 2) {
                uint4 ua = h1v[(size_t)srcs[sub][c + 2] * (HC / 8) + tl];
                float wa = exps[sub][(c + 2) * 8 + h];
                uint4 ub = u0; float wb = 0.f;
                if (c + 3 < cend) {
                    ub = h1v[(size_t)srcs[sub][c + 3] * (HC / 8) + tl];
                    wb = exps[sub][(c + 3) * 8 + h];
                }
                acc[0] += w0 * __uint_as_float(u0.x << 16);
                acc[1] += w0 * __uint_as_float(u0.x & 0xFFFF0000u);
                acc[2] += w0 * __uint_as_float(u0.y << 16);
                acc[3] += w0 * __uint_as_float(u0.y & 0xFFFF0000u);
                acc[4] += w0 * __uint_as_float(u0.z << 16);
                acc[5] += w0 * __uint_as_float(u0.z & 0xFFFF0000u);
                acc[6] += w0 * __uint_as_float(u0.w << 16);
                acc[7] += w0 * __uint_as_float(u0.w & 0xFFFF0000u);
                acc[0] += w1 * __uint_as_float(u1.x << 16);
                acc[1] += w1 * __uint_as_float(u1.x & 0xFFFF0000u);
                acc[2] += w1 * __uint_as_float(u1.y << 16);
                acc[3] += w1 * __uint_as_float(u1.y & 0xFFFF0000u);
                acc[4] += w1 * __uint_as_float(u1.z << 16);
                acc[5] += w1 * __uint_as_float(u1.z & 0xFFFF0000u);
                acc[6] += w1 * __uint_as_float(u1.w << 16);
                acc[7] += w1 * __uint_as_float(u1.w & 0xFFFF0000u);
                u0 = ua; w0 = wa; u1 = ub; w1 = wb;
            }
            /* tail: 1 or 2 edges */
            acc[0] += w0 * __uint_as_float(u0.x << 16);
            acc[1] += w0 * __uint_as_float(u0.x & 0xFFFF0000u);
            acc[2] += w0 * __uint_as_float(u0.y << 16);
            acc[3] += w0 * __uint_as_float(u0.y & 0xFFFF0000u);
            acc[4] += w0 * __uint_as_float(u0.z << 16);
            acc[5] += w0 * __uint_as_float(u0.z & 0xFFFF0000u);
            acc[6] += w0 * __uint_as_float(u0.w << 16);
            acc[7] += w0 * __uint_as_float(u0.w & 0xFFFF0000u);
            if (c + 1 < cend) {
                acc[0] += w1 * __uint_as_float(u1.x << 16);
                acc[1] += w1 * __uint_as_float(u1.x & 0xFFFF0000u);
                acc[2] += w1 * __uint_as_float(u1.y << 16);
                acc[3] += w1 * __uint_as_float(u1.y & 0xFFFF0000u);
                acc[4] += w1 * __uint_as_float(u1.z << 16);
                acc[5] += w1 * __uint_as_float(u1.z & 0xFFFF0000u);
                acc[6] += w1 * __uint_as_float(u1.w << 16);
                acc[7] += w1 * __uint_as_float(u1.w & 0xFFFF0000u);
            }
        }
        __syncthreads();
    }
#pragma unroll
    for (int o = 8; o > 0; o >>= 1) denom_part += __shfl_xor(denom_part, o);
    const float dinv = 1.f / (denom_part + 1e-16f);

    float4 b0 = reinterpret_cast<const float4*>(b1)[tl * 2];
    float4 b4 = reinterpret_cast<const float4*>(b1)[tl * 2 + 1];
    float v[8];
    v[0] = acc[0] * dinv + b0.x; v[1] = acc[1] * dinv + b0.y;
    v[2] = acc[2] * dinv + b0.z; v[3] = acc[3] * dinv + b0.w;
    v[4] = acc[4] * dinv + b4.x; v[5] = acc[5] * dinv + b4.y;
    v[6] = acc[6] * dinv + b4.z; v[7] = acc[7] * dinv + b4.w;
#pragma unroll
    for (int k = 0; k < 8; k++) v[k] = v[k] > 0.f ? v[k] : __expf(v[k]) - 1.f;
    uint4 o;
    o.x = (unsigned)f2bf(v[0]) | ((unsigned)f2bf(v[1]) << 16);
    o.y = (unsigned)f2bf(v[2]) | ((unsigned)f2bf(v[3]) << 16);
    o.z = (unsigned)f2bf(v[4]) | ((unsigned)f2bf(v[5]) << 16);
    o.w = (unsigned)f2bf(v[6]) | ((unsigned)f2bf(v[7]) << 16);
    reinterpret_cast<uint4*>(out1 + (size_t)d * HC)[tl] = o;
}

/* ---------- layer-2 fused softmax+agg + bias + log_softmax ---------- */
__global__ __launch_bounds__(256)
void agg2_lsm(const int* __restrict__ rowstart, const int* __restrict__ degv,
              const int* __restrict__ csr_src,
              const float* __restrict__ h2,
              const float* __restrict__ a_src2, const float* __restrict__ a_dst2,
              const float* __restrict__ b2, float* __restrict__ out)
{
    const int t = threadIdx.x;
    const int sub = t >> 6;
    const int lane = t & 63;
    const int d = blockIdx.x * 4 + sub;

    __shared__ float exs[4][CAP];
    __shared__ int   ss[4][CAP];
    __shared__ int   maxdeg_s;

    const int start = rowstart[d];
    const int deg   = degv[d];

    if (t == 0) maxdeg_s = 0;
    __syncthreads();
    if (lane == 0) atomicMax(&maxdeg_s, deg);
    __syncthreads();
    const int maxdeg = maxdeg_s;

    const float adst = a_dst2[d];
    float denom_part = 0.f;
    float acc = 0.f;

    for (int c0 = 0; c0 < maxdeg; c0 += CAP) {
        const int cend = min(deg - c0, CAP);
        for (int c = lane; c < cend; c += 64) {
            int s = csr_src[start + c0 + c];
            ss[sub][c] = s;
            float a = a_src2[s] + adst;
            float v = a > 0.f ? a : NEG_SLOPE * a;
            float ex = __expf(v);
            exs[sub][c] = ex;
            denom_part += ex;
        }
        __syncthreads();
        if (cend > 0) {
            float u0, u1, w0, w1;
            u0 = h2[(size_t)ss[sub][0] * OUTC + lane];
            w0 = exs[sub][0];
            if (cend > 1) {
                u1 = h2[(size_t)ss[sub][1] * OUTC + lane];
                w1 = exs[sub][1];
            } else { u1 = 0.f; w1 = 0.f; }
            int c = 0;
            for (; c + 2 < cend; c += 2) {
                float ua = h2[(size_t)ss[sub][c + 2] * OUTC + lane];
                float wa = exs[sub][c + 2];
                float ub = 0.f, wb = 0.f;
                if (c + 3 < cend) {
                    ub = h2[(size_t)ss[sub][c + 3] * OUTC + lane];
                    wb = exs[sub][c + 3];
                }
                acc += w0 * u0 + w1 * u1;
                u0 = ua; w0 = wa; u1 = ub; w1 = wb;
            }
            acc += w0 * u0;
            if (c + 1 < cend) acc += w1 * u1;
        }
        __syncthreads();
    }
#pragma unroll
    for (int o = 32; o > 0; o >>= 1) denom_part += __shfl_xor(denom_part, o);
    const float dinv = 1.f / (denom_part + 1e-16f);

    float v = acc * dinv + b2[lane];
    float m = v;
#pragma unroll
    for (int o = 32; o > 0; o >>= 1) m = fmaxf(m, __shfl_xor(m, o));
    float ex = __expf(v - m);
    float ssum = ex;
#pragma unroll
    for (int o = 32; o > 0; o >>= 1) ssum += __shfl_xor(ssum, o);
    out[(size_t)d * OUTC + lane] = v - m - __logf(ssum);
}

extern "C" void kernel_launch(void* const* d_in, const int* in_sizes, int n_in,
                              void* d_out, int out_size, void* d_ws, size_t ws_size,
                              hipStream_t stream)
{
    const float* x   = (const float*)d_in[0];
    const int*   ei  = (const int*)d_in[1];
    const float* W1  = (const float*)d_in[2];
    const float* as1 = (const float*)d_in[3];
    const float* ad1 = (const float*)d_in[4];
    const float* b1  = (const float*)d_in[5];
    const float* W2  = (const float*)d_in[6];
    const float* as2 = (const float*)d_in[7];
    const float* ad2 = (const float*)d_in[8];
    const float* b2  = (const float*)d_in[9];

    char* p = (char*)d_ws;
    auto alloc = [&](size_t bytes) { char* r = p; p += (bytes + 255) & ~(size_t)255; return r; };

    /* region 0: h1 (bf16, 61.44 MB) — dead after agg1_fused; layer-2 buffers alias it */
    char* region0 = (char*)alloc((size_t)N_NODES * HC * 2);
    unsigned short* h1 = (unsigned short*)region0;

    /* region 1: out1 (bf16, 61.44 MB); xb/W1t (dead after gemm1_mfma) alias it */
    char* region1 = (char*)alloc((size_t)N_NODES * HC * 2);
    unsigned short* out1 = (unsigned short*)region1;
    unsigned short* xb   = (unsigned short*)region1;
    unsigned short* W1t  = (unsigned short*)(region1 + (size_t)N_NODES * F_IN * 2 + 256);

    unsigned short* W2t = (unsigned short*)alloc((size_t)OUTC * HC * 2);

    float* a_src1   = (float*)alloc((size_t)N_NODES * HEADS * 4);
    float* a_dst1   = (float*)alloc((size_t)N_NODES * HEADS * 4);
    int*   deg      = (int*)alloc((size_t)(N_NODES + 1) * 4);  /* +1: alloc counter */
    int*   counter  = deg + N_NODES;
    int*   rowstart = (int*)alloc((size_t)N_NODES * 4);
    int*   cursor   = (int*)alloc((size_t)N_NODES * 4);
    int*   csr_src  = (int*)alloc((size_t)E_TOT * 4);

    /* layer-2 buffers aliased into region0 (~8 MB < 61.44 MB) */
    char* q = region0;
    auto alias = [&](size_t bytes) { char* r = q; q += (bytes + 255) & ~(size_t)255; return r; };
    float* h2      = (float*)alias((size_t)N_NODES * OUTC * 4);
    float* a_src2  = (float*)alias((size_t)N_NODES * 4);
    float* a_dst2  = (float*)alias((size_t)N_NODES * 4);

    hipMemsetAsync(deg, 0, (size_t)(N_NODES + 1) * 4, stream);

    /* fused prep: cvt_x | deg | cvt_w1t | cvt_w2t */
    prep_kernel<<<NB_PREP, 256, 0, stream>>>(x, xb, W1, W1t, W2, W2t, ei, deg);

    /* CSR build (parallel, unordered ranges) */
    alloc_kernel<<<(N_NODES + 255) / 256, 256, 0, stream>>>(deg, rowstart, cursor, counter);
    scatter_kernel<<<(E_TOT + 255) / 256, 256, 0, stream>>>(ei, cursor, csr_src);

    /* layer 1 (att dots fused into gemm1 epilogue) */
    gemm1_mfma<<<dim3(HC / 128, (N_NODES + 127) / 128), 256, 0, stream>>>(
        xb, W1t, h1, as1, ad1, a_src1, a_dst1, N_NODES);
    agg1_fused<<<N_NODES / 2, 256, 0, stream>>>(rowstart, deg, csr_src, h1, a_src1, a_dst1, b1, out1);

    /* layer 2 (h1 dead; aliased buffers now safe, stream-ordered; att2 fused into gemm2) */
    gemm2_mfma<<<(N_NODES + 127) / 128, 256, 0, stream>>>(
        out1, W2t, h2, as2, ad2, a_src2, a_dst2, N_NODES);
    agg2_lsm<<<N_NODES / 4, 256, 0, stream>>>(rowstart, deg, csr_src, h2, a_src2, a_dst2, b2, (float*)d_out);
}

// Round 11
// 321.010 us; speedup vs baseline: 15.9452x; 1.0621x over previous
//
#include <hip/hip_runtime.h>
#include <math.h>

#define N_NODES 30000
#define F_IN 256
#define E_RAW 300000
#define E_TOT (E_RAW + N_NODES)   /* 330000: edges + self loops */
#define HEADS 8
#define CH 128
#define HC 1024                   /* HEADS*CH */
#define OUTC 64
#define NEG_SLOPE 0.2f
#define CAP 64                    /* edges per LDS chunk in fused agg kernels */

typedef __attribute__((ext_vector_type(8))) short bf16x8;
typedef __attribute__((ext_vector_type(4))) float f32x4;

/* ---------- helpers ---------- */
__device__ __forceinline__ float bf2f(unsigned short u) {
    return __uint_as_float(((unsigned)u) << 16);
}
__device__ __forceinline__ unsigned short f2bf(float f) {
    unsigned b = __float_as_uint(f);
    b += 0x7FFFu + ((b >> 16) & 1u);   /* round to nearest even */
    return (unsigned short)(b >> 16);
}
__device__ __forceinline__ void edge_sd(const int* __restrict__ ei, int e, int& s, int& d) {
    if (e < E_RAW) { s = ei[e]; d = ei[E_RAW + e]; }
    else           { s = e - E_RAW; d = s; }
}
/* async global->LDS, 16B per lane; LDS dest = wave-uniform base + lane*16 */
__device__ __forceinline__ void async_cp16(const void* g, void* l) {
    __builtin_amdgcn_global_load_lds((const __attribute__((address_space(1))) void*)g,
                                     (__attribute__((address_space(3))) void*)l, 16, 0, 0);
}

/* ---------- fused prep: cvt_x | deg | cvt_w1t | cvt_w2t (independent jobs) ---------- */
#define NB_CVTX (N_NODES * F_IN / 4 / 256)      /* 7500 */
#define NB_DEG  ((E_TOT + 255) / 256)           /* 1290 */
#define NB_W1T  ((F_IN * HC + 255) / 256)       /* 1024 */
#define NB_W2T  ((HC * OUTC + 255) / 256)       /* 256 */
#define NB_PREP (NB_CVTX + NB_DEG + NB_W1T + NB_W2T)

__global__ __launch_bounds__(256)
void prep_kernel(const float* __restrict__ x, unsigned short* __restrict__ xb,
                 const float* __restrict__ W1, unsigned short* __restrict__ W1t,
                 const float* __restrict__ W2, unsigned short* __restrict__ W2t,
                 const int* __restrict__ ei, int* __restrict__ deg)
{
    const int b = blockIdx.x, t = threadIdx.x;
    if (b < NB_CVTX) {
        int i = b * 256 + t;
        const float4 v = reinterpret_cast<const float4*>(x)[i];
        ushort4 o;
        o.x = f2bf(v.x); o.y = f2bf(v.y); o.z = f2bf(v.z); o.w = f2bf(v.w);
        reinterpret_cast<ushort4*>(xb)[i] = o;
    } else if (b < NB_CVTX + NB_DEG) {
        int e = (b - NB_CVTX) * 256 + t;
        if (e < E_TOT) {
            int s, d; edge_sd(ei, e, s, d);
            atomicAdd(&deg[d], 1);
        }
    } else if (b < NB_CVTX + NB_DEG + NB_W1T) {
        int i = (b - NB_CVTX - NB_DEG) * 256 + t;
        if (i < F_IN * HC) {
            int k = i >> 10, n = i & (HC - 1);
            W1t[n * F_IN + k] = f2bf(W1[i]);
        }
    } else {
        int i = (b - NB_CVTX - NB_DEG - NB_W1T) * 256 + t;
        if (i < HC * OUTC) {
            int k = i >> 6, n = i & (OUTC - 1);
            W2t[n * HC + k] = f2bf(W2[i]);
        }
    }
}

/* ---------- layer-1 MFMA GEMM + fused attention dots ----------
   Unpadded LDS (row = 32 bf16 = 64B, ds_read_b128 pattern is bank-balanced),
   global_load_lds width-16 staging. Tail rows read OOB-in-workspace garbage
   that only reaches store-masked output rows. */
__global__ __launch_bounds__(256)
void gemm1_mfma(const unsigned short* __restrict__ A,
                const unsigned short* __restrict__ Bt,
                unsigned short* __restrict__ C,
                const float* __restrict__ att_src, const float* __restrict__ att_dst,
                float* __restrict__ a_src, float* __restrict__ a_dst, int M)
{
    __shared__ unsigned short Al[128 * 32];
    __shared__ unsigned short Bl[128 * 32];
    __shared__ float s_src[128][2];
    __shared__ float s_dst[128][2];
    const int tid  = threadIdx.x;
    const int wave = tid >> 6, lane = tid & 63;
    const int quad = lane >> 4, l16 = lane & 15;
    const int wr = (wave >> 1) * 64, wc = (wave & 1) * 64;
    const int row0 = blockIdx.y * 128;
    const int col0 = blockIdx.x * 128;

    f32x4 acc[4][4];
#pragma unroll
    for (int i = 0; i < 4; i++)
#pragma unroll
        for (int j = 0; j < 4; j++) acc[i][j] = (f32x4){0.f, 0.f, 0.f, 0.f};

    for (int k0 = 0; k0 < F_IN; k0 += 32) {
#pragma unroll
        for (int p = 0; p < 2; p++) {           /* A: 128 rows x 32 bf16 */
            int idx = tid + 256 * p;
            int r = idx >> 2, q = idx & 3;
            async_cp16(A + (size_t)(row0 + r) * F_IN + k0 + q * 8,
                       Al + (size_t)(wave * 64 + 256 * p) * 8);
        }
#pragma unroll
        for (int p = 0; p < 2; p++) {           /* B^T: 128 rows x 32 bf16 */
            int idx = tid + 256 * p;
            int r = idx >> 2, q = idx & 3;
            async_cp16(Bt + (size_t)(col0 + r) * F_IN + k0 + q * 8,
                       Bl + (size_t)(wave * 64 + 256 * p) * 8);
        }
        __syncthreads();
        bf16x8 af[4], bg[4];
#pragma unroll
        for (int i = 0; i < 4; i++)
            af[i] = *reinterpret_cast<const bf16x8*>(Al + (wr + i * 16 + l16) * 32 + quad * 8);
#pragma unroll
        for (int j = 0; j < 4; j++)
            bg[j] = *reinterpret_cast<const bf16x8*>(Bl + (wc + j * 16 + l16) * 32 + quad * 8);
#pragma unroll
        for (int i = 0; i < 4; i++)
#pragma unroll
            for (int j = 0; j < 4; j++)
                acc[i][j] = __builtin_amdgcn_mfma_f32_16x16x32_bf16(af[i], bg[j], acc[i][j], 0, 0, 0);
        __syncthreads();
    }
#pragma unroll
    for (int i = 0; i < 4; i++) {
#pragma unroll
        for (int r = 0; r < 4; r++) {
            int row = row0 + wr + i * 16 + quad * 4 + r;
            if (row >= M) continue;
#pragma unroll
            for (int j = 0; j < 4; j++) {
                int col = col0 + wc + j * 16 + l16;
                C[(size_t)row * HC + col] = f2bf(acc[i][j][r]);
            }
        }
    }
    /* fused attention dots for head = blockIdx.x */
    const float* asv = att_src + blockIdx.x * CH;
    const float* adv = att_dst + blockIdx.x * CH;
    float av[4], dv[4];
#pragma unroll
    for (int j = 0; j < 4; j++) {
        av[j] = asv[wc + j * 16 + l16];
        dv[j] = adv[wc + j * 16 + l16];
    }
#pragma unroll
    for (int i = 0; i < 4; i++) {
#pragma unroll
        for (int r = 0; r < 4; r++) {
            float ps = 0.f, pd = 0.f;
#pragma unroll
            for (int j = 0; j < 4; j++) {
                float cc = acc[i][j][r];
                ps += cc * av[j];
                pd += cc * dv[j];
            }
#pragma unroll
            for (int o = 1; o < 16; o <<= 1) {
                ps += __shfl_xor(ps, o);
                pd += __shfl_xor(pd, o);
            }
            if (l16 == 0) {
                int lr = wr + i * 16 + quad * 4 + r;
                s_src[lr][wc >> 6] = ps;
                s_dst[lr][wc >> 6] = pd;
            }
        }
    }
    __syncthreads();
    if (tid < 128) {
        int row = row0 + tid;
        if (row < M) {
            a_src[row * 8 + blockIdx.x] = s_src[tid][0] + s_src[tid][1];
            a_dst[row * 8 + blockIdx.x] = s_dst[tid][0] + s_dst[tid][1];
        }
    }
}

/* ---------- layer-2 MFMA GEMM + fused att2 dots (same staging scheme) ---------- */
__global__ __launch_bounds__(256)
void gemm2_mfma(const unsigned short* __restrict__ A,
                const unsigned short* __restrict__ Bt,
                float* __restrict__ C,
                const float* __restrict__ att_src2, const float* __restrict__ att_dst2,
                float* __restrict__ a_src2, float* __restrict__ a_dst2, int M)
{
    __shared__ unsigned short Al[128 * 32];
    __shared__ unsigned short Bl[64 * 32];
    const int tid  = threadIdx.x;
    const int wave = tid >> 6, lane = tid & 63;
    const int quad = lane >> 4, l16 = lane & 15;
    const int wr = wave * 32;
    const int row0 = blockIdx.x * 128;

    f32x4 acc[2][4];
#pragma unroll
    for (int i = 0; i < 2; i++)
#pragma unroll
        for (int j = 0; j < 4; j++) acc[i][j] = (f32x4){0.f, 0.f, 0.f, 0.f};

    for (int k0 = 0; k0 < HC; k0 += 32) {
#pragma unroll
        for (int p = 0; p < 2; p++) {           /* A: 128 rows x 32 bf16 */
            int idx = tid + 256 * p;
            int r = idx >> 2, q = idx & 3;
            async_cp16(A + (size_t)(row0 + r) * HC + k0 + q * 8,
                       Al + (size_t)(wave * 64 + 256 * p) * 8);
        }
        {                                        /* B^T: 64 rows x 32 bf16 */
            int r = tid >> 2, q = tid & 3;
            async_cp16(Bt + (size_t)r * HC + k0 + q * 8,
                       Bl + (size_t)(wave * 64) * 8);
        }
        __syncthreads();
        bf16x8 af[2], bg[4];
#pragma unroll
        for (int i = 0; i < 2; i++)
            af[i] = *reinterpret_cast<const bf16x8*>(Al + (wr + i * 16 + l16) * 32 + quad * 8);
#pragma unroll
        for (int j = 0; j < 4; j++)
            bg[j] = *reinterpret_cast<const bf16x8*>(Bl + (j * 16 + l16) * 32 + quad * 8);
#pragma unroll
        for (int i = 0; i < 2; i++)
#pragma unroll
            for (int j = 0; j < 4; j++)
                acc[i][j] = __builtin_amdgcn_mfma_f32_16x16x32_bf16(af[i], bg[j], acc[i][j], 0, 0, 0);
        __syncthreads();
    }
    float av[4], dv[4];
#pragma unroll
    for (int j = 0; j < 4; j++) {
        av[j] = att_src2[j * 16 + l16];
        dv[j] = att_dst2[j * 16 + l16];
    }
#pragma unroll
    for (int i = 0; i < 2; i++) {
#pragma unroll
        for (int r = 0; r < 4; r++) {
            int row = row0 + wr + i * 16 + quad * 4 + r;
            float ps = 0.f, pd = 0.f;
#pragma unroll
            for (int j = 0; j < 4; j++) {
                float cc = acc[i][j][r];
                int col = j * 16 + l16;
                if (row < M) C[(size_t)row * OUTC + col] = cc;
                ps += cc * av[j];
                pd += cc * dv[j];
            }
#pragma unroll
            for (int o = 1; o < 16; o <<= 1) {
                ps += __shfl_xor(ps, o);
                pd += __shfl_xor(pd, o);
            }
            if (l16 == 0 && row < M) {
                a_src2[row] = ps;
                a_dst2[row] = pd;
            }
        }
    }
}

/* ---------- CSR build ---------- */
__global__ __launch_bounds__(256)
void alloc_kernel(const int* __restrict__ deg, int* __restrict__ rowstart,
                  int* __restrict__ cursor, int* __restrict__ counter)
{
    int d = blockIdx.x * 256 + threadIdx.x;
    int lane = threadIdx.x & 63;
    int v = (d < N_NODES) ? deg[d] : 0;
    int x = v;
#pragma unroll
    for (int o = 1; o < 64; o <<= 1) {
        int y = __shfl_up(x, o);
        if (lane >= o) x += y;
    }
    int excl = x - v;
    int total = __shfl(x, 63);
    int base = 0;
    if (lane == 63) base = atomicAdd(counter, total);
    base = __shfl(base, 63);
    if (d < N_NODES) {
        rowstart[d] = base + excl;
        cursor[d]   = base + excl;
    }
}

__global__ void scatter_kernel(const int* __restrict__ ei, int* __restrict__ cursor,
                               int* __restrict__ csr_src)
{
    int e = blockIdx.x * 256 + threadIdx.x;
    if (e >= E_TOT) return;
    int s, d; edge_sd(ei, e, s, d);
    int pos = atomicAdd(&cursor[d], 1);
    csr_src[pos] = s;
}

/* ---------- layer-1 fused softmax+aggregation, bias+ELU, bf16 out ----------
   2 nodes per 256-block; 128 threads/node; 1-ahead pipelined gather
   (2-deep tested in R10: neutral-to-worse — service-rate bound). */
__global__ __launch_bounds__(256)
void agg1_fused(const int* __restrict__ rowstart, const int* __restrict__ degv,
                const int* __restrict__ csr_src,
                const unsigned short* __restrict__ h1,
                const float* __restrict__ a_src1, const float* __restrict__ a_dst1,
                const float* __restrict__ b1, unsigned short* __restrict__ out1)
{
    const int t   = threadIdx.x;
    const int sub = t >> 7;
    const int tl  = t & 127;
    const int h   = tl >> 4;
    const int l   = tl & 15;
    const int d   = blockIdx.x * 2 + sub;

    __shared__ float exps[2][CAP * 8];
    __shared__ int   srcs[2][CAP];
    __shared__ int   maxdeg_s;

    const int start = rowstart[d];
    const int deg   = degv[d];

    if (t == 0) maxdeg_s = 0;
    __syncthreads();
    if (tl == 0) atomicMax(&maxdeg_s, deg);
    __syncthreads();
    const int maxdeg = maxdeg_s;

    const float adst = a_dst1[d * 8 + h];
    const uint4* __restrict__ h1v = reinterpret_cast<const uint4*>(h1);

    float denom_part = 0.f;
    float acc[8];
#pragma unroll
    for (int k = 0; k < 8; k++) acc[k] = 0.f;

    for (int c0 = 0; c0 < maxdeg; c0 += CAP) {
        const int cend = min(deg - c0, CAP);
        for (int c = l; c < cend; c += 16) {
            int s = csr_src[start + c0 + c];
            if (h == 0) srcs[sub][c] = s;
            float a = a_src1[s * 8 + h] + adst;
            float v = a > 0.f ? a : NEG_SLOPE * a;
            float ex = __expf(v);
            exps[sub][c * 8 + h] = ex;
            denom_part += ex;
        }
        __syncthreads();
        if (cend > 0) {
            int   s_cur = srcs[sub][0];
            float w_cur = exps[sub][h];
            uint4 u_cur = h1v[(size_t)s_cur * (HC / 8) + tl];
            for (int c = 0; c < cend; c++) {
                int   s_nxt = 0; float w_nxt = 0.f; uint4 u_nxt;
                if (c + 1 < cend) {
                    s_nxt = srcs[sub][c + 1];
                    w_nxt = exps[sub][(c + 1) * 8 + h];
                    u_nxt = h1v[(size_t)s_nxt * (HC / 8) + tl];
                }
                acc[0] += w_cur * __uint_as_float(u_cur.x << 16);
                acc[1] += w_cur * __uint_as_float(u_cur.x & 0xFFFF0000u);
                acc[2] += w_cur * __uint_as_float(u_cur.y << 16);
                acc[3] += w_cur * __uint_as_float(u_cur.y & 0xFFFF0000u);
                acc[4] += w_cur * __uint_as_float(u_cur.z << 16);
                acc[5] += w_cur * __uint_as_float(u_cur.z & 0xFFFF0000u);
                acc[6] += w_cur * __uint_as_float(u_cur.w << 16);
                acc[7] += w_cur * __uint_as_float(u_cur.w & 0xFFFF0000u);
                s_cur = s_nxt; w_cur = w_nxt; u_cur = u_nxt;
            }
        }
        __syncthreads();
    }
#pragma unroll
    for (int o = 8; o > 0; o >>= 1) denom_part += __shfl_xor(denom_part, o);
    const float dinv = 1.f / (denom_part + 1e-16f);

    float4 b0 = reinterpret_cast<const float4*>(b1)[tl * 2];
    float4 b4 = reinterpret_cast<const float4*>(b1)[tl * 2 + 1];
    float v[8];
    v[0] = acc[0] * dinv + b0.x; v[1] = acc[1] * dinv + b0.y;
    v[2] = acc[2] * dinv + b0.z; v[3] = acc[3] * dinv + b0.w;
    v[4] = acc[4] * dinv + b4.x; v[5] = acc[5] * dinv + b4.y;
    v[6] = acc[6] * dinv + b4.z; v[7] = acc[7] * dinv + b4.w;
#pragma unroll
    for (int k = 0; k < 8; k++) v[k] = v[k] > 0.f ? v[k] : __expf(v[k]) - 1.f;
    uint4 o;
    o.x = (unsigned)f2bf(v[0]) | ((unsigned)f2bf(v[1]) << 16);
    o.y = (unsigned)f2bf(v[2]) | ((unsigned)f2bf(v[3]) << 16);
    o.z = (unsigned)f2bf(v[4]) | ((unsigned)f2bf(v[5]) << 16);
    o.w = (unsigned)f2bf(v[6]) | ((unsigned)f2bf(v[7]) << 16);
    reinterpret_cast<uint4*>(out1 + (size_t)d * HC)[tl] = o;
}

/* ---------- layer-2 fused softmax+agg + bias + log_softmax ----------
   4 nodes per 256-block; per node: 2 edges in flight (lane halves),
   each lane owns a channel pair (float2 loads). */
__global__ __launch_bounds__(256)
void agg2_lsm(const int* __restrict__ rowstart, const int* __restrict__ degv,
              const int* __restrict__ csr_src,
              const float* __restrict__ h2,
              const float* __restrict__ a_src2, const float* __restrict__ a_dst2,
              const float* __restrict__ b2, float* __restrict__ out)
{
    const int t = threadIdx.x;
    const int sub  = t >> 6;
    const int lane = t & 63;
    const int half = lane >> 5;        /* 0: even edge, 1: odd edge */
    const int cl   = lane & 31;        /* channel-pair index */
    const int d = blockIdx.x * 4 + sub;

    __shared__ float exs[4][CAP];
    __shared__ int   ss[4][CAP];
    __shared__ int   maxdeg_s;

    const int start = rowstart[d];
    const int deg   = degv[d];

    if (t == 0) maxdeg_s = 0;
    __syncthreads();
    if (lane == 0) atomicMax(&maxdeg_s, deg);
    __syncthreads();
    const int maxdeg = maxdeg_s;

    const float adst = a_dst2[d];
    const float2* __restrict__ h2v = reinterpret_cast<const float2*>(h2);
    float denom_part = 0.f;
    float2 acc = make_float2(0.f, 0.f);

    for (int c0 = 0; c0 < maxdeg; c0 += CAP) {
        const int cend = min(deg - c0, CAP);
        for (int c = lane; c < cend; c += 64) {
            int s = csr_src[start + c0 + c];
            ss[sub][c] = s;
            float a = a_src2[s] + adst;
            float v = a > 0.f ? a : NEG_SLOPE * a;
            float ex = __expf(v);
            exs[sub][c] = ex;
            denom_part += ex;
        }
        __syncthreads();
        if (cend > 0) {
            int   cc = half;
            float w0 = (cc < cend) ? exs[sub][cc] : 0.f;
            int   s0 = (cc < cend) ? ss[sub][cc] : ss[sub][0];
            float2 u0 = h2v[(size_t)s0 * 32 + cl];
            for (int c = 0; c + 2 < cend; c += 2) {
                int cc1 = c + 2 + half;
                float w1 = (cc1 < cend) ? exs[sub][cc1] : 0.f;
                int   s1 = (cc1 < cend) ? ss[sub][cc1] : ss[sub][0];
                float2 u1 = h2v[(size_t)s1 * 32 + cl];
                acc.x += w0 * u0.x; acc.y += w0 * u0.y;
                w0 = w1; s0 = s1; u0 = u1;
            }
            acc.x += w0 * u0.x; acc.y += w0 * u0.y;
        }
        __syncthreads();
    }
    /* combine edge-halves: lane l and l^32 hold the same channel pair */
    acc.x += __shfl_xor(acc.x, 32);
    acc.y += __shfl_xor(acc.y, 32);
#pragma unroll
    for (int o = 32; o > 0; o >>= 1) denom_part += __shfl_xor(denom_part, o);
    const float dinv = 1.f / (denom_part + 1e-16f);

    float2 bb = reinterpret_cast<const float2*>(b2)[cl];
    float vx = acc.x * dinv + bb.x;
    float vy = acc.y * dinv + bb.y;
    float m = fmaxf(vx, vy);
#pragma unroll
    for (int o = 16; o > 0; o >>= 1) m = fmaxf(m, __shfl_xor(m, o));
    float ex = __expf(vx - m) + __expf(vy - m);
    float ssum = ex;
#pragma unroll
    for (int o = 16; o > 0; o >>= 1) ssum += __shfl_xor(ssum, o);
    if (half == 0) {
        float lg = __logf(ssum);
        reinterpret_cast<float2*>(out + (size_t)d * OUTC)[cl] =
            make_float2(vx - m - lg, vy - m - lg);
    }
}

extern "C" void kernel_launch(void* const* d_in, const int* in_sizes, int n_in,
                              void* d_out, int out_size, void* d_ws, size_t ws_size,
                              hipStream_t stream)
{
    const float* x   = (const float*)d_in[0];
    const int*   ei  = (const int*)d_in[1];
    const float* W1  = (const float*)d_in[2];
    const float* as1 = (const float*)d_in[3];
    const float* ad1 = (const float*)d_in[4];
    const float* b1  = (const float*)d_in[5];
    const float* W2  = (const float*)d_in[6];
    const float* as2 = (const float*)d_in[7];
    const float* ad2 = (const float*)d_in[8];
    const float* b2  = (const float*)d_in[9];

    char* p = (char*)d_ws;
    auto alloc = [&](size_t bytes) { char* r = p; p += (bytes + 255) & ~(size_t)255; return r; };

    /* region 0: h1 (bf16, 61.44 MB) — dead after agg1_fused; layer-2 buffers alias it */
    char* region0 = (char*)alloc((size_t)N_NODES * HC * 2);
    unsigned short* h1 = (unsigned short*)region0;

    /* region 1: out1 (bf16, 61.44 MB); xb/W1t (dead after gemm1_mfma) alias it */
    char* region1 = (char*)alloc((size_t)N_NODES * HC * 2);
    unsigned short* out1 = (unsigned short*)region1;
    unsigned short* xb   = (unsigned short*)region1;
    unsigned short* W1t  = (unsigned short*)(region1 + (size_t)N_NODES * F_IN * 2 + 256);

    unsigned short* W2t = (unsigned short*)alloc((size_t)OUTC * HC * 2);

    float* a_src1   = (float*)alloc((size_t)N_NODES * HEADS * 4);
    float* a_dst1   = (float*)alloc((size_t)N_NODES * HEADS * 4);
    int*   deg      = (int*)alloc((size_t)(N_NODES + 1) * 4);  /* +1: alloc counter */
    int*   counter  = deg + N_NODES;
    int*   rowstart = (int*)alloc((size_t)N_NODES * 4);
    int*   cursor   = (int*)alloc((size_t)N_NODES * 4);
    int*   csr_src  = (int*)alloc((size_t)E_TOT * 4);

    /* layer-2 buffers aliased into region0 (~8 MB < 61.44 MB) */
    char* q = region0;
    auto alias = [&](size_t bytes) { char* r = q; q += (bytes + 255) & ~(size_t)255; return r; };
    float* h2      = (float*)alias((size_t)N_NODES * OUTC * 4);
    float* a_src2  = (float*)alias((size_t)N_NODES * 4);
    float* a_dst2  = (float*)alias((size_t)N_NODES * 4);

    hipMemsetAsync(deg, 0, (size_t)(N_NODES + 1) * 4, stream);

    /* fused prep: cvt_x | deg | cvt_w1t | cvt_w2t */
    prep_kernel<<<NB_PREP, 256, 0, stream>>>(x, xb, W1, W1t, W2, W2t, ei, deg);

    /* CSR build (parallel, unordered ranges) */
    alloc_kernel<<<(N_NODES + 255) / 256, 256, 0, stream>>>(deg, rowstart, cursor, counter);
    scatter_kernel<<<(E_TOT + 255) / 256, 256, 0, stream>>>(ei, cursor, csr_src);

    /* layer 1 (att dots fused into gemm1 epilogue) */
    gemm1_mfma<<<dim3(HC / 128, (N_NODES + 127) / 128), 256, 0, stream>>>(
        xb, W1t, h1, as1, ad1, a_src1, a_dst1, N_NODES);
    agg1_fused<<<N_NODES / 2, 256, 0, stream>>>(rowstart, deg, csr_src, h1, a_src1, a_dst1, b1, out1);

    /* layer 2 (h1 dead; aliased buffers now safe, stream-ordered; att2 fused into gemm2) */
    gemm2_mfma<<<(N_NODES + 127) / 128, 256, 0, stream>>>(
        out1, W2t, h2, as2, ad2, a_src2, a_dst2, N_NODES);
    agg2_lsm<<<N_NODES / 4, 256, 0, stream>>>(rowstart, deg, csr_src, h2, a_src2, a_dst2, b2, (float*)d_out);
}

// Round 12
// 275.556 us; speedup vs baseline: 18.5753x; 1.1650x over previous
//
#include <hip/hip_runtime.h>
#include <math.h>

#define N_NODES 30000
#define F_IN 256
#define E_RAW 300000
#define E_TOT (E_RAW + N_NODES)   /* 330000: edges + self loops */
#define HEADS 8
#define CH 128
#define HC 1024                   /* HEADS*CH */
#define OUTC 64
#define NEG_SLOPE 0.2f
#define CAP 64                    /* edges per LDS chunk in fused agg kernels */

typedef __attribute__((ext_vector_type(8))) short bf16x8;
typedef __attribute__((ext_vector_type(4))) float f32x4;
typedef __attribute__((ext_vector_type(2))) float f32x2;

/* ---------- helpers ---------- */
__device__ __forceinline__ float bf2f(unsigned short u) {
    return __uint_as_float(((unsigned)u) << 16);
}
__device__ __forceinline__ unsigned short f2bf(float f) {
    unsigned b = __float_as_uint(f);
    b += 0x7FFFu + ((b >> 16) & 1u);   /* round to nearest even */
    return (unsigned short)(b >> 16);
}
__device__ __forceinline__ void edge_sd(const int* __restrict__ ei, int e, int& s, int& d) {
    if (e < E_RAW) { s = ei[e]; d = ei[E_RAW + e]; }
    else           { s = e - E_RAW; d = s; }
}
/* async global->LDS, 16B per lane; LDS dest = wave-uniform base + lane*16 */
__device__ __forceinline__ void async_cp16(const void* g, void* l) {
    __builtin_amdgcn_global_load_lds((const __attribute__((address_space(1))) void*)g,
                                     (__attribute__((address_space(3))) void*)l, 16, 0, 0);
}
/* fp8 slot permutation: slot s -> original channel */
__device__ __forceinline__ int slotP(int s) {
    return ((s >> 6) << 6) + ((s >> 2) & 15) + ((s & 3) << 4);
}

/* ---------- fused prep: cvt_x | deg | cvt_w1t | cvt_w2t (independent jobs) ---------- */
#define NB_CVTX (N_NODES * F_IN / 4 / 256)      /* 7500 */
#define NB_DEG  ((E_TOT + 255) / 256)           /* 1290 */
#define NB_W1T  ((F_IN * HC + 255) / 256)       /* 1024 */
#define NB_W2T  ((HC * OUTC + 255) / 256)       /* 256 */
#define NB_PREP (NB_CVTX + NB_DEG + NB_W1T + NB_W2T)

__global__ __launch_bounds__(256)
void prep_kernel(const float* __restrict__ x, unsigned short* __restrict__ xb,
                 const float* __restrict__ W1, unsigned short* __restrict__ W1t,
                 const float* __restrict__ W2, unsigned short* __restrict__ W2t,
                 const int* __restrict__ ei, int* __restrict__ deg)
{
    const int b = blockIdx.x, t = threadIdx.x;
    if (b < NB_CVTX) {
        int i = b * 256 + t;
        const float4 v = reinterpret_cast<const float4*>(x)[i];
        ushort4 o;
        o.x = f2bf(v.x); o.y = f2bf(v.y); o.z = f2bf(v.z); o.w = f2bf(v.w);
        reinterpret_cast<ushort4*>(xb)[i] = o;
    } else if (b < NB_CVTX + NB_DEG) {
        int e = (b - NB_CVTX) * 256 + t;
        if (e < E_TOT) {
            int s, d; edge_sd(ei, e, s, d);
            atomicAdd(&deg[d], 1);
        }
    } else if (b < NB_CVTX + NB_DEG + NB_W1T) {
        int i = (b - NB_CVTX - NB_DEG) * 256 + t;
        if (i < F_IN * HC) {
            int k = i >> 10, n = i & (HC - 1);
            W1t[n * F_IN + k] = f2bf(W1[i]);
        }
    } else {
        /* W2t[n][s] = W2[P(s)][n] — k-axis carries the out1 slot permutation */
        int i = (b - NB_CVTX - NB_DEG - NB_W1T) * 256 + t;
        if (i < HC * OUTC) {
            int s = i >> 6, n = i & (OUTC - 1);
            W2t[n * HC + s] = f2bf(W2[slotP(s) * OUTC + n]);
        }
    }
}

/* ---------- layer-1 MFMA GEMM + fused attention dots, fp8 slot-layout C ---------- */
__global__ __launch_bounds__(256)
void gemm1_mfma(const unsigned short* __restrict__ A,
                const unsigned short* __restrict__ Bt,
                unsigned* __restrict__ Cp,      /* [M][256] dwords, fp8 slots */
                const float* __restrict__ att_src, const float* __restrict__ att_dst,
                float* __restrict__ a_src, float* __restrict__ a_dst, int M)
{
    __shared__ unsigned short Al[128 * 32];
    __shared__ unsigned short Bl[128 * 32];
    __shared__ float s_src[128][2];
    __shared__ float s_dst[128][2];
    const int tid  = threadIdx.x;
    const int wave = tid >> 6, lane = tid & 63;
    const int quad = lane >> 4, l16 = lane & 15;
    const int wr = (wave >> 1) * 64, wc = (wave & 1) * 64;
    const int row0 = blockIdx.y * 128;
    const int col0 = blockIdx.x * 128;

    f32x4 acc[4][4];
#pragma unroll
    for (int i = 0; i < 4; i++)
#pragma unroll
        for (int j = 0; j < 4; j++) acc[i][j] = (f32x4){0.f, 0.f, 0.f, 0.f};

    for (int k0 = 0; k0 < F_IN; k0 += 32) {
#pragma unroll
        for (int p = 0; p < 2; p++) {           /* A: 128 rows x 32 bf16 */
            int idx = tid + 256 * p;
            int r = idx >> 2, q = idx & 3;
            async_cp16(A + (size_t)(row0 + r) * F_IN + k0 + q * 8,
                       Al + (size_t)(wave * 64 + 256 * p) * 8);
        }
#pragma unroll
        for (int p = 0; p < 2; p++) {           /* B^T: 128 rows x 32 bf16 */
            int idx = tid + 256 * p;
            int r = idx >> 2, q = idx & 3;
            async_cp16(Bt + (size_t)(col0 + r) * F_IN + k0 + q * 8,
                       Bl + (size_t)(wave * 64 + 256 * p) * 8);
        }
        __syncthreads();
        bf16x8 af[4], bg[4];
#pragma unroll
        for (int i = 0; i < 4; i++)
            af[i] = *reinterpret_cast<const bf16x8*>(Al + (wr + i * 16 + l16) * 32 + quad * 8);
#pragma unroll
        for (int j = 0; j < 4; j++)
            bg[j] = *reinterpret_cast<const bf16x8*>(Bl + (wc + j * 16 + l16) * 32 + quad * 8);
#pragma unroll
        for (int i = 0; i < 4; i++)
#pragma unroll
            for (int j = 0; j < 4; j++)
                acc[i][j] = __builtin_amdgcn_mfma_f32_16x16x32_bf16(af[i], bg[j], acc[i][j], 0, 0, 0);
        __syncthreads();
    }
    /* C write: pack 4 cols (j=0..3, stride 16) into one fp8 dword at slot-dword D */
    const int D = ((col0 + wc) >> 6) * 16 + l16;
#pragma unroll
    for (int i = 0; i < 4; i++) {
#pragma unroll
        for (int r = 0; r < 4; r++) {
            int row = row0 + wr + i * 16 + quad * 4 + r;
            if (row >= M) continue;
            int w8 = __builtin_amdgcn_cvt_pk_fp8_f32(acc[i][0][r], acc[i][1][r], 0, false);
            w8 = __builtin_amdgcn_cvt_pk_fp8_f32(acc[i][2][r], acc[i][3][r], w8, true);
            Cp[(size_t)row * 256 + D] = (unsigned)w8;
        }
    }
    /* fused attention dots for head = blockIdx.x */
    const float* asv = att_src + blockIdx.x * CH;
    const float* adv = att_dst + blockIdx.x * CH;
    float av[4], dv[4];
#pragma unroll
    for (int j = 0; j < 4; j++) {
        av[j] = asv[wc + j * 16 + l16];
        dv[j] = adv[wc + j * 16 + l16];
    }
#pragma unroll
    for (int i = 0; i < 4; i++) {
#pragma unroll
        for (int r = 0; r < 4; r++) {
            float ps = 0.f, pd = 0.f;
#pragma unroll
            for (int j = 0; j < 4; j++) {
                float cc = acc[i][j][r];
                ps += cc * av[j];
                pd += cc * dv[j];
            }
#pragma unroll
            for (int o = 1; o < 16; o <<= 1) {
                ps += __shfl_xor(ps, o);
                pd += __shfl_xor(pd, o);
            }
            if (l16 == 0) {
                int lr = wr + i * 16 + quad * 4 + r;
                s_src[lr][wc >> 6] = ps;
                s_dst[lr][wc >> 6] = pd;
            }
        }
    }
    __syncthreads();
    if (tid < 128) {
        int row = row0 + tid;
        if (row < M) {
            a_src[row * 8 + blockIdx.x] = s_src[tid][0] + s_src[tid][1];
            a_dst[row * 8 + blockIdx.x] = s_dst[tid][0] + s_dst[tid][1];
        }
    }
}

/* ---------- layer-2 MFMA GEMM + fused att2 dots; A = out1 (bf16, slot layout),
   W2t k-axis carries the same permutation; C (h2) stored bf16 ---------- */
__global__ __launch_bounds__(256)
void gemm2_mfma(const unsigned short* __restrict__ A,
                const unsigned short* __restrict__ Bt,
                unsigned short* __restrict__ C,
                const float* __restrict__ att_src2, const float* __restrict__ att_dst2,
                float* __restrict__ a_src2, float* __restrict__ a_dst2, int M)
{
    __shared__ unsigned short Al[128 * 32];
    __shared__ unsigned short Bl[64 * 32];
    const int tid  = threadIdx.x;
    const int wave = tid >> 6, lane = tid & 63;
    const int quad = lane >> 4, l16 = lane & 15;
    const int wr = wave * 32;
    const int row0 = blockIdx.x * 128;

    f32x4 acc[2][4];
#pragma unroll
    for (int i = 0; i < 2; i++)
#pragma unroll
        for (int j = 0; j < 4; j++) acc[i][j] = (f32x4){0.f, 0.f, 0.f, 0.f};

    for (int k0 = 0; k0 < HC; k0 += 32) {
#pragma unroll
        for (int p = 0; p < 2; p++) {
            int idx = tid + 256 * p;
            int r = idx >> 2, q = idx & 3;
            async_cp16(A + (size_t)(row0 + r) * HC + k0 + q * 8,
                       Al + (size_t)(wave * 64 + 256 * p) * 8);
        }
        {
            int r = tid >> 2, q = tid & 3;
            async_cp16(Bt + (size_t)r * HC + k0 + q * 8,
                       Bl + (size_t)(wave * 64) * 8);
        }
        __syncthreads();
        bf16x8 af[2], bg[4];
#pragma unroll
        for (int i = 0; i < 2; i++)
            af[i] = *reinterpret_cast<const bf16x8*>(Al + (wr + i * 16 + l16) * 32 + quad * 8);
#pragma unroll
        for (int j = 0; j < 4; j++)
            bg[j] = *reinterpret_cast<const bf16x8*>(Bl + (j * 16 + l16) * 32 + quad * 8);
#pragma unroll
        for (int i = 0; i < 2; i++)
#pragma unroll
            for (int j = 0; j < 4; j++)
                acc[i][j] = __builtin_amdgcn_mfma_f32_16x16x32_bf16(af[i], bg[j], acc[i][j], 0, 0, 0);
        __syncthreads();
    }
    float av[4], dv[4];
#pragma unroll
    for (int j = 0; j < 4; j++) {
        av[j] = att_src2[j * 16 + l16];
        dv[j] = att_dst2[j * 16 + l16];
    }
#pragma unroll
    for (int i = 0; i < 2; i++) {
#pragma unroll
        for (int r = 0; r < 4; r++) {
            int row = row0 + wr + i * 16 + quad * 4 + r;
            float ps = 0.f, pd = 0.f;
#pragma unroll
            for (int j = 0; j < 4; j++) {
                float cc = acc[i][j][r];
                int col = j * 16 + l16;
                if (row < M) C[(size_t)row * OUTC + col] = f2bf(cc);
                ps += cc * av[j];
                pd += cc * dv[j];
            }
#pragma unroll
            for (int o = 1; o < 16; o <<= 1) {
                ps += __shfl_xor(ps, o);
                pd += __shfl_xor(pd, o);
            }
            if (l16 == 0 && row < M) {
                a_src2[row] = ps;
                a_dst2[row] = pd;
            }
        }
    }
}

/* ---------- CSR build ---------- */
__global__ __launch_bounds__(256)
void alloc_kernel(const int* __restrict__ deg, int* __restrict__ rowstart,
                  int* __restrict__ cursor, int* __restrict__ counter)
{
    int d = blockIdx.x * 256 + threadIdx.x;
    int lane = threadIdx.x & 63;
    int v = (d < N_NODES) ? deg[d] : 0;
    int x = v;
#pragma unroll
    for (int o = 1; o < 64; o <<= 1) {
        int y = __shfl_up(x, o);
        if (lane >= o) x += y;
    }
    int excl = x - v;
    int total = __shfl(x, 63);
    int base = 0;
    if (lane == 63) base = atomicAdd(counter, total);
    base = __shfl(base, 63);
    if (d < N_NODES) {
        rowstart[d] = base + excl;
        cursor[d]   = base + excl;
    }
}

__global__ void scatter_kernel(const int* __restrict__ ei, int* __restrict__ cursor,
                               int* __restrict__ csr_src)
{
    int e = blockIdx.x * 256 + threadIdx.x;
    if (e >= E_TOT) return;
    int s, d; edge_sd(ei, e, s, d);
    int pos = atomicAdd(&cursor[d], 1);
    csr_src[pos] = s;
}

/* ---------- layer-1 fused softmax+aggregation, bias+ELU ----------
   fp8 h1 (slot layout): 4 nodes per 256-block, 64 threads/node,
   thread owns 16 fp8 channels (uint4 load) all within one head. */
__global__ __launch_bounds__(256)
void agg1_fused(const int* __restrict__ rowstart, const int* __restrict__ degv,
                const int* __restrict__ csr_src,
                const unsigned* __restrict__ h1p,     /* [N][256] fp8 dwords */
                const float* __restrict__ a_src1, const float* __restrict__ a_dst1,
                const float* __restrict__ b1, unsigned short* __restrict__ out1)
{
    const int t   = threadIdx.x;
    const int sub = t >> 6;            /* node within block: 0..3 */
    const int tl  = t & 63;            /* thread within node */
    const int h   = tl >> 3;           /* head (all 16 channels of tl in this head) */
    const int d   = blockIdx.x * 4 + sub;

    __shared__ float exps[4][CAP * 8];
    __shared__ int   srcs[4][CAP];
    __shared__ int   maxdeg_s;

    const int start = rowstart[d];
    const int deg   = degv[d];

    if (t == 0) maxdeg_s = 0;
    __syncthreads();
    if (tl == 0) atomicMax(&maxdeg_s, deg);
    __syncthreads();
    const int maxdeg = maxdeg_s;

    const float adst = a_dst1[d * 8 + h];
    const uint4* __restrict__ h1v = reinterpret_cast<const uint4*>(h1p);  /* row = 64 uint4 */

    float denom_part = 0.f;
    float acc[16];
#pragma unroll
    for (int k = 0; k < 16; k++) acc[k] = 0.f;

    for (int c0 = 0; c0 < maxdeg; c0 += CAP) {
        const int cend = min(deg - c0, CAP);
        /* phase 1: exps for my head; 8 lanes per head stride the chunk */
        for (int c = (tl & 7); c < cend; c += 8) {
            int s = csr_src[start + c0 + c];
            if (h == 0) srcs[sub][c] = s;
            float a = a_src1[s * 8 + h] + adst;
            float v = a > 0.f ? a : NEG_SLOPE * a;
            float ex = __expf(v);
            exps[sub][c * 8 + h] = ex;
            denom_part += ex;
        }
        __syncthreads();
        /* phase 2: 1-ahead pipelined fp8 gather */
        if (cend > 0) {
            int   s_cur = srcs[sub][0];
            float w_cur = exps[sub][h];
            uint4 u_cur = h1v[(size_t)s_cur * 64 + tl];
            for (int c = 0; c < cend; c++) {
                int   s_nxt = 0; float w_nxt = 0.f; uint4 u_nxt;
                if (c + 1 < cend) {
                    s_nxt = srcs[sub][c + 1];
                    w_nxt = exps[sub][(c + 1) * 8 + h];
                    u_nxt = h1v[(size_t)s_nxt * 64 + tl];
                }
#pragma unroll
                for (int dw = 0; dw < 4; dw++) {
                    unsigned wd = (&u_cur.x)[dw];
                    f32x2 lo = __builtin_amdgcn_cvt_pk_f32_fp8((int)wd, false);
                    f32x2 hi = __builtin_amdgcn_cvt_pk_f32_fp8((int)wd, true);
                    acc[dw * 4 + 0] += w_cur * lo.x;
                    acc[dw * 4 + 1] += w_cur * lo.y;
                    acc[dw * 4 + 2] += w_cur * hi.x;
                    acc[dw * 4 + 3] += w_cur * hi.y;
                }
                s_cur = s_nxt; w_cur = w_nxt; u_cur = u_nxt;
            }
        }
        __syncthreads();
    }
    /* denominator: reduce over the 8 lanes of this head */
#pragma unroll
    for (int o = 1; o < 8; o <<= 1) denom_part += __shfl_xor(denom_part, o);
    const float dinv = 1.f / (denom_part + 1e-16f);

    /* bias (gathered at original channels) + ELU, write bf16 slots 16tl..16tl+15 */
    unsigned short ov[16];
#pragma unroll
    for (int e = 0; e < 16; e++) {
        float v = acc[e] * dinv + b1[slotP(16 * tl + e)];
        v = v > 0.f ? v : __expf(v) - 1.f;
        ov[e] = f2bf(v);
    }
    uint4* op = reinterpret_cast<uint4*>(out1 + (size_t)d * HC + 16 * tl);
    op[0] = *reinterpret_cast<uint4*>(&ov[0]);
    op[1] = *reinterpret_cast<uint4*>(&ov[8]);
}

/* ---------- layer-2 fused softmax+agg + bias + log_softmax ----------
   4 nodes per 256-block; 2 edges in flight (lane halves); bf16 h2,
   each lane owns a channel pair (uint load). */
__global__ __launch_bounds__(256)
void agg2_lsm(const int* __restrict__ rowstart, const int* __restrict__ degv,
              const int* __restrict__ csr_src,
              const unsigned short* __restrict__ h2,
              const float* __restrict__ a_src2, const float* __restrict__ a_dst2,
              const float* __restrict__ b2, float* __restrict__ out)
{
    const int t = threadIdx.x;
    const int sub  = t >> 6;
    const int lane = t & 63;
    const int half = lane >> 5;        /* 0: even edge, 1: odd edge */
    const int cl   = lane & 31;        /* channel-pair index */
    const int d = blockIdx.x * 4 + sub;

    __shared__ float exs[4][CAP];
    __shared__ int   ss[4][CAP];
    __shared__ int   maxdeg_s;

    const int start = rowstart[d];
    const int deg   = degv[d];

    if (t == 0) maxdeg_s = 0;
    __syncthreads();
    if (lane == 0) atomicMax(&maxdeg_s, deg);
    __syncthreads();
    const int maxdeg = maxdeg_s;

    const float adst = a_dst2[d];
    const unsigned* __restrict__ h2v = reinterpret_cast<const unsigned*>(h2);
    float denom_part = 0.f;
    float accx = 0.f, accy = 0.f;

    for (int c0 = 0; c0 < maxdeg; c0 += CAP) {
        const int cend = min(deg - c0, CAP);
        for (int c = lane; c < cend; c += 64) {
            int s = csr_src[start + c0 + c];
            ss[sub][c] = s;
            float a = a_src2[s] + adst;
            float v = a > 0.f ? a : NEG_SLOPE * a;
            float ex = __expf(v);
            exs[sub][c] = ex;
            denom_part += ex;
        }
        __syncthreads();
        if (cend > 0) {
            int   cc = half;
            float w0 = (cc < cend) ? exs[sub][cc] : 0.f;
            int   s0 = (cc < cend) ? ss[sub][cc] : ss[sub][0];
            unsigned u0 = h2v[(size_t)s0 * 32 + cl];
            for (int c = 0; c + 2 < cend; c += 2) {
                int cc1 = c + 2 + half;
                float w1 = (cc1 < cend) ? exs[sub][cc1] : 0.f;
                int   s1 = (cc1 < cend) ? ss[sub][cc1] : ss[sub][0];
                unsigned u1 = h2v[(size_t)s1 * 32 + cl];
                accx += w0 * __uint_as_float(u0 << 16);
                accy += w0 * __uint_as_float(u0 & 0xFFFF0000u);
                w0 = w1; s0 = s1; u0 = u1;
            }
            accx += w0 * __uint_as_float(u0 << 16);
            accy += w0 * __uint_as_float(u0 & 0xFFFF0000u);
        }
        __syncthreads();
    }
    /* combine edge-halves: lane l and l^32 hold the same channel pair */
    accx += __shfl_xor(accx, 32);
    accy += __shfl_xor(accy, 32);
#pragma unroll
    for (int o = 32; o > 0; o >>= 1) denom_part += __shfl_xor(denom_part, o);
    const float dinv = 1.f / (denom_part + 1e-16f);

    float2 bb = reinterpret_cast<const float2*>(b2)[cl];
    float vx = accx * dinv + bb.x;
    float vy = accy * dinv + bb.y;
    float m = fmaxf(vx, vy);
#pragma unroll
    for (int o = 16; o > 0; o >>= 1) m = fmaxf(m, __shfl_xor(m, o));
    float ex = __expf(vx - m) + __expf(vy - m);
    float ssum = ex;
#pragma unroll
    for (int o = 16; o > 0; o >>= 1) ssum += __shfl_xor(ssum, o);
    if (half == 0) {
        float lg = __logf(ssum);
        reinterpret_cast<float2*>(out + (size_t)d * OUTC)[cl] =
            make_float2(vx - m - lg, vy - m - lg);
    }
}

extern "C" void kernel_launch(void* const* d_in, const int* in_sizes, int n_in,
                              void* d_out, int out_size, void* d_ws, size_t ws_size,
                              hipStream_t stream)
{
    const float* x   = (const float*)d_in[0];
    const int*   ei  = (const int*)d_in[1];
    const float* W1  = (const float*)d_in[2];
    const float* as1 = (const float*)d_in[3];
    const float* ad1 = (const float*)d_in[4];
    const float* b1  = (const float*)d_in[5];
    const float* W2  = (const float*)d_in[6];
    const float* as2 = (const float*)d_in[7];
    const float* ad2 = (const float*)d_in[8];
    const float* b2  = (const float*)d_in[9];

    char* p = (char*)d_ws;
    auto alloc = [&](size_t bytes) { char* r = p; p += (bytes + 255) & ~(size_t)255; return r; };

    /* region 0: h1p (fp8, 30.72 MB; sized 61.44) — dead after agg1; layer-2 aliases it */
    char* region0 = (char*)alloc((size_t)N_NODES * HC * 2);
    unsigned* h1p = (unsigned*)region0;

    /* region 1: out1 (bf16 slot-layout, 61.44 MB); xb/W1t (dead after gemm1) alias it */
    char* region1 = (char*)alloc((size_t)N_NODES * HC * 2);
    unsigned short* out1 = (unsigned short*)region1;
    unsigned short* xb   = (unsigned short*)region1;
    unsigned short* W1t  = (unsigned short*)(region1 + (size_t)N_NODES * F_IN * 2 + 256);

    unsigned short* W2t = (unsigned short*)alloc((size_t)OUTC * HC * 2);

    float* a_src1   = (float*)alloc((size_t)N_NODES * HEADS * 4);
    float* a_dst1   = (float*)alloc((size_t)N_NODES * HEADS * 4);
    int*   deg      = (int*)alloc((size_t)(N_NODES + 1) * 4);  /* +1: alloc counter */
    int*   counter  = deg + N_NODES;
    int*   rowstart = (int*)alloc((size_t)N_NODES * 4);
    int*   cursor   = (int*)alloc((size_t)N_NODES * 4);
    int*   csr_src  = (int*)alloc((size_t)E_TOT * 4);

    /* layer-2 buffers aliased into region0 */
    char* q = region0;
    auto alias = [&](size_t bytes) { char* r = q; q += (bytes + 255) & ~(size_t)255; return r; };
    unsigned short* h2 = (unsigned short*)alias((size_t)N_NODES * OUTC * 2);
    float* a_src2  = (float*)alias((size_t)N_NODES * 4);
    float* a_dst2  = (float*)alias((size_t)N_NODES * 4);

    hipMemsetAsync(deg, 0, (size_t)(N_NODES + 1) * 4, stream);

    /* fused prep: cvt_x | deg | cvt_w1t | cvt_w2t */
    prep_kernel<<<NB_PREP, 256, 0, stream>>>(x, xb, W1, W1t, W2, W2t, ei, deg);

    /* CSR build (parallel, unordered ranges) */
    alloc_kernel<<<(N_NODES + 255) / 256, 256, 0, stream>>>(deg, rowstart, cursor, counter);
    scatter_kernel<<<(E_TOT + 255) / 256, 256, 0, stream>>>(ei, cursor, csr_src);

    /* layer 1 (att dots fused into gemm1 epilogue; h1 stored fp8 slot-layout) */
    gemm1_mfma<<<dim3(HC / 128, (N_NODES + 127) / 128), 256, 0, stream>>>(
        xb, W1t, h1p, as1, ad1, a_src1, a_dst1, N_NODES);
    agg1_fused<<<N_NODES / 4, 256, 0, stream>>>(rowstart, deg, csr_src, h1p, a_src1, a_dst1, b1, out1);

    /* layer 2 (h1p dead; aliased buffers safe, stream-ordered; att2 fused into gemm2) */
    gemm2_mfma<<<(N_NODES + 127) / 128, 256, 0, stream>>>(
        out1, W2t, h2, as2, ad2, a_src2, a_dst2, N_NODES);
    agg2_lsm<<<N_NODES / 4, 256, 0, stream>>>(rowstart, deg, csr_src, h2, a_src2, a_dst2, b2, (float*)d_out);
}

// Round 13
// 263.543 us; speedup vs baseline: 19.4221x; 1.0456x over previous
//
#include <hip/hip_runtime.h>
#include <math.h>

#define N_NODES 30000
#define F_IN 256
#define E_RAW 300000
#define E_TOT (E_RAW + N_NODES)   /* 330000: edges + self loops */
#define HEADS 8
#define CH 128
#define HC 1024                   /* HEADS*CH */
#define OUTC 64
#define NEG_SLOPE 0.2f
#define CAP 64                    /* edges per LDS chunk in fused agg kernels */

typedef __attribute__((ext_vector_type(8))) short bf16x8;
typedef __attribute__((ext_vector_type(4))) float f32x4;
typedef __attribute__((ext_vector_type(2))) float f32x2;

/* ---------- helpers ---------- */
__device__ __forceinline__ float bf2f(unsigned short u) {
    return __uint_as_float(((unsigned)u) << 16);
}
__device__ __forceinline__ unsigned short f2bf(float f) {
    unsigned b = __float_as_uint(f);
    b += 0x7FFFu + ((b >> 16) & 1u);   /* round to nearest even */
    return (unsigned short)(b >> 16);
}
__device__ __forceinline__ void edge_sd(const int* __restrict__ ei, int e, int& s, int& d) {
    if (e < E_RAW) { s = ei[e]; d = ei[E_RAW + e]; }
    else           { s = e - E_RAW; d = s; }
}
/* async global->LDS, 16B per lane; LDS dest = wave-uniform base + lane*16 */
__device__ __forceinline__ void async_cp16(const void* g, void* l) {
    __builtin_amdgcn_global_load_lds((const __attribute__((address_space(1))) void*)g,
                                     (__attribute__((address_space(3))) void*)l, 16, 0, 0);
}
/* fp8 slot permutation: slot s -> original channel */
__device__ __forceinline__ int slotP(int s) {
    return ((s >> 6) << 6) + ((s >> 2) & 15) + ((s & 3) << 4);
}

/* ---------- fused prep: cvt_x | deg | cvt_w1t | cvt_w2t (independent jobs) ---------- */
#define NB_CVTX (N_NODES * F_IN / 4 / 256)      /* 7500 */
#define NB_DEG  ((E_TOT + 255) / 256)           /* 1290 */
#define NB_W1T  ((F_IN * HC + 255) / 256)       /* 1024 */
#define NB_W2T  ((HC * OUTC + 255) / 256)       /* 256 */
#define NB_PREP (NB_CVTX + NB_DEG + NB_W1T + NB_W2T)

__global__ __launch_bounds__(256)
void prep_kernel(const float* __restrict__ x, unsigned short* __restrict__ xb,
                 const float* __restrict__ W1, unsigned short* __restrict__ W1t,
                 const float* __restrict__ W2, unsigned short* __restrict__ W2t,
                 const int* __restrict__ ei, int* __restrict__ deg)
{
    const int b = blockIdx.x, t = threadIdx.x;
    if (b < NB_CVTX) {
        int i = b * 256 + t;
        const float4 v = reinterpret_cast<const float4*>(x)[i];
        ushort4 o;
        o.x = f2bf(v.x); o.y = f2bf(v.y); o.z = f2bf(v.z); o.w = f2bf(v.w);
        reinterpret_cast<ushort4*>(xb)[i] = o;
    } else if (b < NB_CVTX + NB_DEG) {
        int e = (b - NB_CVTX) * 256 + t;
        if (e < E_TOT) {
            int s, d; edge_sd(ei, e, s, d);
            atomicAdd(&deg[d], 1);
        }
    } else if (b < NB_CVTX + NB_DEG + NB_W1T) {
        int i = (b - NB_CVTX - NB_DEG) * 256 + t;
        if (i < F_IN * HC) {
            int k = i >> 10, n = i & (HC - 1);
            W1t[n * F_IN + k] = f2bf(W1[i]);
        }
    } else {
        /* W2t[n][s] = W2[P(s)][n] — k-axis carries the out1 slot permutation */
        int i = (b - NB_CVTX - NB_DEG - NB_W1T) * 256 + t;
        if (i < HC * OUTC) {
            int s = i >> 6, n = i & (OUTC - 1);
            W2t[n * HC + s] = f2bf(W2[slotP(s) * OUTC + n]);
        }
    }
}

/* ---------- layer-1 MFMA GEMM + fused attention dots, fp8 slot-layout C ----------
   BK=64, XOR-swizzled LDS: LDS[r][q] holds 16B chunk q^(r&7) of the row, so
   fragment reads (chunk c at row rr) hit index c^(rr&7) — all 32 banks, 2-way. */
__global__ __launch_bounds__(256)
void gemm1_mfma(const unsigned short* __restrict__ A,
                const unsigned short* __restrict__ Bt,
                unsigned* __restrict__ Cp,      /* [M][256] dwords, fp8 slots */
                const float* __restrict__ att_src, const float* __restrict__ att_dst,
                float* __restrict__ a_src, float* __restrict__ a_dst, int M)
{
    __shared__ unsigned short Al[128 * 64];
    __shared__ unsigned short Bl[128 * 64];
    __shared__ float s_src[128][2];
    __shared__ float s_dst[128][2];
    const int tid  = threadIdx.x;
    const int wave = tid >> 6, lane = tid & 63;
    const int quad = lane >> 4, l16 = lane & 15;
    const int wr = (wave >> 1) * 64, wc = (wave & 1) * 64;
    const int row0 = blockIdx.y * 128;
    const int col0 = blockIdx.x * 128;

    f32x4 acc[4][4];
#pragma unroll
    for (int i = 0; i < 4; i++)
#pragma unroll
        for (int j = 0; j < 4; j++) acc[i][j] = (f32x4){0.f, 0.f, 0.f, 0.f};

    for (int k0 = 0; k0 < F_IN; k0 += 64) {
#pragma unroll
        for (int p = 0; p < 4; p++) {           /* A: 128 rows x 64 bf16, swizzled */
            int idx = tid + 256 * p;
            int r = idx >> 3, q = idx & 7;
            async_cp16(A + (size_t)(row0 + r) * F_IN + k0 + ((q ^ (r & 7)) * 8),
                       Al + (size_t)(wave * 64 + 256 * p) * 8);
        }
#pragma unroll
        for (int p = 0; p < 4; p++) {           /* B^T: 128 rows x 64 bf16, swizzled */
            int idx = tid + 256 * p;
            int r = idx >> 3, q = idx & 7;
            async_cp16(Bt + (size_t)(col0 + r) * F_IN + k0 + ((q ^ (r & 7)) * 8),
                       Bl + (size_t)(wave * 64 + 256 * p) * 8);
        }
        __syncthreads();
#pragma unroll
        for (int kh = 0; kh < 2; kh++) {        /* two k-halves, sequential (reg-lean) */
            const int cx = (kh * 4 + quad) ^ (l16 & 7);
            bf16x8 af[4], bg[4];
#pragma unroll
            for (int i = 0; i < 4; i++)
                af[i] = *reinterpret_cast<const bf16x8*>(Al + ((wr + i * 16 + l16) * 8 + cx) * 8);
#pragma unroll
            for (int j = 0; j < 4; j++)
                bg[j] = *reinterpret_cast<const bf16x8*>(Bl + ((wc + j * 16 + l16) * 8 + cx) * 8);
#pragma unroll
            for (int i = 0; i < 4; i++)
#pragma unroll
                for (int j = 0; j < 4; j++)
                    acc[i][j] = __builtin_amdgcn_mfma_f32_16x16x32_bf16(af[i], bg[j], acc[i][j], 0, 0, 0);
        }
        __syncthreads();
    }
    /* C write: pack 4 cols (j=0..3, stride 16) into one fp8 dword at slot-dword D */
    const int D = ((col0 + wc) >> 6) * 16 + l16;
#pragma unroll
    for (int i = 0; i < 4; i++) {
#pragma unroll
        for (int r = 0; r < 4; r++) {
            int row = row0 + wr + i * 16 + quad * 4 + r;
            if (row >= M) continue;
            int w8 = __builtin_amdgcn_cvt_pk_fp8_f32(acc[i][0][r], acc[i][1][r], 0, false);
            w8 = __builtin_amdgcn_cvt_pk_fp8_f32(acc[i][2][r], acc[i][3][r], w8, true);
            Cp[(size_t)row * 256 + D] = (unsigned)w8;
        }
    }
    /* fused attention dots for head = blockIdx.x */
    const float* asv = att_src + blockIdx.x * CH;
    const float* adv = att_dst + blockIdx.x * CH;
    float av[4], dv[4];
#pragma unroll
    for (int j = 0; j < 4; j++) {
        av[j] = asv[wc + j * 16 + l16];
        dv[j] = adv[wc + j * 16 + l16];
    }
#pragma unroll
    for (int i = 0; i < 4; i++) {
#pragma unroll
        for (int r = 0; r < 4; r++) {
            float ps = 0.f, pd = 0.f;
#pragma unroll
            for (int j = 0; j < 4; j++) {
                float cc = acc[i][j][r];
                ps += cc * av[j];
                pd += cc * dv[j];
            }
#pragma unroll
            for (int o = 1; o < 16; o <<= 1) {
                ps += __shfl_xor(ps, o);
                pd += __shfl_xor(pd, o);
            }
            if (l16 == 0) {
                int lr = wr + i * 16 + quad * 4 + r;
                s_src[lr][wc >> 6] = ps;
                s_dst[lr][wc >> 6] = pd;
            }
        }
    }
    __syncthreads();
    if (tid < 128) {
        int row = row0 + tid;
        if (row < M) {
            a_src[row * 8 + blockIdx.x] = s_src[tid][0] + s_src[tid][1];
            a_dst[row * 8 + blockIdx.x] = s_dst[tid][0] + s_dst[tid][1];
        }
    }
}

/* ---------- layer-2 MFMA GEMM + fused att2 dots ----------
   64-row tiles (469 blocks), BK=64 swizzled; wave w owns rows w*16..w*16+15. */
__global__ __launch_bounds__(256)
void gemm2_mfma(const unsigned short* __restrict__ A,
                const unsigned short* __restrict__ Bt,
                unsigned short* __restrict__ C,
                const float* __restrict__ att_src2, const float* __restrict__ att_dst2,
                float* __restrict__ a_src2, float* __restrict__ a_dst2, int M)
{
    __shared__ unsigned short Al[64 * 64];
    __shared__ unsigned short Bl[64 * 64];
    const int tid  = threadIdx.x;
    const int wave = tid >> 6, lane = tid & 63;
    const int quad = lane >> 4, l16 = lane & 15;
    const int wr = wave * 16;
    const int row0 = blockIdx.x * 64;

    f32x4 acc[4];
#pragma unroll
    for (int j = 0; j < 4; j++) acc[j] = (f32x4){0.f, 0.f, 0.f, 0.f};

    for (int k0 = 0; k0 < HC; k0 += 64) {
#pragma unroll
        for (int p = 0; p < 2; p++) {           /* A: 64 rows x 64 bf16, swizzled */
            int idx = tid + 256 * p;
            int r = idx >> 3, q = idx & 7;
            async_cp16(A + (size_t)(row0 + r) * HC + k0 + ((q ^ (r & 7)) * 8),
                       Al + (size_t)(wave * 64 + 256 * p) * 8);
        }
#pragma unroll
        for (int p = 0; p < 2; p++) {           /* B^T: 64 rows x 64 bf16, swizzled */
            int idx = tid + 256 * p;
            int r = idx >> 3, q = idx & 7;
            async_cp16(Bt + (size_t)r * HC + k0 + ((q ^ (r & 7)) * 8),
                       Bl + (size_t)(wave * 64 + 256 * p) * 8);
        }
        __syncthreads();
#pragma unroll
        for (int kh = 0; kh < 2; kh++) {
            const int cx = (kh * 4 + quad) ^ (l16 & 7);
            bf16x8 af, bg[4];
            af = *reinterpret_cast<const bf16x8*>(Al + ((wr + l16) * 8 + cx) * 8);
#pragma unroll
            for (int j = 0; j < 4; j++)
                bg[j] = *reinterpret_cast<const bf16x8*>(Bl + ((j * 16 + l16) * 8 + cx) * 8);
#pragma unroll
            for (int j = 0; j < 4; j++)
                acc[j] = __builtin_amdgcn_mfma_f32_16x16x32_bf16(af, bg[j], acc[j], 0, 0, 0);
        }
        __syncthreads();
    }
    float av[4], dv[4];
#pragma unroll
    for (int j = 0; j < 4; j++) {
        av[j] = att_src2[j * 16 + l16];
        dv[j] = att_dst2[j * 16 + l16];
    }
#pragma unroll
    for (int r = 0; r < 4; r++) {
        int row = row0 + wr + quad * 4 + r;
        float ps = 0.f, pd = 0.f;
#pragma unroll
        for (int j = 0; j < 4; j++) {
            float cc = acc[j][r];
            int col = j * 16 + l16;
            if (row < M) C[(size_t)row * OUTC + col] = f2bf(cc);
            ps += cc * av[j];
            pd += cc * dv[j];
        }
#pragma unroll
        for (int o = 1; o < 16; o <<= 1) {
            ps += __shfl_xor(ps, o);
            pd += __shfl_xor(pd, o);
        }
        if (l16 == 0 && row < M) {
            a_src2[row] = ps;
            a_dst2[row] = pd;
        }
    }
}

/* ---------- CSR build ---------- */
__global__ __launch_bounds__(256)
void alloc_kernel(const int* __restrict__ deg, int* __restrict__ rowstart,
                  int* __restrict__ cursor, int* __restrict__ counter)
{
    int d = blockIdx.x * 256 + threadIdx.x;
    int lane = threadIdx.x & 63;
    int v = (d < N_NODES) ? deg[d] : 0;
    int x = v;
#pragma unroll
    for (int o = 1; o < 64; o <<= 1) {
        int y = __shfl_up(x, o);
        if (lane >= o) x += y;
    }
    int excl = x - v;
    int total = __shfl(x, 63);
    int base = 0;
    if (lane == 63) base = atomicAdd(counter, total);
    base = __shfl(base, 63);
    if (d < N_NODES) {
        rowstart[d] = base + excl;
        cursor[d]   = base + excl;
    }
}

__global__ void scatter_kernel(const int* __restrict__ ei, int* __restrict__ cursor,
                               int* __restrict__ csr_src)
{
    int e = blockIdx.x * 256 + threadIdx.x;
    if (e >= E_TOT) return;
    int s, d; edge_sd(ei, e, s, d);
    int pos = atomicAdd(&cursor[d], 1);
    csr_src[pos] = s;
}

/* ---------- layer-1 fused softmax+aggregation, bias+ELU ----------
   fp8 h1 (slot layout): 4 nodes per 256-block, 64 threads/node,
   thread owns 16 fp8 channels (uint4 load) all within one head. */
__global__ __launch_bounds__(256)
void agg1_fused(const int* __restrict__ rowstart, const int* __restrict__ degv,
                const int* __restrict__ csr_src,
                const unsigned* __restrict__ h1p,     /* [N][256] fp8 dwords */
                const float* __restrict__ a_src1, const float* __restrict__ a_dst1,
                const float* __restrict__ b1, unsigned short* __restrict__ out1)
{
    const int t   = threadIdx.x;
    const int sub = t >> 6;            /* node within block: 0..3 */
    const int tl  = t & 63;            /* thread within node */
    const int h   = tl >> 3;           /* head (all 16 channels of tl in this head) */
    const int d   = blockIdx.x * 4 + sub;

    __shared__ float exps[4][CAP * 8];
    __shared__ int   srcs[4][CAP];
    __shared__ int   maxdeg_s;

    const int start = rowstart[d];
    const int deg   = degv[d];

    if (t == 0) maxdeg_s = 0;
    __syncthreads();
    if (tl == 0) atomicMax(&maxdeg_s, deg);
    __syncthreads();
    const int maxdeg = maxdeg_s;

    const float adst = a_dst1[d * 8 + h];
    const uint4* __restrict__ h1v = reinterpret_cast<const uint4*>(h1p);  /* row = 64 uint4 */

    float denom_part = 0.f;
    float acc[16];
#pragma unroll
    for (int k = 0; k < 16; k++) acc[k] = 0.f;

    for (int c0 = 0; c0 < maxdeg; c0 += CAP) {
        const int cend = min(deg - c0, CAP);
        /* phase 1: exps for my head; 8 lanes per head stride the chunk */
        for (int c = (tl & 7); c < cend; c += 8) {
            int s = csr_src[start + c0 + c];
            if (h == 0) srcs[sub][c] = s;
            float a = a_src1[s * 8 + h] + adst;
            float v = a > 0.f ? a : NEG_SLOPE * a;
            float ex = __expf(v);
            exps[sub][c * 8 + h] = ex;
            denom_part += ex;
        }
        __syncthreads();
        /* phase 2: 1-ahead pipelined fp8 gather */
        if (cend > 0) {
            int   s_cur = srcs[sub][0];
            float w_cur = exps[sub][h];
            uint4 u_cur = h1v[(size_t)s_cur * 64 + tl];
            for (int c = 0; c < cend; c++) {
                int   s_nxt = 0; float w_nxt = 0.f; uint4 u_nxt;
                if (c + 1 < cend) {
                    s_nxt = srcs[sub][c + 1];
                    w_nxt = exps[sub][(c + 1) * 8 + h];
                    u_nxt = h1v[(size_t)s_nxt * 64 + tl];
                }
#pragma unroll
                for (int dw = 0; dw < 4; dw++) {
                    unsigned wd = (&u_cur.x)[dw];
                    f32x2 lo = __builtin_amdgcn_cvt_pk_f32_fp8((int)wd, false);
                    f32x2 hi = __builtin_amdgcn_cvt_pk_f32_fp8((int)wd, true);
                    acc[dw * 4 + 0] += w_cur * lo.x;
                    acc[dw * 4 + 1] += w_cur * lo.y;
                    acc[dw * 4 + 2] += w_cur * hi.x;
                    acc[dw * 4 + 3] += w_cur * hi.y;
                }
                s_cur = s_nxt; w_cur = w_nxt; u_cur = u_nxt;
            }
        }
        __syncthreads();
    }
    /* denominator: reduce over the 8 lanes of this head */
#pragma unroll
    for (int o = 1; o < 8; o <<= 1) denom_part += __shfl_xor(denom_part, o);
    const float dinv = 1.f / (denom_part + 1e-16f);

    /* bias (gathered at original channels) + ELU, write bf16 slots 16tl..16tl+15 */
    unsigned short ov[16];
#pragma unroll
    for (int e = 0; e < 16; e++) {
        float v = acc[e] * dinv + b1[slotP(16 * tl + e)];
        v = v > 0.f ? v : __expf(v) - 1.f;
        ov[e] = f2bf(v);
    }
    uint4* op = reinterpret_cast<uint4*>(out1 + (size_t)d * HC + 16 * tl);
    op[0] = *reinterpret_cast<uint4*>(&ov[0]);
    op[1] = *reinterpret_cast<uint4*>(&ov[8]);
}

/* ---------- layer-2 fused softmax+agg + bias + log_softmax ----------
   4 nodes per 256-block; 4 edges in flight (16-lane groups); bf16 h2,
   each lane owns 4 channels (uint2 = 8B loads). */
__global__ __launch_bounds__(256)
void agg2_lsm(const int* __restrict__ rowstart, const int* __restrict__ degv,
              const int* __restrict__ csr_src,
              const unsigned short* __restrict__ h2,
              const float* __restrict__ a_src2, const float* __restrict__ a_dst2,
              const float* __restrict__ b2, float* __restrict__ out)
{
    const int t = threadIdx.x;
    const int sub  = t >> 6;
    const int lane = t & 63;
    const int eo   = lane >> 4;        /* edge offset 0..3 */
    const int cq   = lane & 15;        /* channel quad: channels 4cq..4cq+3 */
    const int d = blockIdx.x * 4 + sub;

    __shared__ float exs[4][CAP];
    __shared__ int   ss[4][CAP];
    __shared__ int   maxdeg_s;

    const int start = rowstart[d];
    const int deg   = degv[d];

    if (t == 0) maxdeg_s = 0;
    __syncthreads();
    if (lane == 0) atomicMax(&maxdeg_s, deg);
    __syncthreads();
    const int maxdeg = maxdeg_s;

    const float adst = a_dst2[d];
    const uint2* __restrict__ h2v = reinterpret_cast<const uint2*>(h2);  /* row = 16 uint2 */
    float denom_part = 0.f;
    float ax = 0.f, ay = 0.f, az = 0.f, aw = 0.f;

    for (int c0 = 0; c0 < maxdeg; c0 += CAP) {
        const int cend = min(deg - c0, CAP);
        for (int c = lane; c < cend; c += 64) {
            int s = csr_src[start + c0 + c];
            ss[sub][c] = s;
            float a = a_src2[s] + adst;
            float v = a > 0.f ? a : NEG_SLOPE * a;
            float ex = __expf(v);
            exs[sub][c] = ex;
            denom_part += ex;
        }
        __syncthreads();
        if (cend > 0) {
            int   cc = eo;
            float w0 = (cc < cend) ? exs[sub][cc] : 0.f;
            int   s0 = (cc < cend) ? ss[sub][cc] : ss[sub][0];
            uint2 u0 = h2v[(size_t)s0 * 16 + cq];
            for (int c = 0; c + 4 < cend; c += 4) {
                int cc1 = c + 4 + eo;
                float w1 = (cc1 < cend) ? exs[sub][cc1] : 0.f;
                int   s1 = (cc1 < cend) ? ss[sub][cc1] : ss[sub][0];
                uint2 u1 = h2v[(size_t)s1 * 16 + cq];
                ax += w0 * __uint_as_float(u0.x << 16);
                ay += w0 * __uint_as_float(u0.x & 0xFFFF0000u);
                az += w0 * __uint_as_float(u0.y << 16);
                aw += w0 * __uint_as_float(u0.y & 0xFFFF0000u);
                w0 = w1; s0 = s1; u0 = u1;
            }
            ax += w0 * __uint_as_float(u0.x << 16);
            ay += w0 * __uint_as_float(u0.x & 0xFFFF0000u);
            az += w0 * __uint_as_float(u0.y << 16);
            aw += w0 * __uint_as_float(u0.y & 0xFFFF0000u);
        }
        __syncthreads();
    }
    /* combine the 4 edge groups: lanes l, l^16, l^32, l^48 share a channel quad */
    ax += __shfl_xor(ax, 16); ax += __shfl_xor(ax, 32);
    ay += __shfl_xor(ay, 16); ay += __shfl_xor(ay, 32);
    az += __shfl_xor(az, 16); az += __shfl_xor(az, 32);
    aw += __shfl_xor(aw, 16); aw += __shfl_xor(aw, 32);
#pragma unroll
    for (int o = 32; o > 0; o >>= 1) denom_part += __shfl_xor(denom_part, o);
    const float dinv = 1.f / (denom_part + 1e-16f);

    float4 bb = reinterpret_cast<const float4*>(b2)[cq];
    float v0 = ax * dinv + bb.x;
    float v1 = ay * dinv + bb.y;
    float v2 = az * dinv + bb.z;
    float v3 = aw * dinv + bb.w;
    float m = fmaxf(fmaxf(v0, v1), fmaxf(v2, v3));
#pragma unroll
    for (int o = 1; o < 16; o <<= 1) m = fmaxf(m, __shfl_xor(m, o));
    float ex = __expf(v0 - m) + __expf(v1 - m) + __expf(v2 - m) + __expf(v3 - m);
    float ssum = ex;
#pragma unroll
    for (int o = 1; o < 16; o <<= 1) ssum += __shfl_xor(ssum, o);
    if (eo == 0) {
        float lg = __logf(ssum);
        reinterpret_cast<float4*>(out + (size_t)d * OUTC)[cq] =
            make_float4(v0 - m - lg, v1 - m - lg, v2 - m - lg, v3 - m - lg);
    }
}

extern "C" void kernel_launch(void* const* d_in, const int* in_sizes, int n_in,
                              void* d_out, int out_size, void* d_ws, size_t ws_size,
                              hipStream_t stream)
{
    const float* x   = (const float*)d_in[0];
    const int*   ei  = (const int*)d_in[1];
    const float* W1  = (const float*)d_in[2];
    const float* as1 = (const float*)d_in[3];
    const float* ad1 = (const float*)d_in[4];
    const float* b1  = (const float*)d_in[5];
    const float* W2  = (const float*)d_in[6];
    const float* as2 = (const float*)d_in[7];
    const float* ad2 = (const float*)d_in[8];
    const float* b2  = (const float*)d_in[9];

    char* p = (char*)d_ws;
    auto alloc = [&](size_t bytes) { char* r = p; p += (bytes + 255) & ~(size_t)255; return r; };

    /* region 0: h1p (fp8, 30.72 MB; sized 61.44) — dead after agg1; layer-2 aliases it */
    char* region0 = (char*)alloc((size_t)N_NODES * HC * 2);
    unsigned* h1p = (unsigned*)region0;

    /* region 1: out1 (bf16 slot-layout, 61.44 MB); xb/W1t (dead after gemm1) alias it */
    char* region1 = (char*)alloc((size_t)N_NODES * HC * 2);
    unsigned short* out1 = (unsigned short*)region1;
    unsigned short* xb   = (unsigned short*)region1;
    unsigned short* W1t  = (unsigned short*)(region1 + (size_t)N_NODES * F_IN * 2 + 256);

    unsigned short* W2t = (unsigned short*)alloc((size_t)OUTC * HC * 2);

    float* a_src1   = (float*)alloc((size_t)N_NODES * HEADS * 4);
    float* a_dst1   = (float*)alloc((size_t)N_NODES * HEADS * 4);
    int*   deg      = (int*)alloc((size_t)(N_NODES + 1) * 4);  /* +1: alloc counter */
    int*   counter  = deg + N_NODES;
    int*   rowstart = (int*)alloc((size_t)N_NODES * 4);
    int*   cursor   = (int*)alloc((size_t)N_NODES * 4);
    int*   csr_src  = (int*)alloc((size_t)E_TOT * 4);

    /* layer-2 buffers aliased into region0 */
    char* q = region0;
    auto alias = [&](size_t bytes) { char* r = q; q += (bytes + 255) & ~(size_t)255; return r; };
    unsigned short* h2 = (unsigned short*)alias((size_t)N_NODES * OUTC * 2);
    float* a_src2  = (float*)alias((size_t)N_NODES * 4);
    float* a_dst2  = (float*)alias((size_t)N_NODES * 4);

    hipMemsetAsync(deg, 0, (size_t)(N_NODES + 1) * 4, stream);

    /* fused prep: cvt_x | deg | cvt_w1t | cvt_w2t */
    prep_kernel<<<NB_PREP, 256, 0, stream>>>(x, xb, W1, W1t, W2, W2t, ei, deg);

    /* CSR build (parallel, unordered ranges) */
    alloc_kernel<<<(N_NODES + 255) / 256, 256, 0, stream>>>(deg, rowstart, cursor, counter);
    scatter_kernel<<<(E_TOT + 255) / 256, 256, 0, stream>>>(ei, cursor, csr_src);

    /* layer 1 (att dots fused into gemm1 epilogue; h1 stored fp8 slot-layout) */
    gemm1_mfma<<<dim3(HC / 128, (N_NODES + 127) / 128), 256, 0, stream>>>(
        xb, W1t, h1p, as1, ad1, a_src1, a_dst1, N_NODES);
    agg1_fused<<<N_NODES / 4, 256, 0, stream>>>(rowstart, deg, csr_src, h1p, a_src1, a_dst1, b1, out1);

    /* layer 2 (h1p dead; aliased buffers safe, stream-ordered; att2 fused into gemm2) */
    gemm2_mfma<<<(N_NODES + 63) / 64, 256, 0, stream>>>(
        out1, W2t, h2, as2, ad2, a_src2, a_dst2, N_NODES);
    agg2_lsm<<<N_NODES / 4, 256, 0, stream>>>(rowstart, deg, csr_src, h2, a_src2, a_dst2, b2, (float*)d_out);
}